// Round 2
// baseline (421.369 us; speedup 1.0000x reference)
//
#include <hip/hip_runtime.h>
#include <hip/hip_bf16.h>
#include <math.h>

typedef __hip_bfloat16 bf16;
typedef float v2f __attribute__((ext_vector_type(2)));
typedef float v4f __attribute__((ext_vector_type(4)));
typedef short v8s __attribute__((ext_vector_type(8)));
typedef _Float16 v2h __attribute__((ext_vector_type(2)));

__device__ __forceinline__ float b2f(bf16 v) { return __bfloat162float(v); }
__device__ __forceinline__ float unpk_lo(unsigned u) { return __uint_as_float(u << 16); }
__device__ __forceinline__ float unpk_hi(unsigned u) { return __uint_as_float(u & 0xffff0000u); }
__device__ __forceinline__ v2f unpk2(unsigned u) {
    v2f r; r.x = __uint_as_float(u << 16); r.y = __uint_as_float(u & 0xffff0000u); return r;
}
__device__ __forceinline__ unsigned pk2(float a, float b) {
    unsigned ua = __float_as_uint(a);
    unsigned ub = __float_as_uint(b);
    ua = (ua + 0x7fffu + ((ua >> 16) & 1u)) >> 16;   // RNE to bf16
    ub = (ub + 0x7fffu + ((ub >> 16) & 1u)) >> 16;
    return ua | (ub << 16);
}
__device__ __forceinline__ short f2bs(float f) {
    unsigned u = __float_as_uint(f);
    u = (u + 0x7fffu + ((u >> 16) & 1u)) >> 16;
    return (short)u;
}
__device__ __forceinline__ v2h u2h(unsigned u) {
    union { unsigned u; v2h h; } c; c.u = u; return c.h;
}
__device__ __forceinline__ float gelu_exact(float x) {
    return 0.5f * x * (1.f + erff(x * 0.70710678118654752440f));
}

#define LOG2E 1.44269504088896340736f

// ---------------------------------------------------------------------------
// Repack a KxN fp32 weight into bf16 MFMA B-fragments for 16x16x32.
// ---------------------------------------------------------------------------
__global__ __launch_bounds__(256) void k_repack(const float* __restrict__ src,
                                                bf16* __restrict__ dst, int K, int N) {
    int idx = blockIdx.x * 256 + threadIdx.x;
    if (idx >= K * N) return;
    int k = idx / N, n = idx % N;
    int kstep = k >> 5, quad = (k & 31) >> 3, j = k & 7;
    int ntile = n >> 4, nn = n & 15;
    size_t di = ((((size_t)kstep * (N >> 4)) + ntile) * 64 + nn + (quad << 4)) * 8 + j;
    dst[di] = __float2bfloat16(src[idx]);
}

// Same repack but scales row k by g[k] (folds the LN gain into the weight).
__global__ __launch_bounds__(256) void k_repack_g(const float* __restrict__ src,
                                                  const float* __restrict__ g,
                                                  bf16* __restrict__ dst, int K, int N) {
    int idx = blockIdx.x * 256 + threadIdx.x;
    if (idx >= K * N) return;
    int k = idx / N, n = idx % N;
    int kstep = k >> 5, quad = (k & 31) >> 3, j = k & 7;
    int ntile = n >> 4, nn = n & 15;
    size_t di = ((((size_t)kstep * (N >> 4)) + ntile) * 64 + nn + (quad << 4)) * 8 + j;
    dst[di] = __float2bfloat16(src[idx] * g[k]);
}

// LN-fold correction vectors for the ctx projection (K=256, N=64):
//   cgw[n] = sum_e g[e] * W[e][n]
//   cbw[n] = sum_e b[e] * W[e][n] + pb[n]
__global__ __launch_bounds__(256) void k_ctxc(const float* __restrict__ w,
                                              const float* __restrict__ g,
                                              const float* __restrict__ bb,
                                              const float* __restrict__ pb,
                                              float* __restrict__ cgw,
                                              float* __restrict__ cbw) {
    __shared__ float rg_[4][64], rb_[4][64];
    const int n = threadIdx.x & 63, eg = threadIdx.x >> 6;
    float sg = 0.f, sb = 0.f;
    for (int e = eg * 64; e < eg * 64 + 64; ++e) {
        float wv = w[e * 64 + n];
        sg += g[e] * wv;
        sb += bb[e] * wv;
    }
    rg_[eg][n] = sg; rb_[eg][n] = sb;
    __syncthreads();
    if (threadIdx.x < 64) {
        float a = rg_[0][n] + rg_[1][n] + rg_[2][n] + rg_[3][n];
        float c = rb_[0][n] + rb_[1][n] + rb_[2][n] + rb_[3][n];
        cgw[n] = a;
        cbw[n] = c + pb[n];
    }
}

// rpb -> log2e*rpb - 8  (the -8 cancels in softmax normalization; keeps
// unnormalized f16 PV accumulation far from overflow)
__global__ __launch_bounds__(256) void k_rpb(const float* __restrict__ src,
                                             float* __restrict__ dst, int n) {
    int i = blockIdx.x * 256 + threadIdx.x;
    if (i < n) dst[i] = src[i] * LOG2E - 8.0f;
}

// ---------------------------------------------------------------------------
// Kernel 1 (MFMA): ctx projection. A = raw ctx (transposed, bf16), B = g.W
// fragments; LN folded into epilogue:
//   out[r][n] = rs_r*(acc - mu_r*cgw[n]) + cbw[n]
// Block: 32 hw rows x 256 e, 4 waves each own one 16-col ntile of N=64.
// ---------------------------------------------------------------------------
__global__ __launch_bounds__(256) void k_ctx(const float* __restrict__ ctx,
                                             const float* __restrict__ cgw,
                                             const float* __restrict__ cbw,
                                             const bf16* __restrict__ wgf,
                                             bf16* __restrict__ outp) {
    __shared__ short As[32][264];
    __shared__ float redS[8][32];
    __shared__ float redQ[8][32];
    __shared__ float smu[32], srs[32];
    const int t = threadIdx.x;
    const int b = blockIdx.x >> 7;
    const int hw0 = (blockIdx.x & 127) << 5;
    {
        // lanes 0..31 of each wave read 32 contiguous hw floats (128B segments);
        // thread t owns row r = t&31, e-slice li*32..li*32+31 (li = t>>5).
        const int r = t & 31, li = t >> 5;
        const float* src = ctx + ((size_t)b * 256 + li * 32) * 4096 + hw0 + r;
        float v[32];
        float s = 0.f, q = 0.f;
#pragma unroll
        for (int j = 0; j < 32; ++j) {
            float x = src[(size_t)j * 4096];
            v[j] = x; s += x; q += x * x;
        }
        redS[li][r] = s;
        redQ[li][r] = q;
        v8s p0, p1, p2, p3;
#pragma unroll
        for (int j = 0; j < 8; ++j) p0[j] = f2bs(v[j]);
#pragma unroll
        for (int j = 0; j < 8; ++j) p1[j] = f2bs(v[8 + j]);
#pragma unroll
        for (int j = 0; j < 8; ++j) p2[j] = f2bs(v[16 + j]);
#pragma unroll
        for (int j = 0; j < 8; ++j) p3[j] = f2bs(v[24 + j]);
        v8s* dst = (v8s*)&As[r][li * 32];
        dst[0] = p0; dst[1] = p1; dst[2] = p2; dst[3] = p3;
    }
    __syncthreads();
    if (t < 32) {
        float s = 0.f, q = 0.f;
#pragma unroll
        for (int k = 0; k < 8; ++k) { s += redS[k][t]; q += redQ[k][t]; }
        float mu = s * (1.f / 256.f);
        float var = q * (1.f / 256.f) - mu * mu;
        smu[t] = mu;
        srs[t] = rsqrtf(var + 1e-5f);
    }
    __syncthreads();
    const int lane = t & 63, wv = t >> 6;
    const int m = lane & 15, quad = lane >> 4;
    v4f acc0 = (v4f){0.f, 0.f, 0.f, 0.f};
    v4f acc1 = (v4f){0.f, 0.f, 0.f, 0.f};
#pragma unroll
    for (int ks = 0; ks < 8; ++ks) {
        v8s a0 = *(const v8s*)&As[m][ks * 32 + quad * 8];
        v8s a1 = *(const v8s*)&As[m + 16][ks * 32 + quad * 8];
        v8s bfr = ((const v8s*)wgf)[((size_t)ks * 4 + wv) * 64 + lane];
        acc0 = __builtin_amdgcn_mfma_f32_16x16x32_bf16(a0, bfr, acc0, 0, 0, 0);
        acc1 = __builtin_amdgcn_mfma_f32_16x16x32_bf16(a1, bfr, acc1, 0, 0, 0);
    }
    const int n = wv * 16 + m;
    const float cg = cgw[n], cb = cbw[n];
    short* obase = (short*)outp + ((size_t)b * 4096 + hw0) * 64 + n;
#pragma unroll
    for (int rg = 0; rg < 4; ++rg) {
        int row = quad * 4 + rg;
        float o = srs[row] * (acc0[rg] - smu[row] * cg) + cb;
        obase[(size_t)row * 64] = f2bs(o);
    }
#pragma unroll
    for (int rg = 0; rg < 4; ++rg) {
        int row = 16 + quad * 4 + rg;
        float o = srs[row] * (acc1[rg] - smu[row] * cg) + cb;
        obase[(size_t)row * 64] = f2bs(o);
    }
}

// ---------------------------------------------------------------------------
// Kernel 2 (MFMA): LN(concat(x,ctx),192) -> q,k ; LN(x,128) -> v.
// q/k/v written as f16 (q folded with 0.25*log2e for exp2-softmax).
// ---------------------------------------------------------------------------
__global__ __launch_bounds__(256) void k_qkv(const float* __restrict__ x,
                                             const bf16* __restrict__ ctxp,
                                             const float* __restrict__ n1g, const float* __restrict__ n1b,
                                             const float* __restrict__ nvg, const float* __restrict__ nvb,
                                             const bf16* __restrict__ qwf, const float* __restrict__ qb,
                                             const bf16* __restrict__ kwf, const float* __restrict__ kb,
                                             const bf16* __restrict__ vwf, const float* __restrict__ vb,
                                             _Float16* __restrict__ qo, _Float16* __restrict__ ko,
                                             _Float16* __restrict__ vo) {
    __shared__ short Aqk[32][200];
    __shared__ short Av[32][136];
    const int t = threadIdx.x;
    const size_t row0 = (size_t)blockIdx.x * 32;
    {
        const int r = t >> 3, li = t & 7;
        const float* xr = x + (row0 + r) * 128 + li * 16;
        float v[16];
        float sx1 = 0.f, sx2 = 0.f;
#pragma unroll
        for (int k4 = 0; k4 < 4; ++k4) {
            float4 vv = *(const float4*)(xr + 4 * k4);
            v[4 * k4 + 0] = vv.x; v[4 * k4 + 1] = vv.y; v[4 * k4 + 2] = vv.z; v[4 * k4 + 3] = vv.w;
            sx1 += vv.x + vv.y + vv.z + vv.w;
            sx2 += vv.x * vv.x + vv.y * vv.y + vv.z * vv.z + vv.w * vv.w;
        }
        float cv[8];
        float sc1 = 0.f, sc2 = 0.f;
        {
            uint4 cu = *(const uint4*)(ctxp + (row0 + r) * 64 + li * 8);
            v2f p0 = unpk2(cu.x), p1 = unpk2(cu.y), p2 = unpk2(cu.z), p3 = unpk2(cu.w);
            cv[0] = p0.x; cv[1] = p0.y; cv[2] = p1.x; cv[3] = p1.y;
            cv[4] = p2.x; cv[5] = p2.y; cv[6] = p3.x; cv[7] = p3.y;
#pragma unroll
            for (int k = 0; k < 8; ++k) { sc1 += cv[k]; sc2 += cv[k] * cv[k]; }
        }
#pragma unroll
        for (int o = 1; o < 8; o <<= 1) {
            sx1 += __shfl_xor(sx1, o); sx2 += __shfl_xor(sx2, o);
            sc1 += __shfl_xor(sc1, o); sc2 += __shfl_xor(sc2, o);
        }
        float mu  = (sx1 + sc1) * (1.f / 192.f);
        float rs  = rsqrtf((sx2 + sc2) * (1.f / 192.f) - mu * mu + 1e-5f);
        float muv = sx1 * (1.f / 128.f);
        float rsv = rsqrtf(sx2 * (1.f / 128.f) - muv * muv + 1e-5f);
        v8s q0, q1, vv0, vv1, cc;
#pragma unroll
        for (int k = 0; k < 8; ++k) {
            int c = li * 16 + k;
            q0[k]  = f2bs((v[k] - mu) * rs * n1g[c] + n1b[c]);
            vv0[k] = f2bs((v[k] - muv) * rsv * nvg[c] + nvb[c]);
        }
#pragma unroll
        for (int k = 0; k < 8; ++k) {
            int c = li * 16 + 8 + k;
            q1[k]  = f2bs((v[8 + k] - mu) * rs * n1g[c] + n1b[c]);
            vv1[k] = f2bs((v[8 + k] - muv) * rsv * nvg[c] + nvb[c]);
        }
#pragma unroll
        for (int k = 0; k < 8; ++k) {
            int c = 128 + li * 8 + k;
            cc[k] = f2bs((cv[k] - mu) * rs * n1g[c] + n1b[c]);
        }
        *(v8s*)&Aqk[r][li * 16]     = q0;
        *(v8s*)&Aqk[r][li * 16 + 8] = q1;
        *(v8s*)&Aqk[r][128 + li * 8] = cc;
        *(v8s*)&Av[r][li * 16]     = vv0;
        *(v8s*)&Av[r][li * 16 + 8] = vv1;
    }
    __syncthreads();
    const int lane = t & 63, wv = t >> 6;
    const int m = lane & 15, quad = lane >> 4;
    const int ntb = wv * 2;
    v4f aq[2][2], ak[2][2], av[2][2];
#pragma unroll
    for (int a = 0; a < 2; ++a)
#pragma unroll
        for (int b = 0; b < 2; ++b) {
            aq[a][b] = (v4f){0.f, 0.f, 0.f, 0.f};
            ak[a][b] = (v4f){0.f, 0.f, 0.f, 0.f};
            av[a][b] = (v4f){0.f, 0.f, 0.f, 0.f};
        }
#pragma unroll
    for (int ks = 0; ks < 6; ++ks) {
        v8s a0 = *(const v8s*)&Aqk[m][ks * 32 + quad * 8];
        v8s a1 = *(const v8s*)&Aqk[m + 16][ks * 32 + quad * 8];
        const v8s* bpq = (const v8s*)qwf + ((size_t)ks * 8 + ntb) * 64 + lane;
        const v8s* bpk = (const v8s*)kwf + ((size_t)ks * 8 + ntb) * 64 + lane;
#pragma unroll
        for (int nt = 0; nt < 2; ++nt) {
            v8s bq = bpq[nt * 64];
            v8s bk = bpk[nt * 64];
            aq[0][nt] = __builtin_amdgcn_mfma_f32_16x16x32_bf16(a0, bq, aq[0][nt], 0, 0, 0);
            aq[1][nt] = __builtin_amdgcn_mfma_f32_16x16x32_bf16(a1, bq, aq[1][nt], 0, 0, 0);
            ak[0][nt] = __builtin_amdgcn_mfma_f32_16x16x32_bf16(a0, bk, ak[0][nt], 0, 0, 0);
            ak[1][nt] = __builtin_amdgcn_mfma_f32_16x16x32_bf16(a1, bk, ak[1][nt], 0, 0, 0);
        }
    }
#pragma unroll
    for (int ks = 0; ks < 4; ++ks) {
        v8s a0 = *(const v8s*)&Av[m][ks * 32 + quad * 8];
        v8s a1 = *(const v8s*)&Av[m + 16][ks * 32 + quad * 8];
        const v8s* bpv = (const v8s*)vwf + ((size_t)ks * 8 + ntb) * 64 + lane;
#pragma unroll
        for (int nt = 0; nt < 2; ++nt) {
            v8s bv = bpv[nt * 64];
            av[0][nt] = __builtin_amdgcn_mfma_f32_16x16x32_bf16(a0, bv, av[0][nt], 0, 0, 0);
            av[1][nt] = __builtin_amdgcn_mfma_f32_16x16x32_bf16(a1, bv, av[1][nt], 0, 0, 0);
        }
    }
#pragma unroll
    for (int nt = 0; nt < 2; ++nt) {
        int n = (ntb + nt) * 16 + m;
        int head = n >> 4, d = n & 15;
        float qbv = qb[n], kbv = kb[n], vbv = vb[n];
#pragma unroll
        for (int mt = 0; mt < 2; ++mt)
#pragma unroll
            for (int rg = 0; rg < 4; ++rg) {
                int rowg = (int)row0 + mt * 16 + quad * 4 + rg;
                int b = rowg >> 12, hw = rowg & 4095;
                size_t oi = (((size_t)b * 8 + head) * 4096 + hw) * 16 + d;
                qo[oi] = (_Float16)((aq[mt][nt][rg] + qbv) * (0.25f * LOG2E));
                ko[oi] = (_Float16)(ak[mt][nt][rg] + kbv);
                vo[oi] = (_Float16)(av[mt][nt][rg] + vbv);
            }
    }
}

// ---------------------------------------------------------------------------
// Kernel 3: neighborhood attention, f16 + v_dot2 + pk_fma_f16.
// 4 query rows per thread (register blocking): one K/V LDS read feeds 4
// outputs -> 3.1x less LDS read traffic (the measured bottleneck).
// LDS tile col-major: per column 18 rows x 16 dwords (K0,K1,V0,V1), column
// stride 292 dwords (292%32==4 -> 8-lane b128 groups cover all 32 banks).
// Block: 128 threads (2 waves), covers 8 i-rows; 74.75KB LDS -> 2 blocks/CU.
// ---------------------------------------------------------------------------
__global__ __launch_bounds__(128) void k_attn(const _Float16* __restrict__ qws,
                                              const _Float16* __restrict__ kws,
                                              const _Float16* __restrict__ vws,
                                              const float* __restrict__ rpbl2,
                                              bf16* __restrict__ ows) {
    __shared__ unsigned ktv[64 * 292];
    const int tid  = threadIdx.x;
    const int bh   = blockIdx.x >> 3;
    const int i0   = (blockIdx.x & 7) << 3;
    const int head = bh & 7;
    int start_min = i0 - 5; if (start_min < 0) start_min = 0; if (start_min > 46) start_min = 46;
    const unsigned* ku = (const unsigned*)kws;
    const unsigned* vu = (const unsigned*)vws;
    const size_t gK = ((size_t)bh * 4096 + (size_t)start_min * 64) * 8;
    for (int idx = tid; idx < 4608; idx += 128) {
        int col = idx & 63, slot = (idx >> 6) & 3, row = idx >> 8;
        const unsigned* src = (slot < 2 ? ku : vu) + gK + (size_t)row * 512 + col * 8 + (slot & 1) * 4;
        *(uint4*)&ktv[col * 292 + row * 16 + slot * 4] = *(const uint4*)src;
    }
    __syncthreads();
    const int wv = tid >> 6;
    const int j  = tid & 63;
    const int ib = i0 + 4 * wv;
    int start_j = j - 5; if (start_j < 0) start_j = 0; if (start_j > 53) start_j = 53;
    v2h qh[4][8];
#pragma unroll
    for (int q = 0; q < 4; ++q) {
        const uint4* qp = (const uint4*)(qws + ((size_t)bh * 4096 + (ib + q) * 64 + j) * 16);
        uint4 q0 = qp[0], q1 = qp[1];
        qh[q][0] = u2h(q0.x); qh[q][1] = u2h(q0.y); qh[q][2] = u2h(q0.z); qh[q][3] = u2h(q0.w);
        qh[q][4] = u2h(q1.x); qh[q][5] = u2h(q1.y); qh[q][6] = u2h(q1.z); qh[q][7] = u2h(q1.w);
    }
    int st0 = ib - 5; if (st0 < 0) st0 = 0; if (st0 > 53) st0 = 53;
    int st3 = ib - 2; if (st3 < 0) st3 = 0; if (st3 > 53) st3 = 53;
    const int nr = st3 - st0 + 11;
    float l[4] = {0.f, 0.f, 0.f, 0.f};
    v2h acc[4][8];
#pragma unroll
    for (int q = 0; q < 4; ++q)
#pragma unroll
        for (int d = 0; d < 8; ++d) acc[q][d] = (v2h){(_Float16)0.f, (_Float16)0.f};
    const float* rpb_base = rpbl2 + head * 441 + (start_j - j + 10);
    const int lds_base = start_j * 292;
    for (int au = 0; au < nr; ++au) {
        const int a_abs = st0 + au;
        const int r16 = (a_abs - start_min) * 16;
        const float* rb[4];
        float pen[4];
#pragma unroll
        for (int q = 0; q < 4; ++q) {
            int iq = ib + q;
            int sq = iq - 5; if (sq < 0) sq = 0; if (sq > 53) sq = 53;
            int ri = a_abs - iq + 10;
            int ric = ri < 0 ? 0 : (ri > 20 ? 20 : ri);
            rb[q] = rpb_base + ric * 21;
            pen[q] = ((unsigned)(a_abs - sq) <= 10u) ? 0.f : -30000.f;
        }
#pragma unroll
        for (int c = 0; c < 11; ++c) {
            const unsigned* cp = &ktv[lds_base + c * 292 + r16];
            uint4 k0 = *(const uint4*)(cp);
            uint4 k1 = *(const uint4*)(cp + 4);
            uint4 v0 = *(const uint4*)(cp + 8);
            uint4 v1 = *(const uint4*)(cp + 12);
#pragma unroll
            for (int q = 0; q < 4; ++q) {
                float sa = __builtin_amdgcn_fdot2(qh[q][0], u2h(k0.x), rb[q][c] + pen[q], false);
                sa = __builtin_amdgcn_fdot2(qh[q][1], u2h(k0.y), sa, false);
                sa = __builtin_amdgcn_fdot2(qh[q][2], u2h(k0.z), sa, false);
                sa = __builtin_amdgcn_fdot2(qh[q][3], u2h(k0.w), sa, false);
                float sb = __builtin_amdgcn_fdot2(qh[q][4], u2h(k1.x), 0.f, false);
                sb = __builtin_amdgcn_fdot2(qh[q][5], u2h(k1.y), sb, false);
                sb = __builtin_amdgcn_fdot2(qh[q][6], u2h(k1.z), sb, false);
                sb = __builtin_amdgcn_fdot2(qh[q][7], u2h(k1.w), sb, false);
                float p = __builtin_amdgcn_exp2f(sa + sb);
                l[q] += p;
                _Float16 ph = (_Float16)p;
                v2h p2 = {ph, ph};
                acc[q][0] += u2h(v0.x) * p2;
                acc[q][1] += u2h(v0.y) * p2;
                acc[q][2] += u2h(v0.z) * p2;
                acc[q][3] += u2h(v0.w) * p2;
                acc[q][4] += u2h(v1.x) * p2;
                acc[q][5] += u2h(v1.y) * p2;
                acc[q][6] += u2h(v1.z) * p2;
                acc[q][7] += u2h(v1.w) * p2;
            }
        }
    }
    const int b = bh >> 3;
#pragma unroll
    for (int q = 0; q < 4; ++q) {
        float inv = 1.f / l[q];
        unsigned* op = (unsigned*)ows + ((size_t)b * 4096 + (ib + q) * 64 + j) * 64 + head * 8;
#pragma unroll
        for (int d2 = 0; d2 < 8; ++d2)
            op[d2] = pk2((float)acc[q][d2].x * inv, (float)acc[q][d2].y * inv);
    }
}

// ---------------------------------------------------------------------------
// Kernel 4 (MFMA): y = x + concat(o, x) @ proj_w + proj_b -> fp32 ws.
// ---------------------------------------------------------------------------
__global__ __launch_bounds__(256) void k_proj(const float* __restrict__ x,
                                              const bf16* __restrict__ ows,
                                              const bf16* __restrict__ pwf,
                                              const float* __restrict__ pb,
                                              float* __restrict__ yws) {
    __shared__ short An[32][264];
    const int t = threadIdx.x;
    const size_t row0 = (size_t)blockIdx.x * 32;
    {
        const int r = t >> 3, li = t & 7;
        const uint4* osrc = (const uint4*)(ows + (row0 + r) * 128 + li * 16);
        uint4 o0 = osrc[0], o1 = osrc[1];
        *(uint4*)&An[r][li * 16]     = o0;
        *(uint4*)&An[r][li * 16 + 8] = o1;
        const float* xr = x + (row0 + r) * 128 + li * 16;
        v8s xa, xb;
#pragma unroll
        for (int k4 = 0; k4 < 2; ++k4) {
            float4 vv = *(const float4*)(xr + 4 * k4);
            xa[4 * k4 + 0] = f2bs(vv.x); xa[4 * k4 + 1] = f2bs(vv.y);
            xa[4 * k4 + 2] = f2bs(vv.z); xa[4 * k4 + 3] = f2bs(vv.w);
        }
#pragma unroll
        for (int k4 = 0; k4 < 2; ++k4) {
            float4 vv = *(const float4*)(xr + 8 + 4 * k4);
            xb[4 * k4 + 0] = f2bs(vv.x); xb[4 * k4 + 1] = f2bs(vv.y);
            xb[4 * k4 + 2] = f2bs(vv.z); xb[4 * k4 + 3] = f2bs(vv.w);
        }
        *(v8s*)&An[r][128 + li * 16]     = xa;
        *(v8s*)&An[r][128 + li * 16 + 8] = xb;
    }
    __syncthreads();
    const int lane = t & 63, wv = t >> 6;
    const int m = lane & 15, quad = lane >> 4;
    const int ntb = wv * 2;
    v4f acc[2][2];
#pragma unroll
    for (int a = 0; a < 2; ++a)
#pragma unroll
        for (int b = 0; b < 2; ++b) acc[a][b] = (v4f){0.f, 0.f, 0.f, 0.f};
#pragma unroll
    for (int ks = 0; ks < 8; ++ks) {
        v8s a0 = *(const v8s*)&An[m][ks * 32 + quad * 8];
        v8s a1 = *(const v8s*)&An[m + 16][ks * 32 + quad * 8];
        const v8s* bp = (const v8s*)pwf + ((size_t)ks * 8 + ntb) * 64 + lane;
#pragma unroll
        for (int nt = 0; nt < 2; ++nt) {
            v8s b = bp[nt * 64];
            acc[0][nt] = __builtin_amdgcn_mfma_f32_16x16x32_bf16(a0, b, acc[0][nt], 0, 0, 0);
            acc[1][nt] = __builtin_amdgcn_mfma_f32_16x16x32_bf16(a1, b, acc[1][nt], 0, 0, 0);
        }
    }
#pragma unroll
    for (int nt = 0; nt < 2; ++nt) {
        int n = (ntb + nt) * 16 + m;
        float bv = pb[n];
#pragma unroll
        for (int mt = 0; mt < 2; ++mt)
#pragma unroll
            for (int rg = 0; rg < 4; ++rg) {
                int row = mt * 16 + quad * 4 + rg;
                size_t gi = (row0 + row) * 128 + n;
                yws[gi] = x[gi] + bv + acc[mt][nt][rg];
            }
    }
}

// ---------------------------------------------------------------------------
// Kernel 5 (MFMA): ffn = gelu(LN(y)@f1+b1)@f2+b2; out = y + ffn.
// ---------------------------------------------------------------------------
__global__ __launch_bounds__(256) void k_ffn(const float* __restrict__ yws,
                                             const float* __restrict__ g, const float* __restrict__ bb,
                                             const bf16* __restrict__ w1f, const float* __restrict__ b1,
                                             const bf16* __restrict__ w2f, const float* __restrict__ b2,
                                             float* __restrict__ outp) {
    __shared__ short An[32][136];
    __shared__ short Hs[32][520];
    const int t = threadIdx.x;
    const size_t row0 = (size_t)blockIdx.x * 32;
    {
        const int r = t >> 3, li = t & 7;
        const float* yr = yws + (row0 + r) * 128 + li * 16;
        float v[16];
        float s1 = 0.f, s2 = 0.f;
#pragma unroll
        for (int k4 = 0; k4 < 4; ++k4) {
            float4 vv = *(const float4*)(yr + 4 * k4);
            v[4 * k4 + 0] = vv.x; v[4 * k4 + 1] = vv.y; v[4 * k4 + 2] = vv.z; v[4 * k4 + 3] = vv.w;
            s1 += vv.x + vv.y + vv.z + vv.w;
            s2 += vv.x * vv.x + vv.y * vv.y + vv.z * vv.z + vv.w * vv.w;
        }
#pragma unroll
        for (int o = 1; o < 8; o <<= 1) { s1 += __shfl_xor(s1, o); s2 += __shfl_xor(s2, o); }
        float mu = s1 * (1.f / 128.f);
        float rs = rsqrtf(s2 * (1.f / 128.f) - mu * mu + 1e-5f);
        v8s lo, hi;
#pragma unroll
        for (int k = 0; k < 8; ++k) {
            int c = li * 16 + k;
            lo[k] = f2bs((v[k] - mu) * rs * g[c] + bb[c]);
        }
#pragma unroll
        for (int k = 0; k < 8; ++k) {
            int c = li * 16 + 8 + k;
            hi[k] = f2bs((v[8 + k] - mu) * rs * g[c] + bb[c]);
        }
        *(v8s*)&An[r][li * 16]     = lo;
        *(v8s*)&An[r][li * 16 + 8] = hi;
    }
    __syncthreads();
    const int lane = t & 63, wv = t >> 6;
    const int m = lane & 15, quad = lane >> 4;
    v4f acc1[2][8];
#pragma unroll
    for (int a = 0; a < 2; ++a)
#pragma unroll
        for (int b = 0; b < 8; ++b) acc1[a][b] = (v4f){0.f, 0.f, 0.f, 0.f};
    const int n0w = wv * 128;
#pragma unroll
    for (int ks = 0; ks < 4; ++ks) {
        v8s a0 = *(const v8s*)&An[m][ks * 32 + quad * 8];
        v8s a1 = *(const v8s*)&An[m + 16][ks * 32 + quad * 8];
        const v8s* bp = (const v8s*)w1f + ((size_t)ks * 32 + (n0w >> 4)) * 64 + lane;
#pragma unroll
        for (int nt = 0; nt < 8; ++nt) {
            v8s b = bp[nt * 64];
            acc1[0][nt] = __builtin_amdgcn_mfma_f32_16x16x32_bf16(a0, b, acc1[0][nt], 0, 0, 0);
            acc1[1][nt] = __builtin_amdgcn_mfma_f32_16x16x32_bf16(a1, b, acc1[1][nt], 0, 0, 0);
        }
    }
#pragma unroll
    for (int nt = 0; nt < 8; ++nt) {
        int n = n0w + nt * 16 + m;
        float b1v = b1[n];
#pragma unroll
        for (int mt = 0; mt < 2; ++mt)
#pragma unroll
            for (int rg = 0; rg < 4; ++rg)
                Hs[mt * 16 + quad * 4 + rg][n] = f2bs(gelu_exact(acc1[mt][nt][rg] + b1v));
    }
    __syncthreads();
    v4f acc2[2][2];
#pragma unroll
    for (int a = 0; a < 2; ++a)
#pragma unroll
        for (int b = 0; b < 2; ++b) acc2[a][b] = (v4f){0.f, 0.f, 0.f, 0.f};
    const int ntb = wv * 2;
#pragma unroll
    for (int ks = 0; ks < 16; ++ks) {
        v8s a0 = *(const v8s*)&Hs[m][ks * 32 + quad * 8];
        v8s a1 = *(const v8s*)&Hs[m + 16][ks * 32 + quad * 8];
        const v8s* bp = (const v8s*)w2f + ((size_t)ks * 8 + ntb) * 64 + lane;
#pragma unroll
        for (int nt = 0; nt < 2; ++nt) {
            v8s b = bp[nt * 64];
            acc2[0][nt] = __builtin_amdgcn_mfma_f32_16x16x32_bf16(a0, b, acc2[0][nt], 0, 0, 0);
            acc2[1][nt] = __builtin_amdgcn_mfma_f32_16x16x32_bf16(a1, b, acc2[1][nt], 0, 0, 0);
        }
    }
#pragma unroll
    for (int nt = 0; nt < 2; ++nt) {
        int n = (ntb + nt) * 16 + m;
        float b2v = b2[n];
#pragma unroll
        for (int mt = 0; mt < 2; ++mt)
#pragma unroll
            for (int rg = 0; rg < 4; ++rg) {
                int row = mt * 16 + quad * 4 + rg;
                size_t gi = (row0 + row) * 128 + n;
                outp[gi] = yws[gi] + b2v + acc2[mt][nt][rg];
            }
    }
}

extern "C" void kernel_launch(void* const* d_in, const int* in_sizes, int n_in,
                              void* d_out, int out_size, void* d_ws, size_t ws_size,
                              hipStream_t stream) {
    const float* x      = (const float*)d_in[0];
    const float* ctx    = (const float*)d_in[1];
    const float* ctxn_g = (const float*)d_in[2];
    const float* ctxn_b = (const float*)d_in[3];
    const float* ctxp_w = (const float*)d_in[4];
    const float* ctxp_b = (const float*)d_in[5];
    const float* n1_g   = (const float*)d_in[6];
    const float* n1_b   = (const float*)d_in[7];
    const float* n1v_g  = (const float*)d_in[8];
    const float* n1v_b  = (const float*)d_in[9];
    const float* q_w    = (const float*)d_in[10];
    const float* q_b    = (const float*)d_in[11];
    const float* k_w    = (const float*)d_in[12];
    const float* k_b    = (const float*)d_in[13];
    const float* v_w    = (const float*)d_in[14];
    const float* v_b    = (const float*)d_in[15];
    const float* rpb    = (const float*)d_in[16];
    const float* proj_w = (const float*)d_in[17];
    const float* proj_b = (const float*)d_in[18];
    const float* n2_g   = (const float*)d_in[19];
    const float* n2_b   = (const float*)d_in[20];
    const float* f1_w   = (const float*)d_in[21];
    const float* f1_b   = (const float*)d_in[22];
    const float* f2_w   = (const float*)d_in[23];
    const float* f2_b   = (const float*)d_in[24];
    float* out = (float*)d_out;

    char* ws = (char*)d_ws;
    bf16*      ctxp = (bf16*)(ws);                 //  8,388,608 B  (B,HW,64) bf16
    _Float16*  qws  = (_Float16*)(ws + 8388608);   // 16,777,216 B  (B,8,HW,16) f16
    _Float16*  kws  = (_Float16*)(ws + 25165824);  // 16,777,216 B
    _Float16*  vws  = (_Float16*)(ws + 41943040);  // 16,777,216 B
    bf16*      ows  = (bf16*)(ws + 58720256);      // 16,777,216 B  (B,HW,128) bf16
    float*     yws  = (float*)(ws + 8388608);      // aliases qws+kws (dead after attn)
    char* frag = ws + 75497472;
    bf16*  w1f  = (bf16*)(frag);                   // 131,072 B
    bf16*  w2f  = (bf16*)(frag + 131072);          // 131,072 B
    bf16*  qwf  = (bf16*)(frag + 262144);          //  49,152 B
    bf16*  kwf  = (bf16*)(frag + 311296);          //  49,152 B
    bf16*  vwf  = (bf16*)(frag + 360448);          //  32,768 B
    bf16*  pwf  = (bf16*)(frag + 393216);          //  65,536 B
    float* rpl2 = (float*)(frag + 458752);         //  14,112 B (8*441 fp32)
    // ctx-GEMM prep lives in the qws region: it is fully consumed by k_ctx,
    // which completes (stream-ordered) before k_qkv writes qws.
    bf16*  wgf  = (bf16*)(ws + 8388608);           //  32,768 B  g.W fragments (K=256,N=64)
    float* cgw  = (float*)(ws + 8388608 + 32768);  //     256 B  sum_e g*W
    float* cbw  = (float*)(ws + 8388608 + 33024);  //     256 B  sum_e b*W + pb

    k_repack<<<256, 256, 0, stream>>>(f1_w, w1f, 128, 512);
    k_repack<<<256, 256, 0, stream>>>(f2_w, w2f, 512, 128);
    k_repack<<<96,  256, 0, stream>>>(q_w,  qwf, 192, 128);
    k_repack<<<96,  256, 0, stream>>>(k_w,  kwf, 192, 128);
    k_repack<<<64,  256, 0, stream>>>(v_w,  vwf, 128, 128);
    k_repack<<<128, 256, 0, stream>>>(proj_w, pwf, 256, 128);
    k_repack_g<<<64, 256, 0, stream>>>(ctxp_w, ctxn_g, wgf, 256, 64);
    k_ctxc<<<1, 256, 0, stream>>>(ctxp_w, ctxn_g, ctxn_b, ctxp_b, cgw, cbw);
    k_rpb<<<14, 256, 0, stream>>>(rpb, rpl2, 8 * 441);
    k_ctx<<<2048, 256, 0, stream>>>(ctx, cgw, cbw, wgf, ctxp);
    k_qkv<<<2048, 256, 0, stream>>>(x, ctxp, n1_g, n1_b, n1v_g, n1v_b,
                                    qwf, q_b, kwf, k_b, vwf, v_b, qws, kws, vws);
    k_attn<<<1024, 128, 0, stream>>>(qws, kws, vws, rpl2, ows);
    k_proj<<<2048, 256, 0, stream>>>(x, ows, pwf, proj_b, yws);
    k_ffn<<<2048, 256, 0, stream>>>(yws, n2_g, n2_b, w1f, f1_b, w2f, f2_b, out);
}

// Round 3
// 400.225 us; speedup vs baseline: 1.0528x; 1.0528x over previous
//
#include <hip/hip_runtime.h>
#include <hip/hip_bf16.h>
#include <math.h>

typedef __hip_bfloat16 bf16;
typedef float v2f __attribute__((ext_vector_type(2)));
typedef float v4f __attribute__((ext_vector_type(4)));
typedef short v8s __attribute__((ext_vector_type(8)));
typedef _Float16 v2h __attribute__((ext_vector_type(2)));

__device__ __forceinline__ float b2f(bf16 v) { return __bfloat162float(v); }
__device__ __forceinline__ float unpk_lo(unsigned u) { return __uint_as_float(u << 16); }
__device__ __forceinline__ float unpk_hi(unsigned u) { return __uint_as_float(u & 0xffff0000u); }
__device__ __forceinline__ v2f unpk2(unsigned u) {
    v2f r; r.x = __uint_as_float(u << 16); r.y = __uint_as_float(u & 0xffff0000u); return r;
}
__device__ __forceinline__ unsigned pk2(float a, float b) {
    unsigned ua = __float_as_uint(a);
    unsigned ub = __float_as_uint(b);
    ua = (ua + 0x7fffu + ((ua >> 16) & 1u)) >> 16;   // RNE to bf16
    ub = (ub + 0x7fffu + ((ub >> 16) & 1u)) >> 16;
    return ua | (ub << 16);
}
__device__ __forceinline__ short f2bs(float f) {
    unsigned u = __float_as_uint(f);
    u = (u + 0x7fffu + ((u >> 16) & 1u)) >> 16;
    return (short)u;
}
__device__ __forceinline__ v2h u2h(unsigned u) {
    union { unsigned u; v2h h; } c; c.u = u; return c.h;
}
__device__ __forceinline__ float gelu_exact(float x) {
    return 0.5f * x * (1.f + erff(x * 0.70710678118654752440f));
}

#define LOG2E 1.44269504088896340736f

// ---------------------------------------------------------------------------
// Repack a KxN fp32 weight into bf16 MFMA B-fragments for 16x16x32.
// ---------------------------------------------------------------------------
__global__ __launch_bounds__(256) void k_repack(const float* __restrict__ src,
                                                bf16* __restrict__ dst, int K, int N) {
    int idx = blockIdx.x * 256 + threadIdx.x;
    if (idx >= K * N) return;
    int k = idx / N, n = idx % N;
    int kstep = k >> 5, quad = (k & 31) >> 3, j = k & 7;
    int ntile = n >> 4, nn = n & 15;
    size_t di = ((((size_t)kstep * (N >> 4)) + ntile) * 64 + nn + (quad << 4)) * 8 + j;
    dst[di] = __float2bfloat16(src[idx]);
}

// Same repack but scales row k by g[k] (folds the LN gain into the weight).
__global__ __launch_bounds__(256) void k_repack_g(const float* __restrict__ src,
                                                  const float* __restrict__ g,
                                                  bf16* __restrict__ dst, int K, int N) {
    int idx = blockIdx.x * 256 + threadIdx.x;
    if (idx >= K * N) return;
    int k = idx / N, n = idx % N;
    int kstep = k >> 5, quad = (k & 31) >> 3, j = k & 7;
    int ntile = n >> 4, nn = n & 15;
    size_t di = ((((size_t)kstep * (N >> 4)) + ntile) * 64 + nn + (quad << 4)) * 8 + j;
    dst[di] = __float2bfloat16(src[idx] * g[k]);
}

// LN-fold correction vectors for the ctx projection (K=256, N=64):
//   cgw[n] = sum_e g[e] * W[e][n]
//   cbw[n] = sum_e b[e] * W[e][n] + pb[n]
__global__ __launch_bounds__(256) void k_ctxc(const float* __restrict__ w,
                                              const float* __restrict__ g,
                                              const float* __restrict__ bb,
                                              const float* __restrict__ pb,
                                              float* __restrict__ cgw,
                                              float* __restrict__ cbw) {
    __shared__ float rg_[4][64], rb_[4][64];
    const int n = threadIdx.x & 63, eg = threadIdx.x >> 6;
    float sg = 0.f, sb = 0.f;
    for (int e = eg * 64; e < eg * 64 + 64; ++e) {
        float wv = w[e * 64 + n];
        sg += g[e] * wv;
        sb += bb[e] * wv;
    }
    rg_[eg][n] = sg; rb_[eg][n] = sb;
    __syncthreads();
    if (threadIdx.x < 64) {
        float a = rg_[0][n] + rg_[1][n] + rg_[2][n] + rg_[3][n];
        float c = rb_[0][n] + rb_[1][n] + rb_[2][n] + rb_[3][n];
        cgw[n] = a;
        cbw[n] = c + pb[n];
    }
}

// rpb -> log2e*rpb - 8  (the -8 cancels in softmax normalization; keeps
// unnormalized f16 PV accumulation far from overflow)
__global__ __launch_bounds__(256) void k_rpb(const float* __restrict__ src,
                                             float* __restrict__ dst, int n) {
    int i = blockIdx.x * 256 + threadIdx.x;
    if (i < n) dst[i] = src[i] * LOG2E - 8.0f;
}

// ---------------------------------------------------------------------------
// Kernel 1 (MFMA): ctx projection. A = raw ctx (transposed, bf16), B = g.W
// fragments; LN folded into epilogue:
//   out[r][n] = rs_r*(acc - mu_r*cgw[n]) + cbw[n]
// Block: 32 hw rows x 256 e, 4 waves each own one 16-col ntile of N=64.
// ---------------------------------------------------------------------------
__global__ __launch_bounds__(256) void k_ctx(const float* __restrict__ ctx,
                                             const float* __restrict__ cgw,
                                             const float* __restrict__ cbw,
                                             const bf16* __restrict__ wgf,
                                             bf16* __restrict__ outp) {
    __shared__ short As[32][264];
    __shared__ float redS[8][32];
    __shared__ float redQ[8][32];
    __shared__ float smu[32], srs[32];
    const int t = threadIdx.x;
    const int b = blockIdx.x >> 7;
    const int hw0 = (blockIdx.x & 127) << 5;
    {
        // lanes 0..31 of each wave read 32 contiguous hw floats (128B segments);
        // thread t owns row r = t&31, e-slice li*32..li*32+31 (li = t>>5).
        const int r = t & 31, li = t >> 5;
        const float* src = ctx + ((size_t)b * 256 + li * 32) * 4096 + hw0 + r;
        float v[32];
        float s = 0.f, q = 0.f;
#pragma unroll
        for (int j = 0; j < 32; ++j) {
            float x = src[(size_t)j * 4096];
            v[j] = x; s += x; q += x * x;
        }
        redS[li][r] = s;
        redQ[li][r] = q;
        v8s p0, p1, p2, p3;
#pragma unroll
        for (int j = 0; j < 8; ++j) p0[j] = f2bs(v[j]);
#pragma unroll
        for (int j = 0; j < 8; ++j) p1[j] = f2bs(v[8 + j]);
#pragma unroll
        for (int j = 0; j < 8; ++j) p2[j] = f2bs(v[16 + j]);
#pragma unroll
        for (int j = 0; j < 8; ++j) p3[j] = f2bs(v[24 + j]);
        v8s* dst = (v8s*)&As[r][li * 32];
        dst[0] = p0; dst[1] = p1; dst[2] = p2; dst[3] = p3;
    }
    __syncthreads();
    if (t < 32) {
        float s = 0.f, q = 0.f;
#pragma unroll
        for (int k = 0; k < 8; ++k) { s += redS[k][t]; q += redQ[k][t]; }
        float mu = s * (1.f / 256.f);
        float var = q * (1.f / 256.f) - mu * mu;
        smu[t] = mu;
        srs[t] = rsqrtf(var + 1e-5f);
    }
    __syncthreads();
    const int lane = t & 63, wv = t >> 6;
    const int m = lane & 15, quad = lane >> 4;
    v4f acc0 = (v4f){0.f, 0.f, 0.f, 0.f};
    v4f acc1 = (v4f){0.f, 0.f, 0.f, 0.f};
#pragma unroll
    for (int ks = 0; ks < 8; ++ks) {
        v8s a0 = *(const v8s*)&As[m][ks * 32 + quad * 8];
        v8s a1 = *(const v8s*)&As[m + 16][ks * 32 + quad * 8];
        v8s bfr = ((const v8s*)wgf)[((size_t)ks * 4 + wv) * 64 + lane];
        acc0 = __builtin_amdgcn_mfma_f32_16x16x32_bf16(a0, bfr, acc0, 0, 0, 0);
        acc1 = __builtin_amdgcn_mfma_f32_16x16x32_bf16(a1, bfr, acc1, 0, 0, 0);
    }
    const int n = wv * 16 + m;
    const float cg = cgw[n], cb = cbw[n];
    short* obase = (short*)outp + ((size_t)b * 4096 + hw0) * 64 + n;
#pragma unroll
    for (int rg = 0; rg < 4; ++rg) {
        int row = quad * 4 + rg;
        float o = srs[row] * (acc0[rg] - smu[row] * cg) + cb;
        obase[(size_t)row * 64] = f2bs(o);
    }
#pragma unroll
    for (int rg = 0; rg < 4; ++rg) {
        int row = 16 + quad * 4 + rg;
        float o = srs[row] * (acc1[rg] - smu[row] * cg) + cb;
        obase[(size_t)row * 64] = f2bs(o);
    }
}

// ---------------------------------------------------------------------------
// Kernel 2 (MFMA): LN(concat(x,ctx),192) -> q,k ; LN(x,128) -> v.
// q/k/v written as f16 (q folded with 0.25*log2e for exp2-softmax).
// ---------------------------------------------------------------------------
__global__ __launch_bounds__(256) void k_qkv(const float* __restrict__ x,
                                             const bf16* __restrict__ ctxp,
                                             const float* __restrict__ n1g, const float* __restrict__ n1b,
                                             const float* __restrict__ nvg, const float* __restrict__ nvb,
                                             const bf16* __restrict__ qwf, const float* __restrict__ qb,
                                             const bf16* __restrict__ kwf, const float* __restrict__ kb,
                                             const bf16* __restrict__ vwf, const float* __restrict__ vb,
                                             _Float16* __restrict__ qo, _Float16* __restrict__ ko,
                                             _Float16* __restrict__ vo) {
    __shared__ short Aqk[32][200];
    __shared__ short Av[32][136];
    const int t = threadIdx.x;
    const size_t row0 = (size_t)blockIdx.x * 32;
    {
        const int r = t >> 3, li = t & 7;
        const float* xr = x + (row0 + r) * 128 + li * 16;
        float v[16];
        float sx1 = 0.f, sx2 = 0.f;
#pragma unroll
        for (int k4 = 0; k4 < 4; ++k4) {
            float4 vv = *(const float4*)(xr + 4 * k4);
            v[4 * k4 + 0] = vv.x; v[4 * k4 + 1] = vv.y; v[4 * k4 + 2] = vv.z; v[4 * k4 + 3] = vv.w;
            sx1 += vv.x + vv.y + vv.z + vv.w;
            sx2 += vv.x * vv.x + vv.y * vv.y + vv.z * vv.z + vv.w * vv.w;
        }
        float cv[8];
        float sc1 = 0.f, sc2 = 0.f;
        {
            uint4 cu = *(const uint4*)(ctxp + (row0 + r) * 64 + li * 8);
            v2f p0 = unpk2(cu.x), p1 = unpk2(cu.y), p2 = unpk2(cu.z), p3 = unpk2(cu.w);
            cv[0] = p0.x; cv[1] = p0.y; cv[2] = p1.x; cv[3] = p1.y;
            cv[4] = p2.x; cv[5] = p2.y; cv[6] = p3.x; cv[7] = p3.y;
#pragma unroll
            for (int k = 0; k < 8; ++k) { sc1 += cv[k]; sc2 += cv[k] * cv[k]; }
        }
#pragma unroll
        for (int o = 1; o < 8; o <<= 1) {
            sx1 += __shfl_xor(sx1, o); sx2 += __shfl_xor(sx2, o);
            sc1 += __shfl_xor(sc1, o); sc2 += __shfl_xor(sc2, o);
        }
        float mu  = (sx1 + sc1) * (1.f / 192.f);
        float rs  = rsqrtf((sx2 + sc2) * (1.f / 192.f) - mu * mu + 1e-5f);
        float muv = sx1 * (1.f / 128.f);
        float rsv = rsqrtf(sx2 * (1.f / 128.f) - muv * muv + 1e-5f);
        v8s q0, q1, vv0, vv1, cc;
#pragma unroll
        for (int k = 0; k < 8; ++k) {
            int c = li * 16 + k;
            q0[k]  = f2bs((v[k] - mu) * rs * n1g[c] + n1b[c]);
            vv0[k] = f2bs((v[k] - muv) * rsv * nvg[c] + nvb[c]);
        }
#pragma unroll
        for (int k = 0; k < 8; ++k) {
            int c = li * 16 + 8 + k;
            q1[k]  = f2bs((v[8 + k] - mu) * rs * n1g[c] + n1b[c]);
            vv1[k] = f2bs((v[8 + k] - muv) * rsv * nvg[c] + nvb[c]);
        }
#pragma unroll
        for (int k = 0; k < 8; ++k) {
            int c = 128 + li * 8 + k;
            cc[k] = f2bs((cv[k] - mu) * rs * n1g[c] + n1b[c]);
        }
        *(v8s*)&Aqk[r][li * 16]     = q0;
        *(v8s*)&Aqk[r][li * 16 + 8] = q1;
        *(v8s*)&Aqk[r][128 + li * 8] = cc;
        *(v8s*)&Av[r][li * 16]     = vv0;
        *(v8s*)&Av[r][li * 16 + 8] = vv1;
    }
    __syncthreads();
    const int lane = t & 63, wv = t >> 6;
    const int m = lane & 15, quad = lane >> 4;
    const int ntb = wv * 2;
    v4f aq[2][2], ak[2][2], av[2][2];
#pragma unroll
    for (int a = 0; a < 2; ++a)
#pragma unroll
        for (int b = 0; b < 2; ++b) {
            aq[a][b] = (v4f){0.f, 0.f, 0.f, 0.f};
            ak[a][b] = (v4f){0.f, 0.f, 0.f, 0.f};
            av[a][b] = (v4f){0.f, 0.f, 0.f, 0.f};
        }
#pragma unroll
    for (int ks = 0; ks < 6; ++ks) {
        v8s a0 = *(const v8s*)&Aqk[m][ks * 32 + quad * 8];
        v8s a1 = *(const v8s*)&Aqk[m + 16][ks * 32 + quad * 8];
        const v8s* bpq = (const v8s*)qwf + ((size_t)ks * 8 + ntb) * 64 + lane;
        const v8s* bpk = (const v8s*)kwf + ((size_t)ks * 8 + ntb) * 64 + lane;
#pragma unroll
        for (int nt = 0; nt < 2; ++nt) {
            v8s bq = bpq[nt * 64];
            v8s bk = bpk[nt * 64];
            aq[0][nt] = __builtin_amdgcn_mfma_f32_16x16x32_bf16(a0, bq, aq[0][nt], 0, 0, 0);
            aq[1][nt] = __builtin_amdgcn_mfma_f32_16x16x32_bf16(a1, bq, aq[1][nt], 0, 0, 0);
            ak[0][nt] = __builtin_amdgcn_mfma_f32_16x16x32_bf16(a0, bk, ak[0][nt], 0, 0, 0);
            ak[1][nt] = __builtin_amdgcn_mfma_f32_16x16x32_bf16(a1, bk, ak[1][nt], 0, 0, 0);
        }
    }
#pragma unroll
    for (int ks = 0; ks < 4; ++ks) {
        v8s a0 = *(const v8s*)&Av[m][ks * 32 + quad * 8];
        v8s a1 = *(const v8s*)&Av[m + 16][ks * 32 + quad * 8];
        const v8s* bpv = (const v8s*)vwf + ((size_t)ks * 8 + ntb) * 64 + lane;
#pragma unroll
        for (int nt = 0; nt < 2; ++nt) {
            v8s bv = bpv[nt * 64];
            av[0][nt] = __builtin_amdgcn_mfma_f32_16x16x32_bf16(a0, bv, av[0][nt], 0, 0, 0);
            av[1][nt] = __builtin_amdgcn_mfma_f32_16x16x32_bf16(a1, bv, av[1][nt], 0, 0, 0);
        }
    }
#pragma unroll
    for (int nt = 0; nt < 2; ++nt) {
        int n = (ntb + nt) * 16 + m;
        int head = n >> 4, d = n & 15;
        float qbv = qb[n], kbv = kb[n], vbv = vb[n];
#pragma unroll
        for (int mt = 0; mt < 2; ++mt)
#pragma unroll
            for (int rg = 0; rg < 4; ++rg) {
                int rowg = (int)row0 + mt * 16 + quad * 4 + rg;
                int b = rowg >> 12, hw = rowg & 4095;
                size_t oi = (((size_t)b * 8 + head) * 4096 + hw) * 16 + d;
                qo[oi] = (_Float16)((aq[mt][nt][rg] + qbv) * (0.25f * LOG2E));
                ko[oi] = (_Float16)(ak[mt][nt][rg] + kbv);
                vo[oi] = (_Float16)(av[mt][nt][rg] + vbv);
            }
    }
}

// ---------------------------------------------------------------------------
// Kernel 3: neighborhood attention, f16 + v_dot2 + pk_fma_f16.
// 2 query rows per thread: one K/V LDS read feeds 2 outputs (1.83x less LDS
// read traffic than 1q) while keeping 256-thread blocks -> 4 waves/block,
// 2 blocks/CU = 8 waves/CU = 2 waves/SIMD (the r2 4q version collapsed to
// 1 wave/SIMD and went latency-bound).
// LDS tile col-major: per column 18 rows x 16 dwords (K0,K1,V0,V1), column
// stride 292 dwords (292%32==4 -> 8-lane b128 groups cover all 32 banks).
// Block: 256 threads (4 waves), covers 8 i-rows; 74.75KB LDS.
// ---------------------------------------------------------------------------
__global__ __launch_bounds__(256) void k_attn(const _Float16* __restrict__ qws,
                                              const _Float16* __restrict__ kws,
                                              const _Float16* __restrict__ vws,
                                              const float* __restrict__ rpbl2,
                                              bf16* __restrict__ ows) {
    __shared__ unsigned ktv[64 * 292];
    const int tid  = threadIdx.x;
    const int bh   = blockIdx.x >> 3;
    const int i0   = (blockIdx.x & 7) << 3;
    const int head = bh & 7;
    int start_min = i0 - 5; if (start_min < 0) start_min = 0; if (start_min > 46) start_min = 46;
    const unsigned* ku = (const unsigned*)kws;
    const unsigned* vu = (const unsigned*)vws;
    const size_t gK = ((size_t)bh * 4096 + (size_t)start_min * 64) * 8;
    for (int idx = tid; idx < 4608; idx += 256) {
        int col = idx & 63, slot = (idx >> 6) & 3, row = idx >> 8;
        const unsigned* src = (slot < 2 ? ku : vu) + gK + (size_t)row * 512 + col * 8 + (slot & 1) * 4;
        *(uint4*)&ktv[col * 292 + row * 16 + slot * 4] = *(const uint4*)src;
    }
    __syncthreads();
    const int wv = tid >> 6;
    const int j  = tid & 63;
    const int ib = i0 + 2 * wv;           // wave owns query rows ib, ib+1
    int start_j = j - 5; if (start_j < 0) start_j = 0; if (start_j > 53) start_j = 53;
    v2h qh[2][8];
#pragma unroll
    for (int q = 0; q < 2; ++q) {
        const uint4* qp = (const uint4*)(qws + ((size_t)bh * 4096 + (ib + q) * 64 + j) * 16);
        uint4 q0 = qp[0], q1 = qp[1];
        qh[q][0] = u2h(q0.x); qh[q][1] = u2h(q0.y); qh[q][2] = u2h(q0.z); qh[q][3] = u2h(q0.w);
        qh[q][4] = u2h(q1.x); qh[q][5] = u2h(q1.y); qh[q][6] = u2h(q1.z); qh[q][7] = u2h(q1.w);
    }
    int st0 = ib - 5; if (st0 < 0) st0 = 0; if (st0 > 53) st0 = 53;
    int st1 = ib - 4; if (st1 < 0) st1 = 0; if (st1 > 53) st1 = 53;
    const int nr = st1 - st0 + 11;        // 11 or 12
    float l[2] = {0.f, 0.f};
    v2h acc[2][8];
#pragma unroll
    for (int q = 0; q < 2; ++q)
#pragma unroll
        for (int d = 0; d < 8; ++d) acc[q][d] = (v2h){(_Float16)0.f, (_Float16)0.f};
    const float* rpb_base = rpbl2 + head * 441 + (start_j - j + 10);
    const int lds_base = start_j * 292;
    for (int au = 0; au < nr; ++au) {
        const int a_abs = st0 + au;
        const int r16 = (a_abs - start_min) * 16;
        const float* rb[2];
        float pen[2];
#pragma unroll
        for (int q = 0; q < 2; ++q) {
            int iq = ib + q;
            int sq = iq - 5; if (sq < 0) sq = 0; if (sq > 53) sq = 53;
            int ri = a_abs - iq + 10;
            int ric = ri < 0 ? 0 : (ri > 20 ? 20 : ri);
            rb[q] = rpb_base + ric * 21;
            pen[q] = ((unsigned)(a_abs - sq) <= 10u) ? 0.f : -30000.f;
        }
#pragma unroll
        for (int c = 0; c < 11; ++c) {
            const unsigned* cp = &ktv[lds_base + c * 292 + r16];
            uint4 k0 = *(const uint4*)(cp);
            uint4 k1 = *(const uint4*)(cp + 4);
            uint4 v0 = *(const uint4*)(cp + 8);
            uint4 v1 = *(const uint4*)(cp + 12);
#pragma unroll
            for (int q = 0; q < 2; ++q) {
                float sa = __builtin_amdgcn_fdot2(qh[q][0], u2h(k0.x), rb[q][c] + pen[q], false);
                sa = __builtin_amdgcn_fdot2(qh[q][1], u2h(k0.y), sa, false);
                sa = __builtin_amdgcn_fdot2(qh[q][2], u2h(k0.z), sa, false);
                sa = __builtin_amdgcn_fdot2(qh[q][3], u2h(k0.w), sa, false);
                float sb = __builtin_amdgcn_fdot2(qh[q][4], u2h(k1.x), 0.f, false);
                sb = __builtin_amdgcn_fdot2(qh[q][5], u2h(k1.y), sb, false);
                sb = __builtin_amdgcn_fdot2(qh[q][6], u2h(k1.z), sb, false);
                sb = __builtin_amdgcn_fdot2(qh[q][7], u2h(k1.w), sb, false);
                float p = __builtin_amdgcn_exp2f(sa + sb);
                l[q] += p;
                _Float16 ph = (_Float16)p;
                v2h p2 = {ph, ph};
                acc[q][0] += u2h(v0.x) * p2;
                acc[q][1] += u2h(v0.y) * p2;
                acc[q][2] += u2h(v0.z) * p2;
                acc[q][3] += u2h(v0.w) * p2;
                acc[q][4] += u2h(v1.x) * p2;
                acc[q][5] += u2h(v1.y) * p2;
                acc[q][6] += u2h(v1.z) * p2;
                acc[q][7] += u2h(v1.w) * p2;
            }
        }
    }
    const int b = bh >> 3;
#pragma unroll
    for (int q = 0; q < 2; ++q) {
        float inv = 1.f / l[q];
        unsigned* op = (unsigned*)ows + ((size_t)b * 4096 + (ib + q) * 64 + j) * 64 + head * 8;
#pragma unroll
        for (int d2 = 0; d2 < 8; ++d2)
            op[d2] = pk2((float)acc[q][d2].x * inv, (float)acc[q][d2].y * inv);
    }
}

// ---------------------------------------------------------------------------
// Kernel 4 (MFMA): y = x + concat(o, x) @ proj_w + proj_b -> fp32 ws.
// ---------------------------------------------------------------------------
__global__ __launch_bounds__(256) void k_proj(const float* __restrict__ x,
                                              const bf16* __restrict__ ows,
                                              const bf16* __restrict__ pwf,
                                              const float* __restrict__ pb,
                                              float* __restrict__ yws) {
    __shared__ short An[32][264];
    const int t = threadIdx.x;
    const size_t row0 = (size_t)blockIdx.x * 32;
    {
        const int r = t >> 3, li = t & 7;
        const uint4* osrc = (const uint4*)(ows + (row0 + r) * 128 + li * 16);
        uint4 o0 = osrc[0], o1 = osrc[1];
        *(uint4*)&An[r][li * 16]     = o0;
        *(uint4*)&An[r][li * 16 + 8] = o1;
        const float* xr = x + (row0 + r) * 128 + li * 16;
        v8s xa, xb;
#pragma unroll
        for (int k4 = 0; k4 < 2; ++k4) {
            float4 vv = *(const float4*)(xr + 4 * k4);
            xa[4 * k4 + 0] = f2bs(vv.x); xa[4 * k4 + 1] = f2bs(vv.y);
            xa[4 * k4 + 2] = f2bs(vv.z); xa[4 * k4 + 3] = f2bs(vv.w);
        }
#pragma unroll
        for (int k4 = 0; k4 < 2; ++k4) {
            float4 vv = *(const float4*)(xr + 8 + 4 * k4);
            xb[4 * k4 + 0] = f2bs(vv.x); xb[4 * k4 + 1] = f2bs(vv.y);
            xb[4 * k4 + 2] = f2bs(vv.z); xb[4 * k4 + 3] = f2bs(vv.w);
        }
        *(v8s*)&An[r][128 + li * 16]     = xa;
        *(v8s*)&An[r][128 + li * 16 + 8] = xb;
    }
    __syncthreads();
    const int lane = t & 63, wv = t >> 6;
    const int m = lane & 15, quad = lane >> 4;
    const int ntb = wv * 2;
    v4f acc[2][2];
#pragma unroll
    for (int a = 0; a < 2; ++a)
#pragma unroll
        for (int b = 0; b < 2; ++b) acc[a][b] = (v4f){0.f, 0.f, 0.f, 0.f};
#pragma unroll
    for (int ks = 0; ks < 8; ++ks) {
        v8s a0 = *(const v8s*)&An[m][ks * 32 + quad * 8];
        v8s a1 = *(const v8s*)&An[m + 16][ks * 32 + quad * 8];
        const v8s* bp = (const v8s*)pwf + ((size_t)ks * 8 + ntb) * 64 + lane;
#pragma unroll
        for (int nt = 0; nt < 2; ++nt) {
            v8s b = bp[nt * 64];
            acc[0][nt] = __builtin_amdgcn_mfma_f32_16x16x32_bf16(a0, b, acc[0][nt], 0, 0, 0);
            acc[1][nt] = __builtin_amdgcn_mfma_f32_16x16x32_bf16(a1, b, acc[1][nt], 0, 0, 0);
        }
    }
#pragma unroll
    for (int nt = 0; nt < 2; ++nt) {
        int n = (ntb + nt) * 16 + m;
        float bv = pb[n];
#pragma unroll
        for (int mt = 0; mt < 2; ++mt)
#pragma unroll
            for (int rg = 0; rg < 4; ++rg) {
                int row = mt * 16 + quad * 4 + rg;
                size_t gi = (row0 + row) * 128 + n;
                yws[gi] = x[gi] + bv + acc[mt][nt][rg];
            }
    }
}

// ---------------------------------------------------------------------------
// Kernel 5 (MFMA): ffn = gelu(LN(y)@f1+b1)@f2+b2; out = y + ffn.
// ---------------------------------------------------------------------------
__global__ __launch_bounds__(256) void k_ffn(const float* __restrict__ yws,
                                             const float* __restrict__ g, const float* __restrict__ bb,
                                             const bf16* __restrict__ w1f, const float* __restrict__ b1,
                                             const bf16* __restrict__ w2f, const float* __restrict__ b2,
                                             float* __restrict__ outp) {
    __shared__ short An[32][136];
    __shared__ short Hs[32][520];
    const int t = threadIdx.x;
    const size_t row0 = (size_t)blockIdx.x * 32;
    {
        const int r = t >> 3, li = t & 7;
        const float* yr = yws + (row0 + r) * 128 + li * 16;
        float v[16];
        float s1 = 0.f, s2 = 0.f;
#pragma unroll
        for (int k4 = 0; k4 < 4; ++k4) {
            float4 vv = *(const float4*)(yr + 4 * k4);
            v[4 * k4 + 0] = vv.x; v[4 * k4 + 1] = vv.y; v[4 * k4 + 2] = vv.z; v[4 * k4 + 3] = vv.w;
            s1 += vv.x + vv.y + vv.z + vv.w;
            s2 += vv.x * vv.x + vv.y * vv.y + vv.z * vv.z + vv.w * vv.w;
        }
#pragma unroll
        for (int o = 1; o < 8; o <<= 1) { s1 += __shfl_xor(s1, o); s2 += __shfl_xor(s2, o); }
        float mu = s1 * (1.f / 128.f);
        float rs = rsqrtf(s2 * (1.f / 128.f) - mu * mu + 1e-5f);
        v8s lo, hi;
#pragma unroll
        for (int k = 0; k < 8; ++k) {
            int c = li * 16 + k;
            lo[k] = f2bs((v[k] - mu) * rs * g[c] + bb[c]);
        }
#pragma unroll
        for (int k = 0; k < 8; ++k) {
            int c = li * 16 + 8 + k;
            hi[k] = f2bs((v[8 + k] - mu) * rs * g[c] + bb[c]);
        }
        *(v8s*)&An[r][li * 16]     = lo;
        *(v8s*)&An[r][li * 16 + 8] = hi;
    }
    __syncthreads();
    const int lane = t & 63, wv = t >> 6;
    const int m = lane & 15, quad = lane >> 4;
    v4f acc1[2][8];
#pragma unroll
    for (int a = 0; a < 2; ++a)
#pragma unroll
        for (int b = 0; b < 8; ++b) acc1[a][b] = (v4f){0.f, 0.f, 0.f, 0.f};
    const int n0w = wv * 128;
#pragma unroll
    for (int ks = 0; ks < 4; ++ks) {
        v8s a0 = *(const v8s*)&An[m][ks * 32 + quad * 8];
        v8s a1 = *(const v8s*)&An[m + 16][ks * 32 + quad * 8];
        const v8s* bp = (const v8s*)w1f + ((size_t)ks * 32 + (n0w >> 4)) * 64 + lane;
#pragma unroll
        for (int nt = 0; nt < 8; ++nt) {
            v8s b = bp[nt * 64];
            acc1[0][nt] = __builtin_amdgcn_mfma_f32_16x16x32_bf16(a0, b, acc1[0][nt], 0, 0, 0);
            acc1[1][nt] = __builtin_amdgcn_mfma_f32_16x16x32_bf16(a1, b, acc1[1][nt], 0, 0, 0);
        }
    }
#pragma unroll
    for (int nt = 0; nt < 8; ++nt) {
        int n = n0w + nt * 16 + m;
        float b1v = b1[n];
#pragma unroll
        for (int mt = 0; mt < 2; ++mt)
#pragma unroll
            for (int rg = 0; rg < 4; ++rg)
                Hs[mt * 16 + quad * 4 + rg][n] = f2bs(gelu_exact(acc1[mt][nt][rg] + b1v));
    }
    __syncthreads();
    v4f acc2[2][2];
#pragma unroll
    for (int a = 0; a < 2; ++a)
#pragma unroll
        for (int b = 0; b < 2; ++b) acc2[a][b] = (v4f){0.f, 0.f, 0.f, 0.f};
    const int ntb = wv * 2;
#pragma unroll
    for (int ks = 0; ks < 16; ++ks) {
        v8s a0 = *(const v8s*)&Hs[m][ks * 32 + quad * 8];
        v8s a1 = *(const v8s*)&Hs[m + 16][ks * 32 + quad * 8];
        const v8s* bp = (const v8s*)w2f + ((size_t)ks * 8 + ntb) * 64 + lane;
#pragma unroll
        for (int nt = 0; nt < 2; ++nt) {
            v8s b = bp[nt * 64];
            acc2[0][nt] = __builtin_amdgcn_mfma_f32_16x16x32_bf16(a0, b, acc2[0][nt], 0, 0, 0);
            acc2[1][nt] = __builtin_amdgcn_mfma_f32_16x16x32_bf16(a1, b, acc2[1][nt], 0, 0, 0);
        }
    }
#pragma unroll
    for (int nt = 0; nt < 2; ++nt) {
        int n = (ntb + nt) * 16 + m;
        float b2v = b2[n];
#pragma unroll
        for (int mt = 0; mt < 2; ++mt)
#pragma unroll
            for (int rg = 0; rg < 4; ++rg) {
                int row = mt * 16 + quad * 4 + rg;
                size_t gi = (row0 + row) * 128 + n;
                outp[gi] = yws[gi] + b2v + acc2[mt][nt][rg];
            }
    }
}

extern "C" void kernel_launch(void* const* d_in, const int* in_sizes, int n_in,
                              void* d_out, int out_size, void* d_ws, size_t ws_size,
                              hipStream_t stream) {
    const float* x      = (const float*)d_in[0];
    const float* ctx    = (const float*)d_in[1];
    const float* ctxn_g = (const float*)d_in[2];
    const float* ctxn_b = (const float*)d_in[3];
    const float* ctxp_w = (const float*)d_in[4];
    const float* ctxp_b = (const float*)d_in[5];
    const float* n1_g   = (const float*)d_in[6];
    const float* n1_b   = (const float*)d_in[7];
    const float* n1v_g  = (const float*)d_in[8];
    const float* n1v_b  = (const float*)d_in[9];
    const float* q_w    = (const float*)d_in[10];
    const float* q_b    = (const float*)d_in[11];
    const float* k_w    = (const float*)d_in[12];
    const float* k_b    = (const float*)d_in[13];
    const float* v_w    = (const float*)d_in[14];
    const float* v_b    = (const float*)d_in[15];
    const float* rpb    = (const float*)d_in[16];
    const float* proj_w = (const float*)d_in[17];
    const float* proj_b = (const float*)d_in[18];
    const float* n2_g   = (const float*)d_in[19];
    const float* n2_b   = (const float*)d_in[20];
    const float* f1_w   = (const float*)d_in[21];
    const float* f1_b   = (const float*)d_in[22];
    const float* f2_w   = (const float*)d_in[23];
    const float* f2_b   = (const float*)d_in[24];
    float* out = (float*)d_out;

    char* ws = (char*)d_ws;
    bf16*      ctxp = (bf16*)(ws);                 //  8,388,608 B  (B,HW,64) bf16
    _Float16*  qws  = (_Float16*)(ws + 8388608);   // 16,777,216 B  (B,8,HW,16) f16
    _Float16*  kws  = (_Float16*)(ws + 25165824);  // 16,777,216 B
    _Float16*  vws  = (_Float16*)(ws + 41943040);  // 16,777,216 B
    bf16*      ows  = (bf16*)(ws + 58720256);      // 16,777,216 B  (B,HW,128) bf16
    float*     yws  = (float*)(ws + 8388608);      // aliases qws+kws (dead after attn)
    char* frag = ws + 75497472;
    bf16*  w1f  = (bf16*)(frag);                   // 131,072 B
    bf16*  w2f  = (bf16*)(frag + 131072);          // 131,072 B
    bf16*  qwf  = (bf16*)(frag + 262144);          //  49,152 B
    bf16*  kwf  = (bf16*)(frag + 311296);          //  49,152 B
    bf16*  vwf  = (bf16*)(frag + 360448);          //  32,768 B
    bf16*  pwf  = (bf16*)(frag + 393216);          //  65,536 B
    float* rpl2 = (float*)(frag + 458752);         //  14,112 B (8*441 fp32)
    // ctx-GEMM prep lives in the qws region: it is fully consumed by k_ctx,
    // which completes (stream-ordered) before k_qkv writes qws.
    bf16*  wgf  = (bf16*)(ws + 8388608);           //  32,768 B  g.W fragments (K=256,N=64)
    float* cgw  = (float*)(ws + 8388608 + 32768);  //     256 B  sum_e g*W
    float* cbw  = (float*)(ws + 8388608 + 33024);  //     256 B  sum_e b*W + pb

    k_repack<<<256, 256, 0, stream>>>(f1_w, w1f, 128, 512);
    k_repack<<<256, 256, 0, stream>>>(f2_w, w2f, 512, 128);
    k_repack<<<96,  256, 0, stream>>>(q_w,  qwf, 192, 128);
    k_repack<<<96,  256, 0, stream>>>(k_w,  kwf, 192, 128);
    k_repack<<<64,  256, 0, stream>>>(v_w,  vwf, 128, 128);
    k_repack<<<128, 256, 0, stream>>>(proj_w, pwf, 256, 128);
    k_repack_g<<<64, 256, 0, stream>>>(ctxp_w, ctxn_g, wgf, 256, 64);
    k_ctxc<<<1, 256, 0, stream>>>(ctxp_w, ctxn_g, ctxn_b, ctxp_b, cgw, cbw);
    k_rpb<<<14, 256, 0, stream>>>(rpb, rpl2, 8 * 441);
    k_ctx<<<2048, 256, 0, stream>>>(ctx, cgw, cbw, wgf, ctxp);
    k_qkv<<<2048, 256, 0, stream>>>(x, ctxp, n1_g, n1_b, n1v_g, n1v_b,
                                    qwf, q_b, kwf, k_b, vwf, v_b, qws, kws, vws);
    k_attn<<<1024, 256, 0, stream>>>(qws, kws, vws, rpl2, ows);
    k_proj<<<2048, 256, 0, stream>>>(x, ows, pwf, proj_b, yws);
    k_ffn<<<2048, 256, 0, stream>>>(yws, n2_g, n2_b, w1f, f1_b, w2f, f2_b, out);
}

// Round 4
// 383.952 us; speedup vs baseline: 1.0975x; 1.0424x over previous
//
#include <hip/hip_runtime.h>
#include <hip/hip_bf16.h>
#include <math.h>

typedef __hip_bfloat16 bf16;
typedef float v2f __attribute__((ext_vector_type(2)));
typedef float v4f __attribute__((ext_vector_type(4)));
typedef short v8s __attribute__((ext_vector_type(8)));
typedef _Float16 v2h __attribute__((ext_vector_type(2)));

__device__ __forceinline__ float b2f(bf16 v) { return __bfloat162float(v); }
__device__ __forceinline__ float unpk_lo(unsigned u) { return __uint_as_float(u << 16); }
__device__ __forceinline__ float unpk_hi(unsigned u) { return __uint_as_float(u & 0xffff0000u); }
__device__ __forceinline__ v2f unpk2(unsigned u) {
    v2f r; r.x = __uint_as_float(u << 16); r.y = __uint_as_float(u & 0xffff0000u); return r;
}
__device__ __forceinline__ unsigned pk2(float a, float b) {
    unsigned ua = __float_as_uint(a);
    unsigned ub = __float_as_uint(b);
    ua = (ua + 0x7fffu + ((ua >> 16) & 1u)) >> 16;   // RNE to bf16
    ub = (ub + 0x7fffu + ((ub >> 16) & 1u)) >> 16;
    return ua | (ub << 16);
}
__device__ __forceinline__ short f2bs(float f) {
    unsigned u = __float_as_uint(f);
    u = (u + 0x7fffu + ((u >> 16) & 1u)) >> 16;
    return (short)u;
}
__device__ __forceinline__ v2h u2h(unsigned u) {
    union { unsigned u; v2h h; } c; c.u = u; return c.h;
}
__device__ __forceinline__ float gelu_exact(float x) {
    return 0.5f * x * (1.f + erff(x * 0.70710678118654752440f));
}

#define LOG2E 1.44269504088896340736f

// ---------------------------------------------------------------------------
// Repack a KxN fp32 weight into bf16 MFMA B-fragments for 16x16x32.
// ---------------------------------------------------------------------------
__global__ __launch_bounds__(256) void k_repack(const float* __restrict__ src,
                                                bf16* __restrict__ dst, int K, int N) {
    int idx = blockIdx.x * 256 + threadIdx.x;
    if (idx >= K * N) return;
    int k = idx / N, n = idx % N;
    int kstep = k >> 5, quad = (k & 31) >> 3, j = k & 7;
    int ntile = n >> 4, nn = n & 15;
    size_t di = ((((size_t)kstep * (N >> 4)) + ntile) * 64 + nn + (quad << 4)) * 8 + j;
    dst[di] = __float2bfloat16(src[idx]);
}

// Same repack but scales row k by g[k] (folds the LN gain into the weight).
__global__ __launch_bounds__(256) void k_repack_g(const float* __restrict__ src,
                                                  const float* __restrict__ g,
                                                  bf16* __restrict__ dst, int K, int N) {
    int idx = blockIdx.x * 256 + threadIdx.x;
    if (idx >= K * N) return;
    int k = idx / N, n = idx % N;
    int kstep = k >> 5, quad = (k & 31) >> 3, j = k & 7;
    int ntile = n >> 4, nn = n & 15;
    size_t di = ((((size_t)kstep * (N >> 4)) + ntile) * 64 + nn + (quad << 4)) * 8 + j;
    dst[di] = __float2bfloat16(src[idx] * g[k]);
}

// LN-fold correction vectors for the ctx projection (K=256, N=64):
//   cgw[n] = sum_e g[e] * W[e][n]
//   cbw[n] = sum_e b[e] * W[e][n] + pb[n]
__global__ __launch_bounds__(256) void k_ctxc(const float* __restrict__ w,
                                              const float* __restrict__ g,
                                              const float* __restrict__ bb,
                                              const float* __restrict__ pb,
                                              float* __restrict__ cgw,
                                              float* __restrict__ cbw) {
    __shared__ float rg_[4][64], rb_[4][64];
    const int n = threadIdx.x & 63, eg = threadIdx.x >> 6;
    float sg = 0.f, sb = 0.f;
    for (int e = eg * 64; e < eg * 64 + 64; ++e) {
        float wv = w[e * 64 + n];
        sg += g[e] * wv;
        sb += bb[e] * wv;
    }
    rg_[eg][n] = sg; rb_[eg][n] = sb;
    __syncthreads();
    if (threadIdx.x < 64) {
        float a = rg_[0][n] + rg_[1][n] + rg_[2][n] + rg_[3][n];
        float c = rb_[0][n] + rb_[1][n] + rb_[2][n] + rb_[3][n];
        cgw[n] = a;
        cbw[n] = c + pb[n];
    }
}

// rpb -> log2e*rpb - 8  (the -8 cancels in softmax normalization; keeps
// unnormalized f16 PV accumulation far from overflow)
__global__ __launch_bounds__(256) void k_rpb(const float* __restrict__ src,
                                             float* __restrict__ dst, int n) {
    int i = blockIdx.x * 256 + threadIdx.x;
    if (i < n) dst[i] = src[i] * LOG2E - 8.0f;
}

// ---------------------------------------------------------------------------
// Kernel 1 (MFMA): ctx projection. A = raw ctx (transposed, bf16), B = g.W
// fragments; LN folded into epilogue:
//   out[r][n] = rs_r*(acc - mu_r*cgw[n]) + cbw[n]
// Block: 32 hw rows x 256 e, 4 waves each own one 16-col ntile of N=64.
// ---------------------------------------------------------------------------
__global__ __launch_bounds__(256) void k_ctx(const float* __restrict__ ctx,
                                             const float* __restrict__ cgw,
                                             const float* __restrict__ cbw,
                                             const bf16* __restrict__ wgf,
                                             bf16* __restrict__ outp) {
    __shared__ short As[32][264];
    __shared__ float redS[8][32];
    __shared__ float redQ[8][32];
    __shared__ float smu[32], srs[32];
    const int t = threadIdx.x;
    const int b = blockIdx.x >> 7;
    const int hw0 = (blockIdx.x & 127) << 5;
    {
        // lanes 0..31 of each wave read 32 contiguous hw floats (128B segments);
        // thread t owns row r = t&31, e-slice li*32..li*32+31 (li = t>>5).
        const int r = t & 31, li = t >> 5;
        const float* src = ctx + ((size_t)b * 256 + li * 32) * 4096 + hw0 + r;
        float v[32];
        float s = 0.f, q = 0.f;
#pragma unroll
        for (int j = 0; j < 32; ++j) {
            float x = src[(size_t)j * 4096];
            v[j] = x; s += x; q += x * x;
        }
        redS[li][r] = s;
        redQ[li][r] = q;
        v8s p0, p1, p2, p3;
#pragma unroll
        for (int j = 0; j < 8; ++j) p0[j] = f2bs(v[j]);
#pragma unroll
        for (int j = 0; j < 8; ++j) p1[j] = f2bs(v[8 + j]);
#pragma unroll
        for (int j = 0; j < 8; ++j) p2[j] = f2bs(v[16 + j]);
#pragma unroll
        for (int j = 0; j < 8; ++j) p3[j] = f2bs(v[24 + j]);
        v8s* dst = (v8s*)&As[r][li * 32];
        dst[0] = p0; dst[1] = p1; dst[2] = p2; dst[3] = p3;
    }
    __syncthreads();
    if (t < 32) {
        float s = 0.f, q = 0.f;
#pragma unroll
        for (int k = 0; k < 8; ++k) { s += redS[k][t]; q += redQ[k][t]; }
        float mu = s * (1.f / 256.f);
        float var = q * (1.f / 256.f) - mu * mu;
        smu[t] = mu;
        srs[t] = rsqrtf(var + 1e-5f);
    }
    __syncthreads();
    const int lane = t & 63, wv = t >> 6;
    const int m = lane & 15, quad = lane >> 4;
    v4f acc0 = (v4f){0.f, 0.f, 0.f, 0.f};
    v4f acc1 = (v4f){0.f, 0.f, 0.f, 0.f};
#pragma unroll
    for (int ks = 0; ks < 8; ++ks) {
        v8s a0 = *(const v8s*)&As[m][ks * 32 + quad * 8];
        v8s a1 = *(const v8s*)&As[m + 16][ks * 32 + quad * 8];
        v8s bfr = ((const v8s*)wgf)[((size_t)ks * 4 + wv) * 64 + lane];
        acc0 = __builtin_amdgcn_mfma_f32_16x16x32_bf16(a0, bfr, acc0, 0, 0, 0);
        acc1 = __builtin_amdgcn_mfma_f32_16x16x32_bf16(a1, bfr, acc1, 0, 0, 0);
    }
    const int n = wv * 16 + m;
    const float cg = cgw[n], cb = cbw[n];
    short* obase = (short*)outp + ((size_t)b * 4096 + hw0) * 64 + n;
#pragma unroll
    for (int rg = 0; rg < 4; ++rg) {
        int row = quad * 4 + rg;
        float o = srs[row] * (acc0[rg] - smu[row] * cg) + cb;
        obase[(size_t)row * 64] = f2bs(o);
    }
#pragma unroll
    for (int rg = 0; rg < 4; ++rg) {
        int row = 16 + quad * 4 + rg;
        float o = srs[row] * (acc1[rg] - smu[row] * cg) + cb;
        obase[(size_t)row * 64] = f2bs(o);
    }
}

// ---------------------------------------------------------------------------
// Kernel 2 (MFMA): LN(concat(x,ctx),192) -> q,k ; LN(x,128) -> v.
// q/k/v written as f16 (q folded with 0.25*log2e for exp2-softmax).
// ---------------------------------------------------------------------------
__global__ __launch_bounds__(256) void k_qkv(const float* __restrict__ x,
                                             const bf16* __restrict__ ctxp,
                                             const float* __restrict__ n1g, const float* __restrict__ n1b,
                                             const float* __restrict__ nvg, const float* __restrict__ nvb,
                                             const bf16* __restrict__ qwf, const float* __restrict__ qb,
                                             const bf16* __restrict__ kwf, const float* __restrict__ kb,
                                             const bf16* __restrict__ vwf, const float* __restrict__ vb,
                                             _Float16* __restrict__ qo, _Float16* __restrict__ ko,
                                             _Float16* __restrict__ vo) {
    __shared__ short Aqk[32][200];
    __shared__ short Av[32][136];
    const int t = threadIdx.x;
    const size_t row0 = (size_t)blockIdx.x * 32;
    {
        const int r = t >> 3, li = t & 7;
        const float* xr = x + (row0 + r) * 128 + li * 16;
        float v[16];
        float sx1 = 0.f, sx2 = 0.f;
#pragma unroll
        for (int k4 = 0; k4 < 4; ++k4) {
            float4 vv = *(const float4*)(xr + 4 * k4);
            v[4 * k4 + 0] = vv.x; v[4 * k4 + 1] = vv.y; v[4 * k4 + 2] = vv.z; v[4 * k4 + 3] = vv.w;
            sx1 += vv.x + vv.y + vv.z + vv.w;
            sx2 += vv.x * vv.x + vv.y * vv.y + vv.z * vv.z + vv.w * vv.w;
        }
        float cv[8];
        float sc1 = 0.f, sc2 = 0.f;
        {
            uint4 cu = *(const uint4*)(ctxp + (row0 + r) * 64 + li * 8);
            v2f p0 = unpk2(cu.x), p1 = unpk2(cu.y), p2 = unpk2(cu.z), p3 = unpk2(cu.w);
            cv[0] = p0.x; cv[1] = p0.y; cv[2] = p1.x; cv[3] = p1.y;
            cv[4] = p2.x; cv[5] = p2.y; cv[6] = p3.x; cv[7] = p3.y;
#pragma unroll
            for (int k = 0; k < 8; ++k) { sc1 += cv[k]; sc2 += cv[k] * cv[k]; }
        }
#pragma unroll
        for (int o = 1; o < 8; o <<= 1) {
            sx1 += __shfl_xor(sx1, o); sx2 += __shfl_xor(sx2, o);
            sc1 += __shfl_xor(sc1, o); sc2 += __shfl_xor(sc2, o);
        }
        float mu  = (sx1 + sc1) * (1.f / 192.f);
        float rs  = rsqrtf((sx2 + sc2) * (1.f / 192.f) - mu * mu + 1e-5f);
        float muv = sx1 * (1.f / 128.f);
        float rsv = rsqrtf(sx2 * (1.f / 128.f) - muv * muv + 1e-5f);
        v8s q0, q1, vv0, vv1, cc;
#pragma unroll
        for (int k = 0; k < 8; ++k) {
            int c = li * 16 + k;
            q0[k]  = f2bs((v[k] - mu) * rs * n1g[c] + n1b[c]);
            vv0[k] = f2bs((v[k] - muv) * rsv * nvg[c] + nvb[c]);
        }
#pragma unroll
        for (int k = 0; k < 8; ++k) {
            int c = li * 16 + 8 + k;
            q1[k]  = f2bs((v[8 + k] - mu) * rs * n1g[c] + n1b[c]);
            vv1[k] = f2bs((v[8 + k] - muv) * rsv * nvg[c] + nvb[c]);
        }
#pragma unroll
        for (int k = 0; k < 8; ++k) {
            int c = 128 + li * 8 + k;
            cc[k] = f2bs((cv[k] - mu) * rs * n1g[c] + n1b[c]);
        }
        *(v8s*)&Aqk[r][li * 16]     = q0;
        *(v8s*)&Aqk[r][li * 16 + 8] = q1;
        *(v8s*)&Aqk[r][128 + li * 8] = cc;
        *(v8s*)&Av[r][li * 16]     = vv0;
        *(v8s*)&Av[r][li * 16 + 8] = vv1;
    }
    __syncthreads();
    const int lane = t & 63, wv = t >> 6;
    const int m = lane & 15, quad = lane >> 4;
    const int ntb = wv * 2;
    v4f aq[2][2], ak[2][2], av[2][2];
#pragma unroll
    for (int a = 0; a < 2; ++a)
#pragma unroll
        for (int b = 0; b < 2; ++b) {
            aq[a][b] = (v4f){0.f, 0.f, 0.f, 0.f};
            ak[a][b] = (v4f){0.f, 0.f, 0.f, 0.f};
            av[a][b] = (v4f){0.f, 0.f, 0.f, 0.f};
        }
#pragma unroll
    for (int ks = 0; ks < 6; ++ks) {
        v8s a0 = *(const v8s*)&Aqk[m][ks * 32 + quad * 8];
        v8s a1 = *(const v8s*)&Aqk[m + 16][ks * 32 + quad * 8];
        const v8s* bpq = (const v8s*)qwf + ((size_t)ks * 8 + ntb) * 64 + lane;
        const v8s* bpk = (const v8s*)kwf + ((size_t)ks * 8 + ntb) * 64 + lane;
#pragma unroll
        for (int nt = 0; nt < 2; ++nt) {
            v8s bq = bpq[nt * 64];
            v8s bk = bpk[nt * 64];
            aq[0][nt] = __builtin_amdgcn_mfma_f32_16x16x32_bf16(a0, bq, aq[0][nt], 0, 0, 0);
            aq[1][nt] = __builtin_amdgcn_mfma_f32_16x16x32_bf16(a1, bq, aq[1][nt], 0, 0, 0);
            ak[0][nt] = __builtin_amdgcn_mfma_f32_16x16x32_bf16(a0, bk, ak[0][nt], 0, 0, 0);
            ak[1][nt] = __builtin_amdgcn_mfma_f32_16x16x32_bf16(a1, bk, ak[1][nt], 0, 0, 0);
        }
    }
#pragma unroll
    for (int ks = 0; ks < 4; ++ks) {
        v8s a0 = *(const v8s*)&Av[m][ks * 32 + quad * 8];
        v8s a1 = *(const v8s*)&Av[m + 16][ks * 32 + quad * 8];
        const v8s* bpv = (const v8s*)vwf + ((size_t)ks * 8 + ntb) * 64 + lane;
#pragma unroll
        for (int nt = 0; nt < 2; ++nt) {
            v8s bv = bpv[nt * 64];
            av[0][nt] = __builtin_amdgcn_mfma_f32_16x16x32_bf16(a0, bv, av[0][nt], 0, 0, 0);
            av[1][nt] = __builtin_amdgcn_mfma_f32_16x16x32_bf16(a1, bv, av[1][nt], 0, 0, 0);
        }
    }
#pragma unroll
    for (int nt = 0; nt < 2; ++nt) {
        int n = (ntb + nt) * 16 + m;
        int head = n >> 4, d = n & 15;
        float qbv = qb[n], kbv = kb[n], vbv = vb[n];
#pragma unroll
        for (int mt = 0; mt < 2; ++mt)
#pragma unroll
            for (int rg = 0; rg < 4; ++rg) {
                int rowg = (int)row0 + mt * 16 + quad * 4 + rg;
                int b = rowg >> 12, hw = rowg & 4095;
                size_t oi = (((size_t)b * 8 + head) * 4096 + hw) * 16 + d;
                qo[oi] = (_Float16)((aq[mt][nt][rg] + qbv) * (0.25f * LOG2E));
                ko[oi] = (_Float16)(ak[mt][nt][rg] + kbv);
                vo[oi] = (_Float16)(av[mt][nt][rg] + vbv);
            }
    }
}

// ---------------------------------------------------------------------------
// Kernel 3: neighborhood attention, f16 + v_dot2 + pk_fma_f16.
// 2 query rows per thread (halves the LDS-read floor) + 512-thread blocks so
// a SINGLE resident block still carries 8 waves/CU = 2 waves/SIMD (the r2/r3
// variants proved <2 waves/SIMD goes latency-bound; 74.75KB tiles don't
// co-schedule 2 blocks).
// Block: 8 waves x 2 query rows = 16 i-rows x 64 j; K/V tile 26 rows.
// LDS col-major, column stride 420 dwords (420%32==4 -> same bank spread as
// the proven 292 stride). 26*16+4=420; 64*420*4 = 107,520 B.
// start_min = clamp(i0-5, 0, 38) makes all 26 tile rows in-bounds (no guard).
// ---------------------------------------------------------------------------
__global__ __launch_bounds__(512) void k_attn(const _Float16* __restrict__ qws,
                                              const _Float16* __restrict__ kws,
                                              const _Float16* __restrict__ vws,
                                              const float* __restrict__ rpbl2,
                                              bf16* __restrict__ ows) {
    __shared__ unsigned ktv[64 * 420];
    const int tid  = threadIdx.x;
    const int bh   = blockIdx.x >> 2;
    const int i0   = (blockIdx.x & 3) << 4;
    const int head = bh & 7;
    int start_min = i0 - 5; if (start_min < 0) start_min = 0; if (start_min > 38) start_min = 38;
    const unsigned* ku = (const unsigned*)kws;
    const unsigned* vu = (const unsigned*)vws;
    const size_t gK = ((size_t)bh * 4096 + (size_t)start_min * 64) * 8;
    // stage 26 rows x 64 cols x (K:8 + V:8 dwords); 26*128 = 3328 index pairs
    for (int idx = tid; idx < 3328; idx += 512) {
        int row = idx >> 7, rem = idx & 127, col = rem >> 1, h4 = (rem & 1) * 4;
        const size_t gsrc = gK + (size_t)row * 512 + col * 8 + h4;
        *(uint4*)&ktv[col * 420 + row * 16 + h4]     = *(const uint4*)(ku + gsrc);
        *(uint4*)&ktv[col * 420 + row * 16 + 8 + h4] = *(const uint4*)(vu + gsrc);
    }
    __syncthreads();
    const int wv = tid >> 6;
    const int j  = tid & 63;
    const int ib = i0 + 2 * wv;           // wave owns query rows ib, ib+1
    int start_j = j - 5; if (start_j < 0) start_j = 0; if (start_j > 53) start_j = 53;
    v2h qh[2][8];
#pragma unroll
    for (int q = 0; q < 2; ++q) {
        const uint4* qp = (const uint4*)(qws + ((size_t)bh * 4096 + (ib + q) * 64 + j) * 16);
        uint4 q0 = qp[0], q1 = qp[1];
        qh[q][0] = u2h(q0.x); qh[q][1] = u2h(q0.y); qh[q][2] = u2h(q0.z); qh[q][3] = u2h(q0.w);
        qh[q][4] = u2h(q1.x); qh[q][5] = u2h(q1.y); qh[q][6] = u2h(q1.z); qh[q][7] = u2h(q1.w);
    }
    int st0 = ib - 5; if (st0 < 0) st0 = 0; if (st0 > 53) st0 = 53;
    int st1 = ib - 4; if (st1 < 0) st1 = 0; if (st1 > 53) st1 = 53;
    const int nr = st1 - st0 + 11;        // 11 or 12
    float l[2] = {0.f, 0.f};
    v2h acc[2][8];
#pragma unroll
    for (int q = 0; q < 2; ++q)
#pragma unroll
        for (int d = 0; d < 8; ++d) acc[q][d] = (v2h){(_Float16)0.f, (_Float16)0.f};
    const float* rpb_base = rpbl2 + head * 441 + (start_j - j + 10);
    const int lds_base = start_j * 420;
    for (int au = 0; au < nr; ++au) {
        const int a_abs = st0 + au;
        const int r16 = (a_abs - start_min) * 16;
        const float* rb[2];
        float pen[2];
#pragma unroll
        for (int q = 0; q < 2; ++q) {
            int iq = ib + q;
            int sq = iq - 5; if (sq < 0) sq = 0; if (sq > 53) sq = 53;
            int ri = a_abs - iq + 10;
            int ric = ri < 0 ? 0 : (ri > 20 ? 20 : ri);
            rb[q] = rpb_base + ric * 21;
            pen[q] = ((unsigned)(a_abs - sq) <= 10u) ? 0.f : -30000.f;
        }
#pragma unroll
        for (int c = 0; c < 11; ++c) {
            const unsigned* cp = &ktv[lds_base + c * 420 + r16];
            uint4 k0 = *(const uint4*)(cp);
            uint4 k1 = *(const uint4*)(cp + 4);
            uint4 v0 = *(const uint4*)(cp + 8);
            uint4 v1 = *(const uint4*)(cp + 12);
#pragma unroll
            for (int q = 0; q < 2; ++q) {
                float sa = __builtin_amdgcn_fdot2(qh[q][0], u2h(k0.x), rb[q][c] + pen[q], false);
                sa = __builtin_amdgcn_fdot2(qh[q][1], u2h(k0.y), sa, false);
                sa = __builtin_amdgcn_fdot2(qh[q][2], u2h(k0.z), sa, false);
                sa = __builtin_amdgcn_fdot2(qh[q][3], u2h(k0.w), sa, false);
                float sb = __builtin_amdgcn_fdot2(qh[q][4], u2h(k1.x), 0.f, false);
                sb = __builtin_amdgcn_fdot2(qh[q][5], u2h(k1.y), sb, false);
                sb = __builtin_amdgcn_fdot2(qh[q][6], u2h(k1.z), sb, false);
                sb = __builtin_amdgcn_fdot2(qh[q][7], u2h(k1.w), sb, false);
                float p = __builtin_amdgcn_exp2f(sa + sb);
                l[q] += p;
                _Float16 ph = (_Float16)p;
                v2h p2 = {ph, ph};
                acc[q][0] += u2h(v0.x) * p2;
                acc[q][1] += u2h(v0.y) * p2;
                acc[q][2] += u2h(v0.z) * p2;
                acc[q][3] += u2h(v0.w) * p2;
                acc[q][4] += u2h(v1.x) * p2;
                acc[q][5] += u2h(v1.y) * p2;
                acc[q][6] += u2h(v1.z) * p2;
                acc[q][7] += u2h(v1.w) * p2;
            }
        }
    }
    const int b = bh >> 3;
#pragma unroll
    for (int q = 0; q < 2; ++q) {
        float inv = 1.f / l[q];
        unsigned* op = (unsigned*)ows + ((size_t)b * 4096 + (ib + q) * 64 + j) * 64 + head * 8;
#pragma unroll
        for (int d2 = 0; d2 < 8; ++d2)
            op[d2] = pk2((float)acc[q][d2].x * inv, (float)acc[q][d2].y * inv);
    }
}

// ---------------------------------------------------------------------------
// Kernel 4 (MFMA): y = x + concat(o, x) @ proj_w + proj_b -> fp32 ws.
// ---------------------------------------------------------------------------
__global__ __launch_bounds__(256) void k_proj(const float* __restrict__ x,
                                              const bf16* __restrict__ ows,
                                              const bf16* __restrict__ pwf,
                                              const float* __restrict__ pb,
                                              float* __restrict__ yws) {
    __shared__ short An[32][264];
    const int t = threadIdx.x;
    const size_t row0 = (size_t)blockIdx.x * 32;
    {
        const int r = t >> 3, li = t & 7;
        const uint4* osrc = (const uint4*)(ows + (row0 + r) * 128 + li * 16);
        uint4 o0 = osrc[0], o1 = osrc[1];
        *(uint4*)&An[r][li * 16]     = o0;
        *(uint4*)&An[r][li * 16 + 8] = o1;
        const float* xr = x + (row0 + r) * 128 + li * 16;
        v8s xa, xb;
#pragma unroll
        for (int k4 = 0; k4 < 2; ++k4) {
            float4 vv = *(const float4*)(xr + 4 * k4);
            xa[4 * k4 + 0] = f2bs(vv.x); xa[4 * k4 + 1] = f2bs(vv.y);
            xa[4 * k4 + 2] = f2bs(vv.z); xa[4 * k4 + 3] = f2bs(vv.w);
        }
#pragma unroll
        for (int k4 = 0; k4 < 2; ++k4) {
            float4 vv = *(const float4*)(xr + 8 + 4 * k4);
            xb[4 * k4 + 0] = f2bs(vv.x); xb[4 * k4 + 1] = f2bs(vv.y);
            xb[4 * k4 + 2] = f2bs(vv.z); xb[4 * k4 + 3] = f2bs(vv.w);
        }
        *(v8s*)&An[r][128 + li * 16]     = xa;
        *(v8s*)&An[r][128 + li * 16 + 8] = xb;
    }
    __syncthreads();
    const int lane = t & 63, wv = t >> 6;
    const int m = lane & 15, quad = lane >> 4;
    const int ntb = wv * 2;
    v4f acc[2][2];
#pragma unroll
    for (int a = 0; a < 2; ++a)
#pragma unroll
        for (int b = 0; b < 2; ++b) acc[a][b] = (v4f){0.f, 0.f, 0.f, 0.f};
#pragma unroll
    for (int ks = 0; ks < 8; ++ks) {
        v8s a0 = *(const v8s*)&An[m][ks * 32 + quad * 8];
        v8s a1 = *(const v8s*)&An[m + 16][ks * 32 + quad * 8];
        const v8s* bp = (const v8s*)pwf + ((size_t)ks * 8 + ntb) * 64 + lane;
#pragma unroll
        for (int nt = 0; nt < 2; ++nt) {
            v8s b = bp[nt * 64];
            acc[0][nt] = __builtin_amdgcn_mfma_f32_16x16x32_bf16(a0, b, acc[0][nt], 0, 0, 0);
            acc[1][nt] = __builtin_amdgcn_mfma_f32_16x16x32_bf16(a1, b, acc[1][nt], 0, 0, 0);
        }
    }
#pragma unroll
    for (int nt = 0; nt < 2; ++nt) {
        int n = (ntb + nt) * 16 + m;
        float bv = pb[n];
#pragma unroll
        for (int mt = 0; mt < 2; ++mt)
#pragma unroll
            for (int rg = 0; rg < 4; ++rg) {
                int row = mt * 16 + quad * 4 + rg;
                size_t gi = (row0 + row) * 128 + n;
                yws[gi] = x[gi] + bv + acc[mt][nt][rg];
            }
    }
}

// ---------------------------------------------------------------------------
// Kernel 5 (MFMA): ffn = gelu(LN(y)@f1+b1)@f2+b2; out = y + ffn.
// ---------------------------------------------------------------------------
__global__ __launch_bounds__(256) void k_ffn(const float* __restrict__ yws,
                                             const float* __restrict__ g, const float* __restrict__ bb,
                                             const bf16* __restrict__ w1f, const float* __restrict__ b1,
                                             const bf16* __restrict__ w2f, const float* __restrict__ b2,
                                             float* __restrict__ outp) {
    __shared__ short An[32][136];
    __shared__ short Hs[32][520];
    const int t = threadIdx.x;
    const size_t row0 = (size_t)blockIdx.x * 32;
    {
        const int r = t >> 3, li = t & 7;
        const float* yr = yws + (row0 + r) * 128 + li * 16;
        float v[16];
        float s1 = 0.f, s2 = 0.f;
#pragma unroll
        for (int k4 = 0; k4 < 4; ++k4) {
            float4 vv = *(const float4*)(yr + 4 * k4);
            v[4 * k4 + 0] = vv.x; v[4 * k4 + 1] = vv.y; v[4 * k4 + 2] = vv.z; v[4 * k4 + 3] = vv.w;
            s1 += vv.x + vv.y + vv.z + vv.w;
            s2 += vv.x * vv.x + vv.y * vv.y + vv.z * vv.z + vv.w * vv.w;
        }
#pragma unroll
        for (int o = 1; o < 8; o <<= 1) { s1 += __shfl_xor(s1, o); s2 += __shfl_xor(s2, o); }
        float mu = s1 * (1.f / 128.f);
        float rs = rsqrtf(s2 * (1.f / 128.f) - mu * mu + 1e-5f);
        v8s lo, hi;
#pragma unroll
        for (int k = 0; k < 8; ++k) {
            int c = li * 16 + k;
            lo[k] = f2bs((v[k] - mu) * rs * g[c] + bb[c]);
        }
#pragma unroll
        for (int k = 0; k < 8; ++k) {
            int c = li * 16 + 8 + k;
            hi[k] = f2bs((v[8 + k] - mu) * rs * g[c] + bb[c]);
        }
        *(v8s*)&An[r][li * 16]     = lo;
        *(v8s*)&An[r][li * 16 + 8] = hi;
    }
    __syncthreads();
    const int lane = t & 63, wv = t >> 6;
    const int m = lane & 15, quad = lane >> 4;
    v4f acc1[2][8];
#pragma unroll
    for (int a = 0; a < 2; ++a)
#pragma unroll
        for (int b = 0; b < 8; ++b) acc1[a][b] = (v4f){0.f, 0.f, 0.f, 0.f};
    const int n0w = wv * 128;
#pragma unroll
    for (int ks = 0; ks < 4; ++ks) {
        v8s a0 = *(const v8s*)&An[m][ks * 32 + quad * 8];
        v8s a1 = *(const v8s*)&An[m + 16][ks * 32 + quad * 8];
        const v8s* bp = (const v8s*)w1f + ((size_t)ks * 32 + (n0w >> 4)) * 64 + lane;
#pragma unroll
        for (int nt = 0; nt < 8; ++nt) {
            v8s b = bp[nt * 64];
            acc1[0][nt] = __builtin_amdgcn_mfma_f32_16x16x32_bf16(a0, b, acc1[0][nt], 0, 0, 0);
            acc1[1][nt] = __builtin_amdgcn_mfma_f32_16x16x32_bf16(a1, b, acc1[1][nt], 0, 0, 0);
        }
    }
#pragma unroll
    for (int nt = 0; nt < 8; ++nt) {
        int n = n0w + nt * 16 + m;
        float b1v = b1[n];
#pragma unroll
        for (int mt = 0; mt < 2; ++mt)
#pragma unroll
            for (int rg = 0; rg < 4; ++rg)
                Hs[mt * 16 + quad * 4 + rg][n] = f2bs(gelu_exact(acc1[mt][nt][rg] + b1v));
    }
    __syncthreads();
    v4f acc2[2][2];
#pragma unroll
    for (int a = 0; a < 2; ++a)
#pragma unroll
        for (int b = 0; b < 2; ++b) acc2[a][b] = (v4f){0.f, 0.f, 0.f, 0.f};
    const int ntb = wv * 2;
#pragma unroll
    for (int ks = 0; ks < 16; ++ks) {
        v8s a0 = *(const v8s*)&Hs[m][ks * 32 + quad * 8];
        v8s a1 = *(const v8s*)&Hs[m + 16][ks * 32 + quad * 8];
        const v8s* bp = (const v8s*)w2f + ((size_t)ks * 8 + ntb) * 64 + lane;
#pragma unroll
        for (int nt = 0; nt < 2; ++nt) {
            v8s b = bp[nt * 64];
            acc2[0][nt] = __builtin_amdgcn_mfma_f32_16x16x32_bf16(a0, b, acc2[0][nt], 0, 0, 0);
            acc2[1][nt] = __builtin_amdgcn_mfma_f32_16x16x32_bf16(a1, b, acc2[1][nt], 0, 0, 0);
        }
    }
#pragma unroll
    for (int nt = 0; nt < 2; ++nt) {
        int n = (ntb + nt) * 16 + m;
        float b2v = b2[n];
#pragma unroll
        for (int mt = 0; mt < 2; ++mt)
#pragma unroll
            for (int rg = 0; rg < 4; ++rg) {
                int row = mt * 16 + quad * 4 + rg;
                size_t gi = (row0 + row) * 128 + n;
                outp[gi] = yws[gi] + b2v + acc2[mt][nt][rg];
            }
    }
}

extern "C" void kernel_launch(void* const* d_in, const int* in_sizes, int n_in,
                              void* d_out, int out_size, void* d_ws, size_t ws_size,
                              hipStream_t stream) {
    const float* x      = (const float*)d_in[0];
    const float* ctx    = (const float*)d_in[1];
    const float* ctxn_g = (const float*)d_in[2];
    const float* ctxn_b = (const float*)d_in[3];
    const float* ctxp_w = (const float*)d_in[4];
    const float* ctxp_b = (const float*)d_in[5];
    const float* n1_g   = (const float*)d_in[6];
    const float* n1_b   = (const float*)d_in[7];
    const float* n1v_g  = (const float*)d_in[8];
    const float* n1v_b  = (const float*)d_in[9];
    const float* q_w    = (const float*)d_in[10];
    const float* q_b    = (const float*)d_in[11];
    const float* k_w    = (const float*)d_in[12];
    const float* k_b    = (const float*)d_in[13];
    const float* v_w    = (const float*)d_in[14];
    const float* v_b    = (const float*)d_in[15];
    const float* rpb    = (const float*)d_in[16];
    const float* proj_w = (const float*)d_in[17];
    const float* proj_b = (const float*)d_in[18];
    const float* n2_g   = (const float*)d_in[19];
    const float* n2_b   = (const float*)d_in[20];
    const float* f1_w   = (const float*)d_in[21];
    const float* f1_b   = (const float*)d_in[22];
    const float* f2_w   = (const float*)d_in[23];
    const float* f2_b   = (const float*)d_in[24];
    float* out = (float*)d_out;

    char* ws = (char*)d_ws;
    bf16*      ctxp = (bf16*)(ws);                 //  8,388,608 B  (B,HW,64) bf16
    _Float16*  qws  = (_Float16*)(ws + 8388608);   // 16,777,216 B  (B,8,HW,16) f16
    _Float16*  kws  = (_Float16*)(ws + 25165824);  // 16,777,216 B
    _Float16*  vws  = (_Float16*)(ws + 41943040);  // 16,777,216 B
    bf16*      ows  = (bf16*)(ws + 58720256);      // 16,777,216 B  (B,HW,128) bf16
    float*     yws  = (float*)(ws + 8388608);      // aliases qws+kws (dead after attn)
    char* frag = ws + 75497472;
    bf16*  w1f  = (bf16*)(frag);                   // 131,072 B
    bf16*  w2f  = (bf16*)(frag + 131072);          // 131,072 B
    bf16*  qwf  = (bf16*)(frag + 262144);          //  49,152 B
    bf16*  kwf  = (bf16*)(frag + 311296);          //  49,152 B
    bf16*  vwf  = (bf16*)(frag + 360448);          //  32,768 B
    bf16*  pwf  = (bf16*)(frag + 393216);          //  65,536 B
    float* rpl2 = (float*)(frag + 458752);         //  14,112 B (8*441 fp32)
    // ctx-GEMM prep lives in the qws region: it is fully consumed by k_ctx,
    // which completes (stream-ordered) before k_qkv writes qws.
    bf16*  wgf  = (bf16*)(ws + 8388608);           //  32,768 B  g.W fragments (K=256,N=64)
    float* cgw  = (float*)(ws + 8388608 + 32768);  //     256 B  sum_e g*W
    float* cbw  = (float*)(ws + 8388608 + 33024);  //     256 B  sum_e b*W + pb

    k_repack<<<256, 256, 0, stream>>>(f1_w, w1f, 128, 512);
    k_repack<<<256, 256, 0, stream>>>(f2_w, w2f, 512, 128);
    k_repack<<<96,  256, 0, stream>>>(q_w,  qwf, 192, 128);
    k_repack<<<96,  256, 0, stream>>>(k_w,  kwf, 192, 128);
    k_repack<<<64,  256, 0, stream>>>(v_w,  vwf, 128, 128);
    k_repack<<<128, 256, 0, stream>>>(proj_w, pwf, 256, 128);
    k_repack_g<<<64, 256, 0, stream>>>(ctxp_w, ctxn_g, wgf, 256, 64);
    k_ctxc<<<1, 256, 0, stream>>>(ctxp_w, ctxn_g, ctxn_b, ctxp_b, cgw, cbw);
    k_rpb<<<14, 256, 0, stream>>>(rpb, rpl2, 8 * 441);
    k_ctx<<<2048, 256, 0, stream>>>(ctx, cgw, cbw, wgf, ctxp);
    k_qkv<<<2048, 256, 0, stream>>>(x, ctxp, n1_g, n1_b, n1v_g, n1v_b,
                                    qwf, q_b, kwf, k_b, vwf, v_b, qws, kws, vws);
    k_attn<<<512, 512, 0, stream>>>(qws, kws, vws, rpl2, ows);
    k_proj<<<2048, 256, 0, stream>>>(x, ows, pwf, proj_b, yws);
    k_ffn<<<2048, 256, 0, stream>>>(yws, n2_g, n2_b, w1f, f1_b, w2f, f2_b, out);
}

// Round 6
// 374.602 us; speedup vs baseline: 1.1248x; 1.0250x over previous
//
#include <hip/hip_runtime.h>
#include <hip/hip_bf16.h>
#include <math.h>

typedef __hip_bfloat16 bf16;
typedef float v2f __attribute__((ext_vector_type(2)));
typedef float v4f __attribute__((ext_vector_type(4)));
typedef short v8s __attribute__((ext_vector_type(8)));
typedef _Float16 v2h __attribute__((ext_vector_type(2)));

__device__ __forceinline__ float b2f(bf16 v) { return __bfloat162float(v); }
__device__ __forceinline__ float unpk_lo(unsigned u) { return __uint_as_float(u << 16); }
__device__ __forceinline__ float unpk_hi(unsigned u) { return __uint_as_float(u & 0xffff0000u); }
__device__ __forceinline__ v2f unpk2(unsigned u) {
    v2f r; r.x = __uint_as_float(u << 16); r.y = __uint_as_float(u & 0xffff0000u); return r;
}
__device__ __forceinline__ unsigned pk2(float a, float b) {
    unsigned ua = __float_as_uint(a);
    unsigned ub = __float_as_uint(b);
    ua = (ua + 0x7fffu + ((ua >> 16) & 1u)) >> 16;   // RNE to bf16
    ub = (ub + 0x7fffu + ((ub >> 16) & 1u)) >> 16;
    return ua | (ub << 16);
}
__device__ __forceinline__ short f2bs(float f) {
    unsigned u = __float_as_uint(f);
    u = (u + 0x7fffu + ((u >> 16) & 1u)) >> 16;
    return (short)u;
}
__device__ __forceinline__ short f2hs(float f) {
    union { _Float16 h; short s; } c; c.h = (_Float16)f; return c.s;
}
__device__ __forceinline__ v2h u2h(unsigned u) {
    union { unsigned u; v2h h; } c; c.u = u; return c.h;
}
__device__ __forceinline__ float gelu_exact(float x) {
    return 0.5f * x * (1.f + erff(x * 0.70710678118654752440f));
}

#define LOG2E 1.44269504088896340736f

// ---------------------------------------------------------------------------
// Repack a KxN fp32 weight into bf16 MFMA B-fragments for 16x16x32.
// ---------------------------------------------------------------------------
__global__ __launch_bounds__(256) void k_repack(const float* __restrict__ src,
                                                bf16* __restrict__ dst, int K, int N) {
    int idx = blockIdx.x * 256 + threadIdx.x;
    if (idx >= K * N) return;
    int k = idx / N, n = idx % N;
    int kstep = k >> 5, quad = (k & 31) >> 3, j = k & 7;
    int ntile = n >> 4, nn = n & 15;
    size_t di = ((((size_t)kstep * (N >> 4)) + ntile) * 64 + nn + (quad << 4)) * 8 + j;
    dst[di] = __float2bfloat16(src[idx]);
}

// Same repack but scales row k by g[k] (folds the LN gain into the weight).
__global__ __launch_bounds__(256) void k_repack_g(const float* __restrict__ src,
                                                  const float* __restrict__ g,
                                                  bf16* __restrict__ dst, int K, int N) {
    int idx = blockIdx.x * 256 + threadIdx.x;
    if (idx >= K * N) return;
    int k = idx / N, n = idx % N;
    int kstep = k >> 5, quad = (k & 31) >> 3, j = k & 7;
    int ntile = n >> 4, nn = n & 15;
    size_t di = ((((size_t)kstep * (N >> 4)) + ntile) * 64 + nn + (quad << 4)) * 8 + j;
    dst[di] = __float2bfloat16(src[idx] * g[k]);
}

// LN-fold correction vectors for the ctx projection (K=256, N=64):
//   cgw[n] = sum_e g[e] * W[e][n]
//   cbw[n] = sum_e b[e] * W[e][n] + pb[n]
__global__ __launch_bounds__(256) void k_ctxc(const float* __restrict__ w,
                                              const float* __restrict__ g,
                                              const float* __restrict__ bb,
                                              const float* __restrict__ pb,
                                              float* __restrict__ cgw,
                                              float* __restrict__ cbw) {
    __shared__ float rg_[4][64], rb_[4][64];
    const int n = threadIdx.x & 63, eg = threadIdx.x >> 6;
    float sg = 0.f, sb = 0.f;
    for (int e = eg * 64; e < eg * 64 + 64; ++e) {
        float wv = w[e * 64 + n];
        sg += g[e] * wv;
        sb += bb[e] * wv;
    }
    rg_[eg][n] = sg; rb_[eg][n] = sb;
    __syncthreads();
    if (threadIdx.x < 64) {
        float a = rg_[0][n] + rg_[1][n] + rg_[2][n] + rg_[3][n];
        float c = rb_[0][n] + rb_[1][n] + rb_[2][n] + rb_[3][n];
        cgw[n] = a;
        cbw[n] = c + pb[n];
    }
}

// rpb -> log2e*rpb - 8  (the -8 cancels in softmax normalization; keeps
// unnormalized f16 PV accumulation far from overflow)
__global__ __launch_bounds__(256) void k_rpb(const float* __restrict__ src,
                                             float* __restrict__ dst, int n) {
    int i = blockIdx.x * 256 + threadIdx.x;
    if (i < n) dst[i] = src[i] * LOG2E - 8.0f;
}

// ---------------------------------------------------------------------------
// Kernel 1 (MFMA): ctx projection. LN folded into epilogue.
// ---------------------------------------------------------------------------
__global__ __launch_bounds__(256) void k_ctx(const float* __restrict__ ctx,
                                             const float* __restrict__ cgw,
                                             const float* __restrict__ cbw,
                                             const bf16* __restrict__ wgf,
                                             bf16* __restrict__ outp) {
    __shared__ short As[32][264];
    __shared__ float redS[8][32];
    __shared__ float redQ[8][32];
    __shared__ float smu[32], srs[32];
    const int t = threadIdx.x;
    const int b = blockIdx.x >> 7;
    const int hw0 = (blockIdx.x & 127) << 5;
    {
        const int r = t & 31, li = t >> 5;
        const float* src = ctx + ((size_t)b * 256 + li * 32) * 4096 + hw0 + r;
        float v[32];
        float s = 0.f, q = 0.f;
#pragma unroll
        for (int j = 0; j < 32; ++j) {
            float x = src[(size_t)j * 4096];
            v[j] = x; s += x; q += x * x;
        }
        redS[li][r] = s;
        redQ[li][r] = q;
        v8s p0, p1, p2, p3;
#pragma unroll
        for (int j = 0; j < 8; ++j) p0[j] = f2bs(v[j]);
#pragma unroll
        for (int j = 0; j < 8; ++j) p1[j] = f2bs(v[8 + j]);
#pragma unroll
        for (int j = 0; j < 8; ++j) p2[j] = f2bs(v[16 + j]);
#pragma unroll
        for (int j = 0; j < 8; ++j) p3[j] = f2bs(v[24 + j]);
        v8s* dst = (v8s*)&As[r][li * 32];
        dst[0] = p0; dst[1] = p1; dst[2] = p2; dst[3] = p3;
    }
    __syncthreads();
    if (t < 32) {
        float s = 0.f, q = 0.f;
#pragma unroll
        for (int k = 0; k < 8; ++k) { s += redS[k][t]; q += redQ[k][t]; }
        float mu = s * (1.f / 256.f);
        float var = q * (1.f / 256.f) - mu * mu;
        smu[t] = mu;
        srs[t] = rsqrtf(var + 1e-5f);
    }
    __syncthreads();
    const int lane = t & 63, wv = t >> 6;
    const int m = lane & 15, quad = lane >> 4;
    v4f acc0 = (v4f){0.f, 0.f, 0.f, 0.f};
    v4f acc1 = (v4f){0.f, 0.f, 0.f, 0.f};
#pragma unroll
    for (int ks = 0; ks < 8; ++ks) {
        v8s a0 = *(const v8s*)&As[m][ks * 32 + quad * 8];
        v8s a1 = *(const v8s*)&As[m + 16][ks * 32 + quad * 8];
        v8s bfr = ((const v8s*)wgf)[((size_t)ks * 4 + wv) * 64 + lane];
        acc0 = __builtin_amdgcn_mfma_f32_16x16x32_bf16(a0, bfr, acc0, 0, 0, 0);
        acc1 = __builtin_amdgcn_mfma_f32_16x16x32_bf16(a1, bfr, acc1, 0, 0, 0);
    }
    const int n = wv * 16 + m;
    const float cg = cgw[n], cb = cbw[n];
    short* obase = (short*)outp + ((size_t)b * 4096 + hw0) * 64 + n;
#pragma unroll
    for (int rg = 0; rg < 4; ++rg) {
        int row = quad * 4 + rg;
        float o = srs[row] * (acc0[rg] - smu[row] * cg) + cb;
        obase[(size_t)row * 64] = f2bs(o);
    }
#pragma unroll
    for (int rg = 0; rg < 4; ++rg) {
        int row = 16 + quad * 4 + rg;
        float o = srs[row] * (acc1[rg] - smu[row] * cg) + cb;
        obase[(size_t)row * 64] = f2bs(o);
    }
}

// ---------------------------------------------------------------------------
// Kernel 2 (MFMA): LN(concat(x,ctx),192) -> q,k ; LN(x,128) -> v.
// Epilogue LDS-transposes and stores 6 coalesced uint4/thread instead of
// 48 scalar 2B stores (1KB contiguous segments per wave store).
// ---------------------------------------------------------------------------
__global__ __launch_bounds__(256) void k_qkv(const float* __restrict__ x,
                                             const bf16* __restrict__ ctxp,
                                             const float* __restrict__ n1g, const float* __restrict__ n1b,
                                             const float* __restrict__ nvg, const float* __restrict__ nvb,
                                             const bf16* __restrict__ qwf, const float* __restrict__ qb,
                                             const bf16* __restrict__ kwf, const float* __restrict__ kb,
                                             const bf16* __restrict__ vwf, const float* __restrict__ vb,
                                             _Float16* __restrict__ qo, _Float16* __restrict__ ko,
                                             _Float16* __restrict__ vo) {
    // phase 1/2: Aqk = SM[0..6400) [32][200], Av = SM[6400..10752) [32][136]
    // phase 3:   Tq/Tk/Tv = SM + {0,4352,8704}, each [32][136] f16
    __shared__ short SM[13056];
    short* Aqk = SM;
    short* Av  = SM + 6400;
    const int t = threadIdx.x;
    const size_t row0 = (size_t)blockIdx.x * 32;
    {
        const int r = t >> 3, li = t & 7;
        const float* xr = x + (row0 + r) * 128 + li * 16;
        float v[16];
        float sx1 = 0.f, sx2 = 0.f;
#pragma unroll
        for (int k4 = 0; k4 < 4; ++k4) {
            float4 vv = *(const float4*)(xr + 4 * k4);
            v[4 * k4 + 0] = vv.x; v[4 * k4 + 1] = vv.y; v[4 * k4 + 2] = vv.z; v[4 * k4 + 3] = vv.w;
            sx1 += vv.x + vv.y + vv.z + vv.w;
            sx2 += vv.x * vv.x + vv.y * vv.y + vv.z * vv.z + vv.w * vv.w;
        }
        float cv[8];
        float sc1 = 0.f, sc2 = 0.f;
        {
            uint4 cu = *(const uint4*)(ctxp + (row0 + r) * 64 + li * 8);
            v2f p0 = unpk2(cu.x), p1 = unpk2(cu.y), p2 = unpk2(cu.z), p3 = unpk2(cu.w);
            cv[0] = p0.x; cv[1] = p0.y; cv[2] = p1.x; cv[3] = p1.y;
            cv[4] = p2.x; cv[5] = p2.y; cv[6] = p3.x; cv[7] = p3.y;
#pragma unroll
            for (int k = 0; k < 8; ++k) { sc1 += cv[k]; sc2 += cv[k] * cv[k]; }
        }
#pragma unroll
        for (int o = 1; o < 8; o <<= 1) {
            sx1 += __shfl_xor(sx1, o); sx2 += __shfl_xor(sx2, o);
            sc1 += __shfl_xor(sc1, o); sc2 += __shfl_xor(sc2, o);
        }
        float mu  = (sx1 + sc1) * (1.f / 192.f);
        float rs  = rsqrtf((sx2 + sc2) * (1.f / 192.f) - mu * mu + 1e-5f);
        float muv = sx1 * (1.f / 128.f);
        float rsv = rsqrtf(sx2 * (1.f / 128.f) - muv * muv + 1e-5f);
        v8s q0, q1, vv0, vv1, cc;
#pragma unroll
        for (int k = 0; k < 8; ++k) {
            int c = li * 16 + k;
            q0[k]  = f2bs((v[k] - mu) * rs * n1g[c] + n1b[c]);
            vv0[k] = f2bs((v[k] - muv) * rsv * nvg[c] + nvb[c]);
        }
#pragma unroll
        for (int k = 0; k < 8; ++k) {
            int c = li * 16 + 8 + k;
            q1[k]  = f2bs((v[8 + k] - mu) * rs * n1g[c] + n1b[c]);
            vv1[k] = f2bs((v[8 + k] - muv) * rsv * nvg[c] + nvb[c]);
        }
#pragma unroll
        for (int k = 0; k < 8; ++k) {
            int c = 128 + li * 8 + k;
            cc[k] = f2bs((cv[k] - mu) * rs * n1g[c] + n1b[c]);
        }
        *(v8s*)&Aqk[r * 200 + li * 16]      = q0;
        *(v8s*)&Aqk[r * 200 + li * 16 + 8]  = q1;
        *(v8s*)&Aqk[r * 200 + 128 + li * 8] = cc;
        *(v8s*)&Av[r * 136 + li * 16]       = vv0;
        *(v8s*)&Av[r * 136 + li * 16 + 8]   = vv1;
    }
    __syncthreads();
    const int lane = t & 63, wv = t >> 6;
    const int m = lane & 15, quad = lane >> 4;
    const int ntb = wv * 2;
    v4f aq[2][2], ak[2][2], av[2][2];
#pragma unroll
    for (int a = 0; a < 2; ++a)
#pragma unroll
        for (int b = 0; b < 2; ++b) {
            aq[a][b] = (v4f){0.f, 0.f, 0.f, 0.f};
            ak[a][b] = (v4f){0.f, 0.f, 0.f, 0.f};
            av[a][b] = (v4f){0.f, 0.f, 0.f, 0.f};
        }
#pragma unroll
    for (int ks = 0; ks < 6; ++ks) {
        v8s a0 = *(const v8s*)&Aqk[m * 200 + ks * 32 + quad * 8];
        v8s a1 = *(const v8s*)&Aqk[(m + 16) * 200 + ks * 32 + quad * 8];
        const v8s* bpq = (const v8s*)qwf + ((size_t)ks * 8 + ntb) * 64 + lane;
        const v8s* bpk = (const v8s*)kwf + ((size_t)ks * 8 + ntb) * 64 + lane;
#pragma unroll
        for (int nt = 0; nt < 2; ++nt) {
            v8s bq = bpq[nt * 64];
            v8s bk = bpk[nt * 64];
            aq[0][nt] = __builtin_amdgcn_mfma_f32_16x16x32_bf16(a0, bq, aq[0][nt], 0, 0, 0);
            aq[1][nt] = __builtin_amdgcn_mfma_f32_16x16x32_bf16(a1, bq, aq[1][nt], 0, 0, 0);
            ak[0][nt] = __builtin_amdgcn_mfma_f32_16x16x32_bf16(a0, bk, ak[0][nt], 0, 0, 0);
            ak[1][nt] = __builtin_amdgcn_mfma_f32_16x16x32_bf16(a1, bk, ak[1][nt], 0, 0, 0);
        }
    }
#pragma unroll
    for (int ks = 0; ks < 4; ++ks) {
        v8s a0 = *(const v8s*)&Av[m * 136 + ks * 32 + quad * 8];
        v8s a1 = *(const v8s*)&Av[(m + 16) * 136 + ks * 32 + quad * 8];
        const v8s* bpv = (const v8s*)vwf + ((size_t)ks * 8 + ntb) * 64 + lane;
#pragma unroll
        for (int nt = 0; nt < 2; ++nt) {
            v8s bv = bpv[nt * 64];
            av[0][nt] = __builtin_amdgcn_mfma_f32_16x16x32_bf16(a0, bv, av[0][nt], 0, 0, 0);
            av[1][nt] = __builtin_amdgcn_mfma_f32_16x16x32_bf16(a1, bv, av[1][nt], 0, 0, 0);
        }
    }
    __syncthreads();    // Aqk/Av dead; reuse SM as transpose buffers
    short* Tq = SM;
    short* Tk = SM + 4352;
    short* Tv = SM + 8704;
#pragma unroll
    for (int nt = 0; nt < 2; ++nt) {
        int n = (ntb + nt) * 16 + m;
        float qbv = qb[n], kbv = kb[n], vbv = vb[n];
#pragma unroll
        for (int mt = 0; mt < 2; ++mt)
#pragma unroll
            for (int rg = 0; rg < 4; ++rg) {
                int row = mt * 16 + quad * 4 + rg;
                Tq[row * 136 + n] = f2hs((aq[mt][nt][rg] + qbv) * (0.25f * LOG2E));
                Tk[row * 136 + n] = f2hs(ak[mt][nt][rg] + kbv);
                Tv[row * 136 + n] = f2hs(av[mt][nt][rg] + vbv);
            }
    }
    __syncthreads();
    {
        const int h = t >> 5, w = t & 31;
        const size_t qrow = row0 + w;
        const int bq = (int)(qrow >> 12), hw = (int)(qrow & 4095);
        const size_t ob = (((size_t)bq * 8 + h) * 4096 + hw) * 16;
        *(uint4*)(qo + ob)     = *(const uint4*)&Tq[w * 136 + h * 16];
        *(uint4*)(qo + ob + 8) = *(const uint4*)&Tq[w * 136 + h * 16 + 8];
        *(uint4*)(ko + ob)     = *(const uint4*)&Tk[w * 136 + h * 16];
        *(uint4*)(ko + ob + 8) = *(const uint4*)&Tk[w * 136 + h * 16 + 8];
        *(uint4*)(vo + ob)     = *(const uint4*)&Tv[w * 136 + h * 16];
        *(uint4*)(vo + ob + 8) = *(const uint4*)&Tv[w * 136 + h * 16 + 8];
    }
}

// ---------------------------------------------------------------------------
// Kernel 3: neighborhood attention (r1-proven config: 1 query/thread,
// 256 threads, 71.7KB LDS -> 2 blocks/CU, measured 73.4us).
// ---------------------------------------------------------------------------
__global__ __launch_bounds__(256) void k_attn(const _Float16* __restrict__ qws,
                                              const _Float16* __restrict__ kws,
                                              const _Float16* __restrict__ vws,
                                              const float* __restrict__ rpbl2,
                                              bf16* __restrict__ ows) {
    __shared__ unsigned ktv[14][64][20];   // [0..7]=k f16x16, [8..15]=v, [16..19] pad
    const int tid  = threadIdx.x;
    const int bh   = blockIdx.x >> 4;
    const int i0   = (blockIdx.x & 15) << 2;
    const int head = bh & 7;
    int start_min = i0 - 5; if (start_min < 0) start_min = 0; if (start_min > 53) start_min = 53;
    const unsigned* ku = (const unsigned*)kws;
    const unsigned* vu = (const unsigned*)vws;
    const size_t gbase = ((size_t)bh * 4096 + (size_t)start_min * 64) * 8;
    for (int idx = tid; idx < 1792; idx += 256) {
        int a = idx >> 7, rem = idx & 127, col = rem >> 1, h4 = (rem & 1) * 4;
        if (start_min + a < 64) {
            *(uint4*)&ktv[a][col][h4]     = *(const uint4*)(ku + gbase + (size_t)a * 512 + col * 8 + h4);
            *(uint4*)&ktv[a][col][8 + h4] = *(const uint4*)(vu + gbase + (size_t)a * 512 + col * 8 + h4);
        }
    }
    __syncthreads();
    const int wv = tid >> 6;
    const int j  = tid & 63;
    const int i  = i0 + wv;
    int start_i = i - 5; if (start_i < 0) start_i = 0; if (start_i > 53) start_i = 53;
    const int off = start_i - start_min;
    v2h qh[8];
    {
        const uint4* qp = (const uint4*)(qws + ((size_t)bh * 4096 + i * 64 + j) * 16);
        uint4 q0 = qp[0], q1 = qp[1];
        qh[0] = u2h(q0.x); qh[1] = u2h(q0.y); qh[2] = u2h(q0.z); qh[3] = u2h(q0.w);
        qh[4] = u2h(q1.x); qh[5] = u2h(q1.y); qh[6] = u2h(q1.z); qh[7] = u2h(q1.w);
    }
    int start_j = j - 5; if (start_j < 0) start_j = 0; if (start_j > 53) start_j = 53;
    float l = 0.f;
    v2h acc[8];
#pragma unroll
    for (int d = 0; d < 8; ++d) acc[d] = (v2h){(_Float16)0.f, (_Float16)0.f};
    const float* rpb_h = rpbl2 + head * 441 + (start_j - j + 10);
    for (int a = 0; a < 11; ++a) {
        const int r = off + a;
        const float* rb = rpb_h + (start_i + a - i + 10) * 21;
#pragma unroll
        for (int c = 0; c < 11; ++c) {
            const unsigned* cp = ktv[r][start_j + c];
            uint4 k0 = *(const uint4*)(cp);
            uint4 k1 = *(const uint4*)(cp + 4);
            uint4 v0 = *(const uint4*)(cp + 8);
            uint4 v1 = *(const uint4*)(cp + 12);
            float sa = __builtin_amdgcn_fdot2(qh[0], u2h(k0.x), rb[c], false);
            sa = __builtin_amdgcn_fdot2(qh[1], u2h(k0.y), sa, false);
            sa = __builtin_amdgcn_fdot2(qh[2], u2h(k0.z), sa, false);
            sa = __builtin_amdgcn_fdot2(qh[3], u2h(k0.w), sa, false);
            float sb = __builtin_amdgcn_fdot2(qh[4], u2h(k1.x), 0.f, false);
            sb = __builtin_amdgcn_fdot2(qh[5], u2h(k1.y), sb, false);
            sb = __builtin_amdgcn_fdot2(qh[6], u2h(k1.z), sb, false);
            sb = __builtin_amdgcn_fdot2(qh[7], u2h(k1.w), sb, false);
            float p = __builtin_amdgcn_exp2f(sa + sb);
            l += p;
            _Float16 ph = (_Float16)p;
            v2h p2 = {ph, ph};
            acc[0] += u2h(v0.x) * p2;
            acc[1] += u2h(v0.y) * p2;
            acc[2] += u2h(v0.z) * p2;
            acc[3] += u2h(v0.w) * p2;
            acc[4] += u2h(v1.x) * p2;
            acc[5] += u2h(v1.y) * p2;
            acc[6] += u2h(v1.z) * p2;
            acc[7] += u2h(v1.w) * p2;
        }
    }
    float inv = 1.f / l;
    int b = bh >> 3;
    unsigned* op = (unsigned*)ows + ((size_t)b * 4096 + i * 64 + j) * 64 + head * 8;
#pragma unroll
    for (int d2 = 0; d2 < 8; ++d2)
        op[d2] = pk2((float)acc[d2].x * inv, (float)acc[d2].y * inv);
}

// ---------------------------------------------------------------------------
// Kernel 4 (MFMA, fused proj+ffn):
//   y = x + concat(o,x)@proj_w + proj_b          (y kept in LDS, never HBM)
//   out = y + gelu(LN(y)@f1+b1)@f2 + b2
// Saves 96MB of HBM traffic vs split kernels (yws write + LN read + resid read).
// LDS: RegionA 33,792B (An+Xs -> An2 -> Hs, phase-overlaid) + Ys 16,896B.
// ---------------------------------------------------------------------------
__global__ __launch_bounds__(256) void k_pf(const float* __restrict__ x,
                                            const bf16* __restrict__ ows,
                                            const bf16* __restrict__ pwf,
                                            const float* __restrict__ pb,
                                            const float* __restrict__ g, const float* __restrict__ bb,
                                            const bf16* __restrict__ w1f, const float* __restrict__ b1,
                                            const bf16* __restrict__ w2f, const float* __restrict__ b2,
                                            float* __restrict__ outp) {
    __shared__ short RA[16896];          // 33,792 B overlay region
    __shared__ float Ys[32 * 132];       // 16,896 B (y rows, fp32, pad 132)
    short* An = RA;                      // [32][264] proj staging (o|x bf16)
    float* Xs = (float*)(RA + 8448);     // [32][132] raw x fp32
    const int t = threadIdx.x;
    const size_t row0 = (size_t)blockIdx.x * 32;
    // ---- proj staging ----
    {
        const int r = t >> 3, li = t & 7;
        const uint4* osrc = (const uint4*)(ows + (row0 + r) * 128 + li * 16);
        uint4 o0 = osrc[0], o1 = osrc[1];
        *(uint4*)&An[r * 264 + li * 16]     = o0;
        *(uint4*)&An[r * 264 + li * 16 + 8] = o1;
        const float* xr = x + (row0 + r) * 128 + li * 16;
        v8s xa, xb;
#pragma unroll
        for (int k4 = 0; k4 < 2; ++k4) {
            float4 vv = *(const float4*)(xr + 4 * k4);
            *(float4*)&Xs[r * 132 + li * 16 + 4 * k4] = vv;
            xa[4 * k4 + 0] = f2bs(vv.x); xa[4 * k4 + 1] = f2bs(vv.y);
            xa[4 * k4 + 2] = f2bs(vv.z); xa[4 * k4 + 3] = f2bs(vv.w);
        }
#pragma unroll
        for (int k4 = 0; k4 < 2; ++k4) {
            float4 vv = *(const float4*)(xr + 8 + 4 * k4);
            *(float4*)&Xs[r * 132 + li * 16 + 8 + 4 * k4] = vv;
            xb[4 * k4 + 0] = f2bs(vv.x); xb[4 * k4 + 1] = f2bs(vv.y);
            xb[4 * k4 + 2] = f2bs(vv.z); xb[4 * k4 + 3] = f2bs(vv.w);
        }
        *(v8s*)&An[r * 264 + 128 + li * 16]     = xa;
        *(v8s*)&An[r * 264 + 128 + li * 16 + 8] = xb;
    }
    __syncthreads();
    const int lane = t & 63, wv = t >> 6;
    const int m = lane & 15, quad = lane >> 4;
    const int ntb = wv * 2;
    // ---- proj MFMA ----
    {
        v4f acc[2][2];
#pragma unroll
        for (int a = 0; a < 2; ++a)
#pragma unroll
            for (int b = 0; b < 2; ++b) acc[a][b] = (v4f){0.f, 0.f, 0.f, 0.f};
#pragma unroll
        for (int ks = 0; ks < 8; ++ks) {
            v8s a0 = *(const v8s*)&An[m * 264 + ks * 32 + quad * 8];
            v8s a1 = *(const v8s*)&An[(m + 16) * 264 + ks * 32 + quad * 8];
            const v8s* bp = (const v8s*)pwf + ((size_t)ks * 8 + ntb) * 64 + lane;
#pragma unroll
            for (int nt = 0; nt < 2; ++nt) {
                v8s b = bp[nt * 64];
                acc[0][nt] = __builtin_amdgcn_mfma_f32_16x16x32_bf16(a0, b, acc[0][nt], 0, 0, 0);
                acc[1][nt] = __builtin_amdgcn_mfma_f32_16x16x32_bf16(a1, b, acc[1][nt], 0, 0, 0);
            }
        }
        // y -> Ys (LDS), residual from Xs
#pragma unroll
        for (int nt = 0; nt < 2; ++nt) {
            int n = (ntb + nt) * 16 + m;
            float bv = pb[n];
#pragma unroll
            for (int mt = 0; mt < 2; ++mt)
#pragma unroll
                for (int rg = 0; rg < 4; ++rg) {
                    int row = mt * 16 + quad * 4 + rg;
                    Ys[row * 132 + n] = Xs[row * 132 + n] + bv + acc[mt][nt][rg];
                }
        }
    }
    __syncthreads();    // An/Xs dead; Ys complete
    // ---- LN(y) -> An2 (bf16) ----
    short* An2 = RA;    // [32][136]
    {
        const int r = t >> 3, li = t & 7;
        const float* yr = &Ys[r * 132 + li * 16];
        float v[16];
        float s1 = 0.f, s2 = 0.f;
#pragma unroll
        for (int k = 0; k < 16; ++k) {
            float vv = yr[k];
            v[k] = vv; s1 += vv; s2 += vv * vv;
        }
#pragma unroll
        for (int o = 1; o < 8; o <<= 1) { s1 += __shfl_xor(s1, o); s2 += __shfl_xor(s2, o); }
        float mu = s1 * (1.f / 128.f);
        float rs = rsqrtf(s2 * (1.f / 128.f) - mu * mu + 1e-5f);
        v8s lo, hi;
#pragma unroll
        for (int k = 0; k < 8; ++k) {
            int c = li * 16 + k;
            lo[k] = f2bs((v[k] - mu) * rs * g[c] + bb[c]);
        }
#pragma unroll
        for (int k = 0; k < 8; ++k) {
            int c = li * 16 + 8 + k;
            hi[k] = f2bs((v[8 + k] - mu) * rs * g[c] + bb[c]);
        }
        *(v8s*)&An2[r * 136 + li * 16]     = lo;
        *(v8s*)&An2[r * 136 + li * 16 + 8] = hi;
    }
    __syncthreads();
    // ---- ffn stage 1 ----
    v4f acc1[2][8];
#pragma unroll
    for (int a = 0; a < 2; ++a)
#pragma unroll
        for (int b = 0; b < 8; ++b) acc1[a][b] = (v4f){0.f, 0.f, 0.f, 0.f};
    const int n0w = wv * 128;
#pragma unroll
    for (int ks = 0; ks < 4; ++ks) {
        v8s a0 = *(const v8s*)&An2[m * 136 + ks * 32 + quad * 8];
        v8s a1 = *(const v8s*)&An2[(m + 16) * 136 + ks * 32 + quad * 8];
        const v8s* bp = (const v8s*)w1f + ((size_t)ks * 32 + (n0w >> 4)) * 64 + lane;
#pragma unroll
        for (int nt = 0; nt < 8; ++nt) {
            v8s b = bp[nt * 64];
            acc1[0][nt] = __builtin_amdgcn_mfma_f32_16x16x32_bf16(a0, b, acc1[0][nt], 0, 0, 0);
            acc1[1][nt] = __builtin_amdgcn_mfma_f32_16x16x32_bf16(a1, b, acc1[1][nt], 0, 0, 0);
        }
    }
    __syncthreads();    // An2 dead
    short* Hs = RA;     // [32][520]
#pragma unroll
    for (int nt = 0; nt < 8; ++nt) {
        int n = n0w + nt * 16 + m;
        float b1v = b1[n];
#pragma unroll
        for (int mt = 0; mt < 2; ++mt)
#pragma unroll
            for (int rg = 0; rg < 4; ++rg)
                Hs[(mt * 16 + quad * 4 + rg) * 520 + n] = f2bs(gelu_exact(acc1[mt][nt][rg] + b1v));
    }
    __syncthreads();
    // ---- ffn stage 2 ----
    v4f acc2[2][2];
#pragma unroll
    for (int a = 0; a < 2; ++a)
#pragma unroll
        for (int b = 0; b < 2; ++b) acc2[a][b] = (v4f){0.f, 0.f, 0.f, 0.f};
#pragma unroll
    for (int ks = 0; ks < 16; ++ks) {
        v8s a0 = *(const v8s*)&Hs[m * 520 + ks * 32 + quad * 8];
        v8s a1 = *(const v8s*)&Hs[(m + 16) * 520 + ks * 32 + quad * 8];
        const v8s* bp = (const v8s*)w2f + ((size_t)ks * 8 + ntb) * 64 + lane;
#pragma unroll
        for (int nt = 0; nt < 2; ++nt) {
            v8s b = bp[nt * 64];
            acc2[0][nt] = __builtin_amdgcn_mfma_f32_16x16x32_bf16(a0, b, acc2[0][nt], 0, 0, 0);
            acc2[1][nt] = __builtin_amdgcn_mfma_f32_16x16x32_bf16(a1, b, acc2[1][nt], 0, 0, 0);
        }
    }
#pragma unroll
    for (int nt = 0; nt < 2; ++nt) {
        int n = (ntb + nt) * 16 + m;
        float b2v = b2[n];
#pragma unroll
        for (int mt = 0; mt < 2; ++mt)
#pragma unroll
            for (int rg = 0; rg < 4; ++rg) {
                int row = mt * 16 + quad * 4 + rg;
                size_t gi = (row0 + row) * 128 + n;
                outp[gi] = Ys[row * 132 + n] + b2v + acc2[mt][nt][rg];
            }
    }
}

extern "C" void kernel_launch(void* const* d_in, const int* in_sizes, int n_in,
                              void* d_out, int out_size, void* d_ws, size_t ws_size,
                              hipStream_t stream) {
    const float* x      = (const float*)d_in[0];
    const float* ctx    = (const float*)d_in[1];
    const float* ctxn_g = (const float*)d_in[2];
    const float* ctxn_b = (const float*)d_in[3];
    const float* ctxp_w = (const float*)d_in[4];
    const float* ctxp_b = (const float*)d_in[5];
    const float* n1_g   = (const float*)d_in[6];
    const float* n1_b   = (const float*)d_in[7];
    const float* n1v_g  = (const float*)d_in[8];
    const float* n1v_b  = (const float*)d_in[9];
    const float* q_w    = (const float*)d_in[10];
    const float* q_b    = (const float*)d_in[11];
    const float* k_w    = (const float*)d_in[12];
    const float* k_b    = (const float*)d_in[13];
    const float* v_w    = (const float*)d_in[14];
    const float* v_b    = (const float*)d_in[15];
    const float* rpb    = (const float*)d_in[16];
    const float* proj_w = (const float*)d_in[17];
    const float* proj_b = (const float*)d_in[18];
    const float* n2_g   = (const float*)d_in[19];
    const float* n2_b   = (const float*)d_in[20];
    const float* f1_w   = (const float*)d_in[21];
    const float* f1_b   = (const float*)d_in[22];
    const float* f2_w   = (const float*)d_in[23];
    const float* f2_b   = (const float*)d_in[24];
    float* out = (float*)d_out;

    char* ws = (char*)d_ws;
    bf16*      ctxp = (bf16*)(ws);                 //  8,388,608 B  (B,HW,64) bf16
    _Float16*  qws  = (_Float16*)(ws + 8388608);   // 16,777,216 B  (B,8,HW,16) f16
    _Float16*  kws  = (_Float16*)(ws + 25165824);  // 16,777,216 B
    _Float16*  vws  = (_Float16*)(ws + 41943040);  // 16,777,216 B
    bf16*      ows  = (bf16*)(ws + 58720256);      // 16,777,216 B  (B,HW,128) bf16
    char* frag = ws + 75497472;
    bf16*  w1f  = (bf16*)(frag);                   // 131,072 B
    bf16*  w2f  = (bf16*)(frag + 131072);          // 131,072 B
    bf16*  qwf  = (bf16*)(frag + 262144);          //  49,152 B
    bf16*  kwf  = (bf16*)(frag + 311296);          //  49,152 B
    bf16*  vwf  = (bf16*)(frag + 360448);          //  32,768 B
    bf16*  pwf  = (bf16*)(frag + 393216);          //  65,536 B
    float* rpl2 = (float*)(frag + 458752);         //  14,112 B (8*441 fp32)
    // ctx-GEMM prep lives in the qws region: it is fully consumed by k_ctx,
    // which completes (stream-ordered) before k_qkv writes qws.
    bf16*  wgf  = (bf16*)(ws + 8388608);           //  32,768 B  g.W fragments (K=256,N=64)
    float* cgw  = (float*)(ws + 8388608 + 32768);  //     256 B  sum_e g*W
    float* cbw  = (float*)(ws + 8388608 + 33024);  //     256 B  sum_e b*W + pb

    k_repack<<<256, 256, 0, stream>>>(f1_w, w1f, 128, 512);
    k_repack<<<256, 256, 0, stream>>>(f2_w, w2f, 512, 128);
    k_repack<<<96,  256, 0, stream>>>(q_w,  qwf, 192, 128);
    k_repack<<<96,  256, 0, stream>>>(k_w,  kwf, 192, 128);
    k_repack<<<64,  256, 0, stream>>>(v_w,  vwf, 128, 128);
    k_repack<<<128, 256, 0, stream>>>(proj_w, pwf, 256, 128);
    k_repack_g<<<64, 256, 0, stream>>>(ctxp_w, ctxn_g, wgf, 256, 64);
    k_ctxc<<<1, 256, 0, stream>>>(ctxp_w, ctxn_g, ctxn_b, ctxp_b, cgw, cbw);
    k_rpb<<<14, 256, 0, stream>>>(rpb, rpl2, 8 * 441);
    k_ctx<<<2048, 256, 0, stream>>>(ctx, cgw, cbw, wgf, ctxp);
    k_qkv<<<2048, 256, 0, stream>>>(x, ctxp, n1_g, n1_b, n1v_g, n1v_b,
                                    qwf, q_b, kwf, k_b, vwf, v_b, qws, kws, vws);
    k_attn<<<2048, 256, 0, stream>>>(qws, kws, vws, rpl2, ows);
    k_pf<<<2048, 256, 0, stream>>>(x, ows, pwf, proj_b, n2_g, n2_b,
                                   w1f, f1_b, w2f, f2_b, out);
}

// Round 7
// 348.985 us; speedup vs baseline: 1.2074x; 1.0734x over previous
//
#include <hip/hip_runtime.h>
#include <hip/hip_bf16.h>
#include <math.h>

typedef __hip_bfloat16 bf16;
typedef float v2f __attribute__((ext_vector_type(2)));
typedef float v4f __attribute__((ext_vector_type(4)));
typedef short v8s __attribute__((ext_vector_type(8)));
typedef _Float16 v2h __attribute__((ext_vector_type(2)));

__device__ __forceinline__ float b2f(bf16 v) { return __bfloat162float(v); }
__device__ __forceinline__ float unpk_lo(unsigned u) { return __uint_as_float(u << 16); }
__device__ __forceinline__ float unpk_hi(unsigned u) { return __uint_as_float(u & 0xffff0000u); }
__device__ __forceinline__ v2f unpk2(unsigned u) {
    v2f r; r.x = __uint_as_float(u << 16); r.y = __uint_as_float(u & 0xffff0000u); return r;
}
__device__ __forceinline__ unsigned pk2(float a, float b) {
    unsigned ua = __float_as_uint(a);
    unsigned ub = __float_as_uint(b);
    ua = (ua + 0x7fffu + ((ua >> 16) & 1u)) >> 16;   // RNE to bf16
    ub = (ub + 0x7fffu + ((ub >> 16) & 1u)) >> 16;
    return ua | (ub << 16);
}
__device__ __forceinline__ short f2bs(float f) {
    unsigned u = __float_as_uint(f);
    u = (u + 0x7fffu + ((u >> 16) & 1u)) >> 16;
    return (short)u;
}
__device__ __forceinline__ short f2hs(float f) {
    union { _Float16 h; short s; } c; c.h = (_Float16)f; return c.s;
}
__device__ __forceinline__ v2h u2h(unsigned u) {
    union { unsigned u; v2h h; } c; c.u = u; return c.h;
}
// tanh-form gelu: x*sigmoid(2z), z=0.79788456(x+0.044715x^3).
// 8 VALU instr (2 transcendental) vs ~25 for erff; max abs dev ~3e-4,
// below the bf16 rounding applied to H anyway.
__device__ __forceinline__ float gelu_fast(float x) {
    float u = x * (1.f + 0.044715f * x * x);
    float t = __builtin_amdgcn_exp2f(-2.3022078f * u);
#if __has_builtin(__builtin_amdgcn_rcpf)
    return x * __builtin_amdgcn_rcpf(1.f + t);
#else
    return x / (1.f + t);
#endif
}

#define LOG2E 1.44269504088896340736f

// ---------------------------------------------------------------------------
// One-shot prep kernel: all weight repacks + LN-fold vectors + rpb transform.
// blockIdx ranges: [0,256) f1 | [256,512) f2 | [512,608) q | [608,704) k |
// [704,768) v | [768,896) proj | [896,960) wgf(g-scaled) | [960,974) rpb |
// 974 ctxc. Replaces 9 launches with 1.
// ---------------------------------------------------------------------------
__global__ __launch_bounds__(256) void k_prep(const float* __restrict__ f1_w,
                                              const float* __restrict__ f2_w,
                                              const float* __restrict__ q_w,
                                              const float* __restrict__ k_w,
                                              const float* __restrict__ v_w,
                                              const float* __restrict__ proj_w,
                                              const float* __restrict__ ctxp_w,
                                              const float* __restrict__ ctxn_g,
                                              const float* __restrict__ ctxn_b,
                                              const float* __restrict__ ctxp_b,
                                              const float* __restrict__ rpb,
                                              bf16* __restrict__ w1f, bf16* __restrict__ w2f,
                                              bf16* __restrict__ qwf, bf16* __restrict__ kwf,
                                              bf16* __restrict__ vwf, bf16* __restrict__ pwf,
                                              bf16* __restrict__ wgf,
                                              float* __restrict__ cgw, float* __restrict__ cbw,
                                              float* __restrict__ rpl2) {
    const int blk = blockIdx.x;
    if (blk < 896) {
        const float* src; bf16* dst; int K, N, base;
        if (blk < 256)      { src = f1_w;   dst = w1f; K = 128; N = 512; base = 0;   }
        else if (blk < 512) { src = f2_w;   dst = w2f; K = 512; N = 128; base = 256; }
        else if (blk < 608) { src = q_w;    dst = qwf; K = 192; N = 128; base = 512; }
        else if (blk < 704) { src = k_w;    dst = kwf; K = 192; N = 128; base = 608; }
        else if (blk < 768) { src = v_w;    dst = vwf; K = 128; N = 128; base = 704; }
        else                { src = proj_w; dst = pwf; K = 256; N = 128; base = 768; }
        int idx = (blk - base) * 256 + threadIdx.x;
        if (idx >= K * N) return;
        int k = idx / N, n = idx % N;
        int kstep = k >> 5, quad = (k & 31) >> 3, j = k & 7;
        int ntile = n >> 4, nn = n & 15;
        size_t di = ((((size_t)kstep * (N >> 4)) + ntile) * 64 + nn + (quad << 4)) * 8 + j;
        dst[di] = __float2bfloat16(src[idx]);
    } else if (blk < 960) {
        // wgf: repack ctxp_w (K=256,N=64) with row-scale ctxn_g[k]
        int idx = (blk - 896) * 256 + threadIdx.x;
        const int N = 64;
        int k = idx / N, n = idx % N;
        int kstep = k >> 5, quad = (k & 31) >> 3, j = k & 7;
        int ntile = n >> 4, nn = n & 15;
        size_t di = ((((size_t)kstep * (N >> 4)) + ntile) * 64 + nn + (quad << 4)) * 8 + j;
        wgf[di] = __float2bfloat16(ctxp_w[idx] * ctxn_g[k]);
    } else if (blk < 974) {
        int i = (blk - 960) * 256 + threadIdx.x;
        if (i < 8 * 441) rpl2[i] = rpb[i] * LOG2E - 8.0f;
    } else {
        // ctxc: cgw[n] = sum_e g*W, cbw[n] = sum_e b*W + pb
        __shared__ float rg_[4][64], rb_[4][64];
        const int n = threadIdx.x & 63, eg = threadIdx.x >> 6;
        float sg = 0.f, sb = 0.f;
        for (int e = eg * 64; e < eg * 64 + 64; ++e) {
            float wv = ctxp_w[e * 64 + n];
            sg += ctxn_g[e] * wv;
            sb += ctxn_b[e] * wv;
        }
        rg_[eg][n] = sg; rb_[eg][n] = sb;
        __syncthreads();
        if (threadIdx.x < 64) {
            float a = rg_[0][n] + rg_[1][n] + rg_[2][n] + rg_[3][n];
            float c = rb_[0][n] + rb_[1][n] + rb_[2][n] + rb_[3][n];
            cgw[n] = a;
            cbw[n] = c + ctxp_b[n];
        }
    }
}

// ---------------------------------------------------------------------------
// Kernel 1 (MFMA): ctx projection. LN folded into epilogue.
// ---------------------------------------------------------------------------
__global__ __launch_bounds__(256) void k_ctx(const float* __restrict__ ctx,
                                             const float* __restrict__ cgw,
                                             const float* __restrict__ cbw,
                                             const bf16* __restrict__ wgf,
                                             bf16* __restrict__ outp) {
    __shared__ short As[32][264];
    __shared__ float redS[8][32];
    __shared__ float redQ[8][32];
    __shared__ float smu[32], srs[32];
    const int t = threadIdx.x;
    const int b = blockIdx.x >> 7;
    const int hw0 = (blockIdx.x & 127) << 5;
    {
        const int r = t & 31, li = t >> 5;
        const float* src = ctx + ((size_t)b * 256 + li * 32) * 4096 + hw0 + r;
        float v[32];
        float s = 0.f, q = 0.f;
#pragma unroll
        for (int j = 0; j < 32; ++j) {
            float x = src[(size_t)j * 4096];
            v[j] = x; s += x; q += x * x;
        }
        redS[li][r] = s;
        redQ[li][r] = q;
        v8s p0, p1, p2, p3;
#pragma unroll
        for (int j = 0; j < 8; ++j) p0[j] = f2bs(v[j]);
#pragma unroll
        for (int j = 0; j < 8; ++j) p1[j] = f2bs(v[8 + j]);
#pragma unroll
        for (int j = 0; j < 8; ++j) p2[j] = f2bs(v[16 + j]);
#pragma unroll
        for (int j = 0; j < 8; ++j) p3[j] = f2bs(v[24 + j]);
        v8s* dst = (v8s*)&As[r][li * 32];
        dst[0] = p0; dst[1] = p1; dst[2] = p2; dst[3] = p3;
    }
    __syncthreads();
    if (t < 32) {
        float s = 0.f, q = 0.f;
#pragma unroll
        for (int k = 0; k < 8; ++k) { s += redS[k][t]; q += redQ[k][t]; }
        float mu = s * (1.f / 256.f);
        float var = q * (1.f / 256.f) - mu * mu;
        smu[t] = mu;
        srs[t] = rsqrtf(var + 1e-5f);
    }
    __syncthreads();
    const int lane = t & 63, wv = t >> 6;
    const int m = lane & 15, quad = lane >> 4;
    v4f acc0 = (v4f){0.f, 0.f, 0.f, 0.f};
    v4f acc1 = (v4f){0.f, 0.f, 0.f, 0.f};
#pragma unroll
    for (int ks = 0; ks < 8; ++ks) {
        v8s a0 = *(const v8s*)&As[m][ks * 32 + quad * 8];
        v8s a1 = *(const v8s*)&As[m + 16][ks * 32 + quad * 8];
        v8s bfr = ((const v8s*)wgf)[((size_t)ks * 4 + wv) * 64 + lane];
        acc0 = __builtin_amdgcn_mfma_f32_16x16x32_bf16(a0, bfr, acc0, 0, 0, 0);
        acc1 = __builtin_amdgcn_mfma_f32_16x16x32_bf16(a1, bfr, acc1, 0, 0, 0);
    }
    const int n = wv * 16 + m;
    const float cg = cgw[n], cb = cbw[n];
    short* obase = (short*)outp + ((size_t)b * 4096 + hw0) * 64 + n;
#pragma unroll
    for (int rg = 0; rg < 4; ++rg) {
        int row = quad * 4 + rg;
        float o = srs[row] * (acc0[rg] - smu[row] * cg) + cb;
        obase[(size_t)row * 64] = f2bs(o);
    }
#pragma unroll
    for (int rg = 0; rg < 4; ++rg) {
        int row = 16 + quad * 4 + rg;
        float o = srs[row] * (acc1[rg] - smu[row] * cg) + cb;
        obase[(size_t)row * 64] = f2bs(o);
    }
}

// ---------------------------------------------------------------------------
// Kernel 2 (MFMA): LN(concat(x,ctx),192) -> q,k ; LN(x,128) -> v.
// Epilogue LDS-transposes and stores 6 coalesced uint4/thread.
// ---------------------------------------------------------------------------
__global__ __launch_bounds__(256) void k_qkv(const float* __restrict__ x,
                                             const bf16* __restrict__ ctxp,
                                             const float* __restrict__ n1g, const float* __restrict__ n1b,
                                             const float* __restrict__ nvg, const float* __restrict__ nvb,
                                             const bf16* __restrict__ qwf, const float* __restrict__ qb,
                                             const bf16* __restrict__ kwf, const float* __restrict__ kb,
                                             const bf16* __restrict__ vwf, const float* __restrict__ vb,
                                             _Float16* __restrict__ qo, _Float16* __restrict__ ko,
                                             _Float16* __restrict__ vo) {
    __shared__ short SM[13056];
    short* Aqk = SM;
    short* Av  = SM + 6400;
    const int t = threadIdx.x;
    const size_t row0 = (size_t)blockIdx.x * 32;
    {
        const int r = t >> 3, li = t & 7;
        const float* xr = x + (row0 + r) * 128 + li * 16;
        float v[16];
        float sx1 = 0.f, sx2 = 0.f;
#pragma unroll
        for (int k4 = 0; k4 < 4; ++k4) {
            float4 vv = *(const float4*)(xr + 4 * k4);
            v[4 * k4 + 0] = vv.x; v[4 * k4 + 1] = vv.y; v[4 * k4 + 2] = vv.z; v[4 * k4 + 3] = vv.w;
            sx1 += vv.x + vv.y + vv.z + vv.w;
            sx2 += vv.x * vv.x + vv.y * vv.y + vv.z * vv.z + vv.w * vv.w;
        }
        float cv[8];
        float sc1 = 0.f, sc2 = 0.f;
        {
            uint4 cu = *(const uint4*)(ctxp + (row0 + r) * 64 + li * 8);
            v2f p0 = unpk2(cu.x), p1 = unpk2(cu.y), p2 = unpk2(cu.z), p3 = unpk2(cu.w);
            cv[0] = p0.x; cv[1] = p0.y; cv[2] = p1.x; cv[3] = p1.y;
            cv[4] = p2.x; cv[5] = p2.y; cv[6] = p3.x; cv[7] = p3.y;
#pragma unroll
            for (int k = 0; k < 8; ++k) { sc1 += cv[k]; sc2 += cv[k] * cv[k]; }
        }
#pragma unroll
        for (int o = 1; o < 8; o <<= 1) {
            sx1 += __shfl_xor(sx1, o); sx2 += __shfl_xor(sx2, o);
            sc1 += __shfl_xor(sc1, o); sc2 += __shfl_xor(sc2, o);
        }
        float mu  = (sx1 + sc1) * (1.f / 192.f);
        float rs  = rsqrtf((sx2 + sc2) * (1.f / 192.f) - mu * mu + 1e-5f);
        float muv = sx1 * (1.f / 128.f);
        float rsv = rsqrtf(sx2 * (1.f / 128.f) - muv * muv + 1e-5f);
        v8s q0, q1, vv0, vv1, cc;
#pragma unroll
        for (int k = 0; k < 8; ++k) {
            int c = li * 16 + k;
            q0[k]  = f2bs((v[k] - mu) * rs * n1g[c] + n1b[c]);
            vv0[k] = f2bs((v[k] - muv) * rsv * nvg[c] + nvb[c]);
        }
#pragma unroll
        for (int k = 0; k < 8; ++k) {
            int c = li * 16 + 8 + k;
            q1[k]  = f2bs((v[8 + k] - mu) * rs * n1g[c] + n1b[c]);
            vv1[k] = f2bs((v[8 + k] - muv) * rsv * nvg[c] + nvb[c]);
        }
#pragma unroll
        for (int k = 0; k < 8; ++k) {
            int c = 128 + li * 8 + k;
            cc[k] = f2bs((cv[k] - mu) * rs * n1g[c] + n1b[c]);
        }
        *(v8s*)&Aqk[r * 200 + li * 16]      = q0;
        *(v8s*)&Aqk[r * 200 + li * 16 + 8]  = q1;
        *(v8s*)&Aqk[r * 200 + 128 + li * 8] = cc;
        *(v8s*)&Av[r * 136 + li * 16]       = vv0;
        *(v8s*)&Av[r * 136 + li * 16 + 8]   = vv1;
    }
    __syncthreads();
    const int lane = t & 63, wv = t >> 6;
    const int m = lane & 15, quad = lane >> 4;
    const int ntb = wv * 2;
    v4f aq[2][2], ak[2][2], av[2][2];
#pragma unroll
    for (int a = 0; a < 2; ++a)
#pragma unroll
        for (int b = 0; b < 2; ++b) {
            aq[a][b] = (v4f){0.f, 0.f, 0.f, 0.f};
            ak[a][b] = (v4f){0.f, 0.f, 0.f, 0.f};
            av[a][b] = (v4f){0.f, 0.f, 0.f, 0.f};
        }
#pragma unroll
    for (int ks = 0; ks < 6; ++ks) {
        v8s a0 = *(const v8s*)&Aqk[m * 200 + ks * 32 + quad * 8];
        v8s a1 = *(const v8s*)&Aqk[(m + 16) * 200 + ks * 32 + quad * 8];
        const v8s* bpq = (const v8s*)qwf + ((size_t)ks * 8 + ntb) * 64 + lane;
        const v8s* bpk = (const v8s*)kwf + ((size_t)ks * 8 + ntb) * 64 + lane;
#pragma unroll
        for (int nt = 0; nt < 2; ++nt) {
            v8s bq = bpq[nt * 64];
            v8s bk = bpk[nt * 64];
            aq[0][nt] = __builtin_amdgcn_mfma_f32_16x16x32_bf16(a0, bq, aq[0][nt], 0, 0, 0);
            aq[1][nt] = __builtin_amdgcn_mfma_f32_16x16x32_bf16(a1, bq, aq[1][nt], 0, 0, 0);
            ak[0][nt] = __builtin_amdgcn_mfma_f32_16x16x32_bf16(a0, bk, ak[0][nt], 0, 0, 0);
            ak[1][nt] = __builtin_amdgcn_mfma_f32_16x16x32_bf16(a1, bk, ak[1][nt], 0, 0, 0);
        }
    }
#pragma unroll
    for (int ks = 0; ks < 4; ++ks) {
        v8s a0 = *(const v8s*)&Av[m * 136 + ks * 32 + quad * 8];
        v8s a1 = *(const v8s*)&Av[(m + 16) * 136 + ks * 32 + quad * 8];
        const v8s* bpv = (const v8s*)vwf + ((size_t)ks * 8 + ntb) * 64 + lane;
#pragma unroll
        for (int nt = 0; nt < 2; ++nt) {
            v8s bv = bpv[nt * 64];
            av[0][nt] = __builtin_amdgcn_mfma_f32_16x16x32_bf16(a0, bv, av[0][nt], 0, 0, 0);
            av[1][nt] = __builtin_amdgcn_mfma_f32_16x16x32_bf16(a1, bv, av[1][nt], 0, 0, 0);
        }
    }
    __syncthreads();    // Aqk/Av dead; reuse SM as transpose buffers
    short* Tq = SM;
    short* Tk = SM + 4352;
    short* Tv = SM + 8704;
#pragma unroll
    for (int nt = 0; nt < 2; ++nt) {
        int n = (ntb + nt) * 16 + m;
        float qbv = qb[n], kbv = kb[n], vbv = vb[n];
#pragma unroll
        for (int mt = 0; mt < 2; ++mt)
#pragma unroll
            for (int rg = 0; rg < 4; ++rg) {
                int row = mt * 16 + quad * 4 + rg;
                Tq[row * 136 + n] = f2hs((aq[mt][nt][rg] + qbv) * (0.25f * LOG2E));
                Tk[row * 136 + n] = f2hs(ak[mt][nt][rg] + kbv);
                Tv[row * 136 + n] = f2hs(av[mt][nt][rg] + vbv);
            }
    }
    __syncthreads();
    {
        const int h = t >> 5, w = t & 31;
        const size_t qrow = row0 + w;
        const int bq = (int)(qrow >> 12), hw = (int)(qrow & 4095);
        const size_t ob = (((size_t)bq * 8 + h) * 4096 + hw) * 16;
        *(uint4*)(qo + ob)     = *(const uint4*)&Tq[w * 136 + h * 16];
        *(uint4*)(qo + ob + 8) = *(const uint4*)&Tq[w * 136 + h * 16 + 8];
        *(uint4*)(ko + ob)     = *(const uint4*)&Tk[w * 136 + h * 16];
        *(uint4*)(ko + ob + 8) = *(const uint4*)&Tk[w * 136 + h * 16 + 8];
        *(uint4*)(vo + ob)     = *(const uint4*)&Tv[w * 136 + h * 16];
        *(uint4*)(vo + ob + 8) = *(const uint4*)&Tv[w * 136 + h * 16 + 8];
    }
}

// ---------------------------------------------------------------------------
// Kernel 3: neighborhood attention (r1-proven config: 1 query/thread,
// 256 threads, 71.7KB LDS -> 2 blocks/CU, measured 73.4us).
// ---------------------------------------------------------------------------
__global__ __launch_bounds__(256) void k_attn(const _Float16* __restrict__ qws,
                                              const _Float16* __restrict__ kws,
                                              const _Float16* __restrict__ vws,
                                              const float* __restrict__ rpbl2,
                                              bf16* __restrict__ ows) {
    __shared__ unsigned ktv[14][64][20];   // [0..7]=k f16x16, [8..15]=v, [16..19] pad
    const int tid  = threadIdx.x;
    const int bh   = blockIdx.x >> 4;
    const int i0   = (blockIdx.x & 15) << 2;
    const int head = bh & 7;
    int start_min = i0 - 5; if (start_min < 0) start_min = 0; if (start_min > 53) start_min = 53;
    const unsigned* ku = (const unsigned*)kws;
    const unsigned* vu = (const unsigned*)vws;
    const size_t gbase = ((size_t)bh * 4096 + (size_t)start_min * 64) * 8;
    for (int idx = tid; idx < 1792; idx += 256) {
        int a = idx >> 7, rem = idx & 127, col = rem >> 1, h4 = (rem & 1) * 4;
        if (start_min + a < 64) {
            *(uint4*)&ktv[a][col][h4]     = *(const uint4*)(ku + gbase + (size_t)a * 512 + col * 8 + h4);
            *(uint4*)&ktv[a][col][8 + h4] = *(const uint4*)(vu + gbase + (size_t)a * 512 + col * 8 + h4);
        }
    }
    __syncthreads();
    const int wv = tid >> 6;
    const int j  = tid & 63;
    const int i  = i0 + wv;
    int start_i = i - 5; if (start_i < 0) start_i = 0; if (start_i > 53) start_i = 53;
    const int off = start_i - start_min;
    v2h qh[8];
    {
        const uint4* qp = (const uint4*)(qws + ((size_t)bh * 4096 + i * 64 + j) * 16);
        uint4 q0 = qp[0], q1 = qp[1];
        qh[0] = u2h(q0.x); qh[1] = u2h(q0.y); qh[2] = u2h(q0.z); qh[3] = u2h(q0.w);
        qh[4] = u2h(q1.x); qh[5] = u2h(q1.y); qh[6] = u2h(q1.z); qh[7] = u2h(q1.w);
    }
    int start_j = j - 5; if (start_j < 0) start_j = 0; if (start_j > 53) start_j = 53;
    float l = 0.f;
    v2h acc[8];
#pragma unroll
    for (int d = 0; d < 8; ++d) acc[d] = (v2h){(_Float16)0.f, (_Float16)0.f};
    const float* rpb_h = rpbl2 + head * 441 + (start_j - j + 10);
    for (int a = 0; a < 11; ++a) {
        const int r = off + a;
        const float* rb = rpb_h + (start_i + a - i + 10) * 21;
#pragma unroll
        for (int c = 0; c < 11; ++c) {
            const unsigned* cp = ktv[r][start_j + c];
            uint4 k0 = *(const uint4*)(cp);
            uint4 k1 = *(const uint4*)(cp + 4);
            uint4 v0 = *(const uint4*)(cp + 8);
            uint4 v1 = *(const uint4*)(cp + 12);
            float sa = __builtin_amdgcn_fdot2(qh[0], u2h(k0.x), rb[c], false);
            sa = __builtin_amdgcn_fdot2(qh[1], u2h(k0.y), sa, false);
            sa = __builtin_amdgcn_fdot2(qh[2], u2h(k0.z), sa, false);
            sa = __builtin_amdgcn_fdot2(qh[3], u2h(k0.w), sa, false);
            float sb = __builtin_amdgcn_fdot2(qh[4], u2h(k1.x), 0.f, false);
            sb = __builtin_amdgcn_fdot2(qh[5], u2h(k1.y), sb, false);
            sb = __builtin_amdgcn_fdot2(qh[6], u2h(k1.z), sb, false);
            sb = __builtin_amdgcn_fdot2(qh[7], u2h(k1.w), sb, false);
            float p = __builtin_amdgcn_exp2f(sa + sb);
            l += p;
            _Float16 ph = (_Float16)p;
            v2h p2 = {ph, ph};
            acc[0] += u2h(v0.x) * p2;
            acc[1] += u2h(v0.y) * p2;
            acc[2] += u2h(v0.z) * p2;
            acc[3] += u2h(v0.w) * p2;
            acc[4] += u2h(v1.x) * p2;
            acc[5] += u2h(v1.y) * p2;
            acc[6] += u2h(v1.z) * p2;
            acc[7] += u2h(v1.w) * p2;
        }
    }
    float inv = 1.f / l;
    int b = bh >> 3;
    unsigned* op = (unsigned*)ows + ((size_t)b * 4096 + i * 64 + j) * 64 + head * 8;
#pragma unroll
    for (int d2 = 0; d2 < 8; ++d2)
        op[d2] = pk2((float)acc[d2].x * inv, (float)acc[d2].y * inv);
}

// ---------------------------------------------------------------------------
// Kernel 4 (MFMA, fused proj+ffn):
//   y = x + concat(o,x)@proj_w + proj_b          (y kept in LDS, never HBM)
//   out = y + gelu(LN(y)@f1+b1)@f2 + b2
// gelu = tanh-form fast approx (the erff version was ~3x the kernel's MFMA
// work on the VALU pipe -- r6 counters: VALUBusy 32% vs MfmaUtil 11.5%).
// ---------------------------------------------------------------------------
__global__ __launch_bounds__(256) void k_pf(const float* __restrict__ x,
                                            const bf16* __restrict__ ows,
                                            const bf16* __restrict__ pwf,
                                            const float* __restrict__ pb,
                                            const float* __restrict__ g, const float* __restrict__ bb,
                                            const bf16* __restrict__ w1f, const float* __restrict__ b1,
                                            const bf16* __restrict__ w2f, const float* __restrict__ b2,
                                            float* __restrict__ outp) {
    __shared__ short RA[16896];          // 33,792 B overlay region
    __shared__ float Ys[32 * 132];       // 16,896 B (y rows, fp32, pad 132)
    short* An = RA;                      // [32][264] proj staging (o|x bf16)
    float* Xs = (float*)(RA + 8448);     // [32][132] raw x fp32
    const int t = threadIdx.x;
    const size_t row0 = (size_t)blockIdx.x * 32;
    // ---- proj staging ----
    {
        const int r = t >> 3, li = t & 7;
        const uint4* osrc = (const uint4*)(ows + (row0 + r) * 128 + li * 16);
        uint4 o0 = osrc[0], o1 = osrc[1];
        *(uint4*)&An[r * 264 + li * 16]     = o0;
        *(uint4*)&An[r * 264 + li * 16 + 8] = o1;
        const float* xr = x + (row0 + r) * 128 + li * 16;
        v8s xa, xb;
#pragma unroll
        for (int k4 = 0; k4 < 2; ++k4) {
            float4 vv = *(const float4*)(xr + 4 * k4);
            *(float4*)&Xs[r * 132 + li * 16 + 4 * k4] = vv;
            xa[4 * k4 + 0] = f2bs(vv.x); xa[4 * k4 + 1] = f2bs(vv.y);
            xa[4 * k4 + 2] = f2bs(vv.z); xa[4 * k4 + 3] = f2bs(vv.w);
        }
#pragma unroll
        for (int k4 = 0; k4 < 2; ++k4) {
            float4 vv = *(const float4*)(xr + 8 + 4 * k4);
            *(float4*)&Xs[r * 132 + li * 16 + 8 + 4 * k4] = vv;
            xb[4 * k4 + 0] = f2bs(vv.x); xb[4 * k4 + 1] = f2bs(vv.y);
            xb[4 * k4 + 2] = f2bs(vv.z); xb[4 * k4 + 3] = f2bs(vv.w);
        }
        *(v8s*)&An[r * 264 + 128 + li * 16]     = xa;
        *(v8s*)&An[r * 264 + 128 + li * 16 + 8] = xb;
    }
    __syncthreads();
    const int lane = t & 63, wv = t >> 6;
    const int m = lane & 15, quad = lane >> 4;
    const int ntb = wv * 2;
    // ---- proj MFMA ----
    {
        v4f acc[2][2];
#pragma unroll
        for (int a = 0; a < 2; ++a)
#pragma unroll
            for (int b = 0; b < 2; ++b) acc[a][b] = (v4f){0.f, 0.f, 0.f, 0.f};
#pragma unroll
        for (int ks = 0; ks < 8; ++ks) {
            v8s a0 = *(const v8s*)&An[m * 264 + ks * 32 + quad * 8];
            v8s a1 = *(const v8s*)&An[(m + 16) * 264 + ks * 32 + quad * 8];
            const v8s* bp = (const v8s*)pwf + ((size_t)ks * 8 + ntb) * 64 + lane;
#pragma unroll
            for (int nt = 0; nt < 2; ++nt) {
                v8s b = bp[nt * 64];
                acc[0][nt] = __builtin_amdgcn_mfma_f32_16x16x32_bf16(a0, b, acc[0][nt], 0, 0, 0);
                acc[1][nt] = __builtin_amdgcn_mfma_f32_16x16x32_bf16(a1, b, acc[1][nt], 0, 0, 0);
            }
        }
        // y -> Ys (LDS), residual from Xs
#pragma unroll
        for (int nt = 0; nt < 2; ++nt) {
            int n = (ntb + nt) * 16 + m;
            float bv = pb[n];
#pragma unroll
            for (int mt = 0; mt < 2; ++mt)
#pragma unroll
                for (int rg = 0; rg < 4; ++rg) {
                    int row = mt * 16 + quad * 4 + rg;
                    Ys[row * 132 + n] = Xs[row * 132 + n] + bv + acc[mt][nt][rg];
                }
        }
    }
    __syncthreads();    // An/Xs dead; Ys complete
    // ---- LN(y) -> An2 (bf16) ----
    short* An2 = RA;    // [32][136]
    {
        const int r = t >> 3, li = t & 7;
        const float* yr = &Ys[r * 132 + li * 16];
        float v[16];
        float s1 = 0.f, s2 = 0.f;
#pragma unroll
        for (int k = 0; k < 16; ++k) {
            float vv = yr[k];
            v[k] = vv; s1 += vv; s2 += vv * vv;
        }
#pragma unroll
        for (int o = 1; o < 8; o <<= 1) { s1 += __shfl_xor(s1, o); s2 += __shfl_xor(s2, o); }
        float mu = s1 * (1.f / 128.f);
        float rs = rsqrtf(s2 * (1.f / 128.f) - mu * mu + 1e-5f);
        v8s lo, hi;
#pragma unroll
        for (int k = 0; k < 8; ++k) {
            int c = li * 16 + k;
            lo[k] = f2bs((v[k] - mu) * rs * g[c] + bb[c]);
        }
#pragma unroll
        for (int k = 0; k < 8; ++k) {
            int c = li * 16 + 8 + k;
            hi[k] = f2bs((v[8 + k] - mu) * rs * g[c] + bb[c]);
        }
        *(v8s*)&An2[r * 136 + li * 16]     = lo;
        *(v8s*)&An2[r * 136 + li * 16 + 8] = hi;
    }
    __syncthreads();
    // ---- ffn stage 1 ----
    v4f acc1[2][8];
#pragma unroll
    for (int a = 0; a < 2; ++a)
#pragma unroll
        for (int b = 0; b < 8; ++b) acc1[a][b] = (v4f){0.f, 0.f, 0.f, 0.f};
    const int n0w = wv * 128;
#pragma unroll
    for (int ks = 0; ks < 4; ++ks) {
        v8s a0 = *(const v8s*)&An2[m * 136 + ks * 32 + quad * 8];
        v8s a1 = *(const v8s*)&An2[(m + 16) * 136 + ks * 32 + quad * 8];
        const v8s* bp = (const v8s*)w1f + ((size_t)ks * 32 + (n0w >> 4)) * 64 + lane;
#pragma unroll
        for (int nt = 0; nt < 8; ++nt) {
            v8s b = bp[nt * 64];
            acc1[0][nt] = __builtin_amdgcn_mfma_f32_16x16x32_bf16(a0, b, acc1[0][nt], 0, 0, 0);
            acc1[1][nt] = __builtin_amdgcn_mfma_f32_16x16x32_bf16(a1, b, acc1[1][nt], 0, 0, 0);
        }
    }
    __syncthreads();    // An2 dead
    short* Hs = RA;     // [32][520]
#pragma unroll
    for (int nt = 0; nt < 8; ++nt) {
        int n = n0w + nt * 16 + m;
        float b1v = b1[n];
#pragma unroll
        for (int mt = 0; mt < 2; ++mt)
#pragma unroll
            for (int rg = 0; rg < 4; ++rg)
                Hs[(mt * 16 + quad * 4 + rg) * 520 + n] = f2bs(gelu_fast(acc1[mt][nt][rg] + b1v));
    }
    __syncthreads();
    // ---- ffn stage 2 ----
    v4f acc2[2][2];
#pragma unroll
    for (int a = 0; a < 2; ++a)
#pragma unroll
        for (int b = 0; b < 2; ++b) acc2[a][b] = (v4f){0.f, 0.f, 0.f, 0.f};
#pragma unroll
    for (int ks = 0; ks < 16; ++ks) {
        v8s a0 = *(const v8s*)&Hs[m * 520 + ks * 32 + quad * 8];
        v8s a1 = *(const v8s*)&Hs[(m + 16) * 520 + ks * 32 + quad * 8];
        const v8s* bp = (const v8s*)w2f + ((size_t)ks * 8 + ntb) * 64 + lane;
#pragma unroll
        for (int nt = 0; nt < 2; ++nt) {
            v8s b = bp[nt * 64];
            acc2[0][nt] = __builtin_amdgcn_mfma_f32_16x16x32_bf16(a0, b, acc2[0][nt], 0, 0, 0);
            acc2[1][nt] = __builtin_amdgcn_mfma_f32_16x16x32_bf16(a1, b, acc2[1][nt], 0, 0, 0);
        }
    }
#pragma unroll
    for (int nt = 0; nt < 2; ++nt) {
        int n = (ntb + nt) * 16 + m;
        float b2v = b2[n];
#pragma unroll
        for (int mt = 0; mt < 2; ++mt)
#pragma unroll
            for (int rg = 0; rg < 4; ++rg) {
                int row = mt * 16 + quad * 4 + rg;
                size_t gi = (row0 + row) * 128 + n;
                outp[gi] = Ys[row * 132 + n] + b2v + acc2[mt][nt][rg];
            }
    }
}

extern "C" void kernel_launch(void* const* d_in, const int* in_sizes, int n_in,
                              void* d_out, int out_size, void* d_ws, size_t ws_size,
                              hipStream_t stream) {
    const float* x      = (const float*)d_in[0];
    const float* ctx    = (const float*)d_in[1];
    const float* ctxn_g = (const float*)d_in[2];
    const float* ctxn_b = (const float*)d_in[3];
    const float* ctxp_w = (const float*)d_in[4];
    const float* ctxp_b = (const float*)d_in[5];
    const float* n1_g   = (const float*)d_in[6];
    const float* n1_b   = (const float*)d_in[7];
    const float* n1v_g  = (const float*)d_in[8];
    const float* n1v_b  = (const float*)d_in[9];
    const float* q_w    = (const float*)d_in[10];
    const float* q_b    = (const float*)d_in[11];
    const float* k_w    = (const float*)d_in[12];
    const float* k_b    = (const float*)d_in[13];
    const float* v_w    = (const float*)d_in[14];
    const float* v_b    = (const float*)d_in[15];
    const float* rpb    = (const float*)d_in[16];
    const float* proj_w = (const float*)d_in[17];
    const float* proj_b = (const float*)d_in[18];
    const float* n2_g   = (const float*)d_in[19];
    const float* n2_b   = (const float*)d_in[20];
    const float* f1_w   = (const float*)d_in[21];
    const float* f1_b   = (const float*)d_in[22];
    const float* f2_w   = (const float*)d_in[23];
    const float* f2_b   = (const float*)d_in[24];
    float* out = (float*)d_out;

    char* ws = (char*)d_ws;
    bf16*      ctxp = (bf16*)(ws);                 //  8,388,608 B  (B,HW,64) bf16
    _Float16*  qws  = (_Float16*)(ws + 8388608);   // 16,777,216 B  (B,8,HW,16) f16
    _Float16*  kws  = (_Float16*)(ws + 25165824);  // 16,777,216 B
    _Float16*  vws  = (_Float16*)(ws + 41943040);  // 16,777,216 B
    bf16*      ows  = (bf16*)(ws + 58720256);      // 16,777,216 B  (B,HW,128) bf16
    char* frag = ws + 75497472;
    bf16*  w1f  = (bf16*)(frag);                   // 131,072 B
    bf16*  w2f  = (bf16*)(frag + 131072);          // 131,072 B
    bf16*  qwf  = (bf16*)(frag + 262144);          //  49,152 B
    bf16*  kwf  = (bf16*)(frag + 311296);          //  49,152 B
    bf16*  vwf  = (bf16*)(frag + 360448);          //  32,768 B
    bf16*  pwf  = (bf16*)(frag + 393216);          //  65,536 B
    float* rpl2 = (float*)(frag + 458752);         //  14,112 B (8*441 fp32)
    // ctx-GEMM prep lives in the qws region: it is fully consumed by k_ctx,
    // which completes (stream-ordered) before k_qkv writes qws.
    bf16*  wgf  = (bf16*)(ws + 8388608);           //  32,768 B  g.W fragments (K=256,N=64)
    float* cgw  = (float*)(ws + 8388608 + 32768);  //     256 B  sum_e g*W
    float* cbw  = (float*)(ws + 8388608 + 33024);  //     256 B  sum_e b*W + pb

    k_prep<<<975, 256, 0, stream>>>(f1_w, f2_w, q_w, k_w, v_w, proj_w, ctxp_w,
                                    ctxn_g, ctxn_b, ctxp_b, rpb,
                                    w1f, w2f, qwf, kwf, vwf, pwf,
                                    wgf, cgw, cbw, rpl2);
    k_ctx<<<2048, 256, 0, stream>>>(ctx, cgw, cbw, wgf, ctxp);
    k_qkv<<<2048, 256, 0, stream>>>(x, ctxp, n1_g, n1_b, n1v_g, n1v_b,
                                    qwf, q_b, kwf, k_b, vwf, v_b, qws, kws, vws);
    k_attn<<<2048, 256, 0, stream>>>(qws, kws, vws, rpl2, ows);
    k_pf<<<2048, 256, 0, stream>>>(x, ows, pwf, proj_b, n2_g, n2_b,
                                   w1f, f1_b, w2f, f2_b, out);
}

// Round 9
// 343.685 us; speedup vs baseline: 1.2260x; 1.0154x over previous
//
#include <hip/hip_runtime.h>
#include <hip/hip_bf16.h>
#include <math.h>

typedef __hip_bfloat16 bf16;
typedef float v2f __attribute__((ext_vector_type(2)));
typedef float v4f __attribute__((ext_vector_type(4)));
typedef short v8s __attribute__((ext_vector_type(8)));
typedef _Float16 v2h __attribute__((ext_vector_type(2)));

__device__ __forceinline__ float b2f(bf16 v) { return __bfloat162float(v); }
__device__ __forceinline__ float unpk_lo(unsigned u) { return __uint_as_float(u << 16); }
__device__ __forceinline__ float unpk_hi(unsigned u) { return __uint_as_float(u & 0xffff0000u); }
__device__ __forceinline__ v2f unpk2(unsigned u) {
    v2f r; r.x = __uint_as_float(u << 16); r.y = __uint_as_float(u & 0xffff0000u); return r;
}
__device__ __forceinline__ unsigned pk2(float a, float b) {
    unsigned ua = __float_as_uint(a);
    unsigned ub = __float_as_uint(b);
    ua = (ua + 0x7fffu + ((ua >> 16) & 1u)) >> 16;   // RNE to bf16
    ub = (ub + 0x7fffu + ((ub >> 16) & 1u)) >> 16;
    return ua | (ub << 16);
}
__device__ __forceinline__ short f2bs(float f) {
    unsigned u = __float_as_uint(f);
    u = (u + 0x7fffu + ((u >> 16) & 1u)) >> 16;
    return (short)u;
}
__device__ __forceinline__ short f2hs(float f) {
    union { _Float16 h; short s; } c; c.h = (_Float16)f; return c.s;
}
__device__ __forceinline__ v2h u2h(unsigned u) {
    union { unsigned u; v2h h; } c; c.u = u; return c.h;
}
// tanh-form gelu: 8 VALU instr (2 transcendental) vs ~25 for erff.
__device__ __forceinline__ float gelu_fast(float x) {
    float u = x * (1.f + 0.044715f * x * x);
    float t = __builtin_amdgcn_exp2f(-2.3022078f * u);
#if __has_builtin(__builtin_amdgcn_rcpf)
    return x * __builtin_amdgcn_rcpf(1.f + t);
#else
    return x / (1.f + t);
#endif
}

#define LOG2E 1.44269504088896340736f

// ---------------------------------------------------------------------------
// One-shot prep kernel: all weight repacks + LN-fold vectors + rpb transform.
// ---------------------------------------------------------------------------
__global__ __launch_bounds__(256) void k_prep(const float* __restrict__ f1_w,
                                              const float* __restrict__ f2_w,
                                              const float* __restrict__ q_w,
                                              const float* __restrict__ k_w,
                                              const float* __restrict__ v_w,
                                              const float* __restrict__ proj_w,
                                              const float* __restrict__ ctxp_w,
                                              const float* __restrict__ ctxn_g,
                                              const float* __restrict__ ctxn_b,
                                              const float* __restrict__ ctxp_b,
                                              const float* __restrict__ rpb,
                                              bf16* __restrict__ w1f, bf16* __restrict__ w2f,
                                              bf16* __restrict__ qwf, bf16* __restrict__ kwf,
                                              bf16* __restrict__ vwf, bf16* __restrict__ pwf,
                                              bf16* __restrict__ wgf,
                                              float* __restrict__ cgw, float* __restrict__ cbw,
                                              float* __restrict__ rpl2) {
    const int blk = blockIdx.x;
    if (blk < 896) {
        const float* src; bf16* dst; int K, N, base;
        if (blk < 256)      { src = f1_w;   dst = w1f; K = 128; N = 512; base = 0;   }
        else if (blk < 512) { src = f2_w;   dst = w2f; K = 512; N = 128; base = 256; }
        else if (blk < 608) { src = q_w;    dst = qwf; K = 192; N = 128; base = 512; }
        else if (blk < 704) { src = k_w;    dst = kwf; K = 192; N = 128; base = 608; }
        else if (blk < 768) { src = v_w;    dst = vwf; K = 128; N = 128; base = 704; }
        else                { src = proj_w; dst = pwf; K = 256; N = 128; base = 768; }
        int idx = (blk - base) * 256 + threadIdx.x;
        if (idx >= K * N) return;
        int k = idx / N, n = idx % N;
        int kstep = k >> 5, quad = (k & 31) >> 3, j = k & 7;
        int ntile = n >> 4, nn = n & 15;
        size_t di = ((((size_t)kstep * (N >> 4)) + ntile) * 64 + nn + (quad << 4)) * 8 + j;
        dst[di] = __float2bfloat16(src[idx]);
    } else if (blk < 960) {
        // wgf: repack ctxp_w (K=256,N=64) with row-scale ctxn_g[k]
        int idx = (blk - 896) * 256 + threadIdx.x;
        const int N = 64;
        int k = idx / N, n = idx % N;
        int kstep = k >> 5, quad = (k & 31) >> 3, j = k & 7;
        int ntile = n >> 4, nn = n & 15;
        size_t di = ((((size_t)kstep * (N >> 4)) + ntile) * 64 + nn + (quad << 4)) * 8 + j;
        wgf[di] = __float2bfloat16(ctxp_w[idx] * ctxn_g[k]);
    } else if (blk < 974) {
        int i = (blk - 960) * 256 + threadIdx.x;
        if (i < 8 * 441) rpl2[i] = rpb[i] * LOG2E - 8.0f;
    } else {
        // ctxc: cgw[n] = sum_e g*W, cbw[n] = sum_e b*W + pb
        __shared__ float rg_[4][64], rb_[4][64];
        const int n = threadIdx.x & 63, eg = threadIdx.x >> 6;
        float sg = 0.f, sb = 0.f;
        for (int e = eg * 64; e < eg * 64 + 64; ++e) {
            float wv = ctxp_w[e * 64 + n];
            sg += ctxn_g[e] * wv;
            sb += ctxn_b[e] * wv;
        }
        rg_[eg][n] = sg; rb_[eg][n] = sb;
        __syncthreads();
        if (threadIdx.x < 64) {
            float a = rg_[0][n] + rg_[1][n] + rg_[2][n] + rg_[3][n];
            float c = rb_[0][n] + rb_[1][n] + rb_[2][n] + rb_[3][n];
            cgw[n] = a;
            cbw[n] = c + ctxp_b[n];
        }
    }
}

// ---------------------------------------------------------------------------
// Kernel 1 (MFMA, fused ctx-projection + qkv):
//  Phase A: ctx GEMM (LN folded in epilogue) -> Cs in LDS (fp32, never HBM)
//  Phase B: LN(concat(x,Cs),192) -> q,k ; LN(x,128) -> v  (verbatim k_qkv,
//           ctx read from LDS instead of global).
// Same block decomposition as both parents (2048 x 32 rows). Saves the 16MB
// ctxp round-trip and overlaps two latency-bound phases.
// LDS: SM 26,112B (As -> Aqk|Av -> Tq|Tk|Tv) + Cs 8,704B + red 2,304B.
// ---------------------------------------------------------------------------
__global__ __launch_bounds__(256) void k_cqkv(const float* __restrict__ ctx,
                                              const float* __restrict__ cgw,
                                              const float* __restrict__ cbw,
                                              const bf16* __restrict__ wgf,
                                              const float* __restrict__ x,
                                              const float* __restrict__ n1g, const float* __restrict__ n1b,
                                              const float* __restrict__ nvg, const float* __restrict__ nvb,
                                              const bf16* __restrict__ qwf, const float* __restrict__ qb,
                                              const bf16* __restrict__ kwf, const float* __restrict__ kb,
                                              const bf16* __restrict__ vwf, const float* __restrict__ vb,
                                              _Float16* __restrict__ qo, _Float16* __restrict__ ko,
                                              _Float16* __restrict__ vo) {
    __shared__ short SM[13056];          // phase A: As [32][264]; phase B overlays
    __shared__ float Cs[32 * 68];        // ctx-projection output, fp32
    __shared__ float redS[8][32];
    __shared__ float redQ[8][32];
    __shared__ float smu[32], srs[32];
    const int t = threadIdx.x;
    const size_t row0 = (size_t)blockIdx.x * 32;
    const int b   = (int)(row0 >> 12);
    const int hw0 = (int)(row0 & 4095);
    const int lane = t & 63, wv = t >> 6;
    const int m = lane & 15, quad = lane >> 4;
    // ================= Phase A: ctx load + LN stats + GEMM =================
    {
        short* As = SM;                  // [32][264]
        {
            const int r = t & 31, li = t >> 5;
            const float* src = ctx + ((size_t)b * 256 + li * 32) * 4096 + hw0 + r;
            float v[32];
            float s = 0.f, q = 0.f;
#pragma unroll
            for (int j = 0; j < 32; ++j) {
                float xx = src[(size_t)j * 4096];
                v[j] = xx; s += xx; q += xx * xx;
            }
            redS[li][r] = s;
            redQ[li][r] = q;
            v8s p0, p1, p2, p3;
#pragma unroll
            for (int j = 0; j < 8; ++j) p0[j] = f2bs(v[j]);
#pragma unroll
            for (int j = 0; j < 8; ++j) p1[j] = f2bs(v[8 + j]);
#pragma unroll
            for (int j = 0; j < 8; ++j) p2[j] = f2bs(v[16 + j]);
#pragma unroll
            for (int j = 0; j < 8; ++j) p3[j] = f2bs(v[24 + j]);
            v8s* dst = (v8s*)&As[r * 264 + li * 32];
            dst[0] = p0; dst[1] = p1; dst[2] = p2; dst[3] = p3;
        }
        __syncthreads();
        if (t < 32) {
            float s = 0.f, q = 0.f;
#pragma unroll
            for (int k = 0; k < 8; ++k) { s += redS[k][t]; q += redQ[k][t]; }
            float mu = s * (1.f / 256.f);
            float var = q * (1.f / 256.f) - mu * mu;
            smu[t] = mu;
            srs[t] = rsqrtf(var + 1e-5f);
        }
        __syncthreads();
        v4f acc0 = (v4f){0.f, 0.f, 0.f, 0.f};
        v4f acc1 = (v4f){0.f, 0.f, 0.f, 0.f};
#pragma unroll
        for (int ks = 0; ks < 8; ++ks) {
            v8s a0 = *(const v8s*)&As[m * 264 + ks * 32 + quad * 8];
            v8s a1 = *(const v8s*)&As[(m + 16) * 264 + ks * 32 + quad * 8];
            v8s bfr = ((const v8s*)wgf)[((size_t)ks * 4 + wv) * 64 + lane];
            acc0 = __builtin_amdgcn_mfma_f32_16x16x32_bf16(a0, bfr, acc0, 0, 0, 0);
            acc1 = __builtin_amdgcn_mfma_f32_16x16x32_bf16(a1, bfr, acc1, 0, 0, 0);
        }
        const int n = wv * 16 + m;
        const float cg = cgw[n], cb = cbw[n];
#pragma unroll
        for (int rg = 0; rg < 4; ++rg) {
            int row = quad * 4 + rg;
            Cs[row * 68 + n] = srs[row] * (acc0[rg] - smu[row] * cg) + cb;
        }
#pragma unroll
        for (int rg = 0; rg < 4; ++rg) {
            int row = 16 + quad * 4 + rg;
            Cs[row * 68 + n] = srs[row] * (acc1[rg] - smu[row] * cg) + cb;
        }
    }
    __syncthreads();   // As dead, Cs complete
    // ================= Phase B: qkv (verbatim, ctx from Cs) ================
    short* Aqk = SM;
    short* Av  = SM + 6400;
    {
        const int r = t >> 3, li = t & 7;
        const float* xr = x + (row0 + r) * 128 + li * 16;
        float v[16];
        float sx1 = 0.f, sx2 = 0.f;
#pragma unroll
        for (int k4 = 0; k4 < 4; ++k4) {
            float4 vv = *(const float4*)(xr + 4 * k4);
            v[4 * k4 + 0] = vv.x; v[4 * k4 + 1] = vv.y; v[4 * k4 + 2] = vv.z; v[4 * k4 + 3] = vv.w;
            sx1 += vv.x + vv.y + vv.z + vv.w;
            sx2 += vv.x * vv.x + vv.y * vv.y + vv.z * vv.z + vv.w * vv.w;
        }
        float cv[8];
        float sc1 = 0.f, sc2 = 0.f;
        {
            const float* cr = &Cs[r * 68 + li * 8];
            float4 c0 = *(const float4*)(cr);
            float4 c1 = *(const float4*)(cr + 4);
            cv[0] = c0.x; cv[1] = c0.y; cv[2] = c0.z; cv[3] = c0.w;
            cv[4] = c1.x; cv[5] = c1.y; cv[6] = c1.z; cv[7] = c1.w;
#pragma unroll
            for (int k = 0; k < 8; ++k) { sc1 += cv[k]; sc2 += cv[k] * cv[k]; }
        }
#pragma unroll
        for (int o = 1; o < 8; o <<= 1) {
            sx1 += __shfl_xor(sx1, o); sx2 += __shfl_xor(sx2, o);
            sc1 += __shfl_xor(sc1, o); sc2 += __shfl_xor(sc2, o);
        }
        float mu  = (sx1 + sc1) * (1.f / 192.f);
        float rs  = rsqrtf((sx2 + sc2) * (1.f / 192.f) - mu * mu + 1e-5f);
        float muv = sx1 * (1.f / 128.f);
        float rsv = rsqrtf(sx2 * (1.f / 128.f) - muv * muv + 1e-5f);
        v8s q0, q1, vv0, vv1, cc;
#pragma unroll
        for (int k = 0; k < 8; ++k) {
            int c = li * 16 + k;
            q0[k]  = f2bs((v[k] - mu) * rs * n1g[c] + n1b[c]);
            vv0[k] = f2bs((v[k] - muv) * rsv * nvg[c] + nvb[c]);
        }
#pragma unroll
        for (int k = 0; k < 8; ++k) {
            int c = li * 16 + 8 + k;
            q1[k]  = f2bs((v[8 + k] - mu) * rs * n1g[c] + n1b[c]);
            vv1[k] = f2bs((v[8 + k] - muv) * rsv * nvg[c] + nvb[c]);
        }
#pragma unroll
        for (int k = 0; k < 8; ++k) {
            int c = 128 + li * 8 + k;
            cc[k] = f2bs((cv[k] - mu) * rs * n1g[c] + n1b[c]);
        }
        *(v8s*)&Aqk[r * 200 + li * 16]      = q0;
        *(v8s*)&Aqk[r * 200 + li * 16 + 8]  = q1;
        *(v8s*)&Aqk[r * 200 + 128 + li * 8] = cc;
        *(v8s*)&Av[r * 136 + li * 16]       = vv0;
        *(v8s*)&Av[r * 136 + li * 16 + 8]   = vv1;
    }
    __syncthreads();
    const int ntb = wv * 2;
    v4f aq[2][2], ak[2][2], av[2][2];
#pragma unroll
    for (int a = 0; a < 2; ++a)
#pragma unroll
        for (int b2 = 0; b2 < 2; ++b2) {
            aq[a][b2] = (v4f){0.f, 0.f, 0.f, 0.f};
            ak[a][b2] = (v4f){0.f, 0.f, 0.f, 0.f};
            av[a][b2] = (v4f){0.f, 0.f, 0.f, 0.f};
        }
#pragma unroll
    for (int ks = 0; ks < 6; ++ks) {
        v8s a0 = *(const v8s*)&Aqk[m * 200 + ks * 32 + quad * 8];
        v8s a1 = *(const v8s*)&Aqk[(m + 16) * 200 + ks * 32 + quad * 8];
        const v8s* bpq = (const v8s*)qwf + ((size_t)ks * 8 + ntb) * 64 + lane;
        const v8s* bpk = (const v8s*)kwf + ((size_t)ks * 8 + ntb) * 64 + lane;
#pragma unroll
        for (int nt = 0; nt < 2; ++nt) {
            v8s bq = bpq[nt * 64];
            v8s bk = bpk[nt * 64];
            aq[0][nt] = __builtin_amdgcn_mfma_f32_16x16x32_bf16(a0, bq, aq[0][nt], 0, 0, 0);
            aq[1][nt] = __builtin_amdgcn_mfma_f32_16x16x32_bf16(a1, bq, aq[1][nt], 0, 0, 0);
            ak[0][nt] = __builtin_amdgcn_mfma_f32_16x16x32_bf16(a0, bk, ak[0][nt], 0, 0, 0);
            ak[1][nt] = __builtin_amdgcn_mfma_f32_16x16x32_bf16(a1, bk, ak[1][nt], 0, 0, 0);
        }
    }
#pragma unroll
    for (int ks = 0; ks < 4; ++ks) {
        v8s a0 = *(const v8s*)&Av[m * 136 + ks * 32 + quad * 8];
        v8s a1 = *(const v8s*)&Av[(m + 16) * 136 + ks * 32 + quad * 8];
        const v8s* bpv = (const v8s*)vwf + ((size_t)ks * 8 + ntb) * 64 + lane;
#pragma unroll
        for (int nt = 0; nt < 2; ++nt) {
            v8s bv = bpv[nt * 64];
            av[0][nt] = __builtin_amdgcn_mfma_f32_16x16x32_bf16(a0, bv, av[0][nt], 0, 0, 0);
            av[1][nt] = __builtin_amdgcn_mfma_f32_16x16x32_bf16(a1, bv, av[1][nt], 0, 0, 0);
        }
    }
    __syncthreads();    // Aqk/Av dead; reuse SM as transpose buffers
    short* Tq = SM;
    short* Tk = SM + 4352;
    short* Tv = SM + 8704;
#pragma unroll
    for (int nt = 0; nt < 2; ++nt) {
        int n = (ntb + nt) * 16 + m;
        float qbv = qb[n], kbv = kb[n], vbv = vb[n];
#pragma unroll
        for (int mt = 0; mt < 2; ++mt)
#pragma unroll
            for (int rg = 0; rg < 4; ++rg) {
                int row = mt * 16 + quad * 4 + rg;
                Tq[row * 136 + n] = f2hs((aq[mt][nt][rg] + qbv) * (0.25f * LOG2E));
                Tk[row * 136 + n] = f2hs(ak[mt][nt][rg] + kbv);
                Tv[row * 136 + n] = f2hs(av[mt][nt][rg] + vbv);
            }
    }
    __syncthreads();
    {
        const int h = t >> 5, w = t & 31;
        const size_t qrow = row0 + w;
        const int bq = (int)(qrow >> 12), hw = (int)(qrow & 4095);
        const size_t ob = (((size_t)bq * 8 + h) * 4096 + hw) * 16;
        *(uint4*)(qo + ob)     = *(const uint4*)&Tq[w * 136 + h * 16];
        *(uint4*)(qo + ob + 8) = *(const uint4*)&Tq[w * 136 + h * 16 + 8];
        *(uint4*)(ko + ob)     = *(const uint4*)&Tk[w * 136 + h * 16];
        *(uint4*)(ko + ob + 8) = *(const uint4*)&Tk[w * 136 + h * 16 + 8];
        *(uint4*)(vo + ob)     = *(const uint4*)&Tv[w * 136 + h * 16];
        *(uint4*)(vo + ob + 8) = *(const uint4*)&Tv[w * 136 + h * 16 + 8];
    }
}

// ---------------------------------------------------------------------------
// Kernel 2: neighborhood attention (r1-proven config: 1 query/thread,
// 256 threads, 71.7KB LDS -> 2 blocks/CU, measured 73.4us).
// ---------------------------------------------------------------------------
__global__ __launch_bounds__(256) void k_attn(const _Float16* __restrict__ qws,
                                              const _Float16* __restrict__ kws,
                                              const _Float16* __restrict__ vws,
                                              const float* __restrict__ rpbl2,
                                              bf16* __restrict__ ows) {
    __shared__ unsigned ktv[14][64][20];   // [0..7]=k f16x16, [8..15]=v, [16..19] pad
    const int tid  = threadIdx.x;
    const int bh   = blockIdx.x >> 4;
    const int i0   = (blockIdx.x & 15) << 2;
    const int head = bh & 7;
    int start_min = i0 - 5; if (start_min < 0) start_min = 0; if (start_min > 53) start_min = 53;
    const unsigned* ku = (const unsigned*)kws;
    const unsigned* vu = (const unsigned*)vws;
    const size_t gbase = ((size_t)bh * 4096 + (size_t)start_min * 64) * 8;
    for (int idx = tid; idx < 1792; idx += 256) {
        int a = idx >> 7, rem = idx & 127, col = rem >> 1, h4 = (rem & 1) * 4;
        if (start_min + a < 64) {
            *(uint4*)&ktv[a][col][h4]     = *(const uint4*)(ku + gbase + (size_t)a * 512 + col * 8 + h4);
            *(uint4*)&ktv[a][col][8 + h4] = *(const uint4*)(vu + gbase + (size_t)a * 512 + col * 8 + h4);
        }
    }
    __syncthreads();
    const int wv = tid >> 6;
    const int j  = tid & 63;
    const int i  = i0 + wv;
    int start_i = i - 5; if (start_i < 0) start_i = 0; if (start_i > 53) start_i = 53;
    const int off = start_i - start_min;
    v2h qh[8];
    {
        const uint4* qp = (const uint4*)(qws + ((size_t)bh * 4096 + i * 64 + j) * 16);
        uint4 q0 = qp[0], q1 = qp[1];
        qh[0] = u2h(q0.x); qh[1] = u2h(q0.y); qh[2] = u2h(q0.z); qh[3] = u2h(q0.w);
        qh[4] = u2h(q1.x); qh[5] = u2h(q1.y); qh[6] = u2h(q1.z); qh[7] = u2h(q1.w);
    }
    int start_j = j - 5; if (start_j < 0) start_j = 0; if (start_j > 53) start_j = 53;
    float l = 0.f;
    v2h acc[8];
#pragma unroll
    for (int d = 0; d < 8; ++d) acc[d] = (v2h){(_Float16)0.f, (_Float16)0.f};
    const float* rpb_h = rpbl2 + head * 441 + (start_j - j + 10);
    for (int a = 0; a < 11; ++a) {
        const int r = off + a;
        const float* rb = rpb_h + (start_i + a - i + 10) * 21;
#pragma unroll
        for (int c = 0; c < 11; ++c) {
            const unsigned* cp = ktv[r][start_j + c];
            uint4 k0 = *(const uint4*)(cp);
            uint4 k1 = *(const uint4*)(cp + 4);
            uint4 v0 = *(const uint4*)(cp + 8);
            uint4 v1 = *(const uint4*)(cp + 12);
            float sa = __builtin_amdgcn_fdot2(qh[0], u2h(k0.x), rb[c], false);
            sa = __builtin_amdgcn_fdot2(qh[1], u2h(k0.y), sa, false);
            sa = __builtin_amdgcn_fdot2(qh[2], u2h(k0.z), sa, false);
            sa = __builtin_amdgcn_fdot2(qh[3], u2h(k0.w), sa, false);
            float sb = __builtin_amdgcn_fdot2(qh[4], u2h(k1.x), 0.f, false);
            sb = __builtin_amdgcn_fdot2(qh[5], u2h(k1.y), sb, false);
            sb = __builtin_amdgcn_fdot2(qh[6], u2h(k1.z), sb, false);
            sb = __builtin_amdgcn_fdot2(qh[7], u2h(k1.w), sb, false);
            float p = __builtin_amdgcn_exp2f(sa + sb);
            l += p;
            _Float16 ph = (_Float16)p;
            v2h p2 = {ph, ph};
            acc[0] += u2h(v0.x) * p2;
            acc[1] += u2h(v0.y) * p2;
            acc[2] += u2h(v0.z) * p2;
            acc[3] += u2h(v0.w) * p2;
            acc[4] += u2h(v1.x) * p2;
            acc[5] += u2h(v1.y) * p2;
            acc[6] += u2h(v1.z) * p2;
            acc[7] += u2h(v1.w) * p2;
        }
    }
    float inv = 1.f / l;
    int b = bh >> 3;
    unsigned* op = (unsigned*)ows + ((size_t)b * 4096 + i * 64 + j) * 64 + head * 8;
#pragma unroll
    for (int d2 = 0; d2 < 8; ++d2)
        op[d2] = pk2((float)acc[d2].x * inv, (float)acc[d2].y * inv);
}

// ---------------------------------------------------------------------------
// Kernel 3 (MFMA, fused proj+ffn):
//   y = x + concat(o,x)@proj_w + proj_b          (y kept in LDS, never HBM)
//   out = y + gelu(LN(y)@f1+b1)@f2 + b2
// ---------------------------------------------------------------------------
__global__ __launch_bounds__(256) void k_pf(const float* __restrict__ x,
                                            const bf16* __restrict__ ows,
                                            const bf16* __restrict__ pwf,
                                            const float* __restrict__ pb,
                                            const float* __restrict__ g, const float* __restrict__ bb,
                                            const bf16* __restrict__ w1f, const float* __restrict__ b1,
                                            const bf16* __restrict__ w2f, const float* __restrict__ b2,
                                            float* __restrict__ outp) {
    __shared__ short RA[16896];          // 33,792 B overlay region
    __shared__ float Ys[32 * 132];       // 16,896 B (y rows, fp32, pad 132)
    short* An = RA;                      // [32][264] proj staging (o|x bf16)
    float* Xs = (float*)(RA + 8448);     // [32][132] raw x fp32
    const int t = threadIdx.x;
    const size_t row0 = (size_t)blockIdx.x * 32;
    // ---- proj staging ----
    {
        const int r = t >> 3, li = t & 7;
        const uint4* osrc = (const uint4*)(ows + (row0 + r) * 128 + li * 16);
        uint4 o0 = osrc[0], o1 = osrc[1];
        *(uint4*)&An[r * 264 + li * 16]     = o0;
        *(uint4*)&An[r * 264 + li * 16 + 8] = o1;
        const float* xr = x + (row0 + r) * 128 + li * 16;
        v8s xa, xb;
#pragma unroll
        for (int k4 = 0; k4 < 2; ++k4) {
            float4 vv = *(const float4*)(xr + 4 * k4);
            *(float4*)&Xs[r * 132 + li * 16 + 4 * k4] = vv;
            xa[4 * k4 + 0] = f2bs(vv.x); xa[4 * k4 + 1] = f2bs(vv.y);
            xa[4 * k4 + 2] = f2bs(vv.z); xa[4 * k4 + 3] = f2bs(vv.w);
        }
#pragma unroll
        for (int k4 = 0; k4 < 2; ++k4) {
            float4 vv = *(const float4*)(xr + 8 + 4 * k4);
            *(float4*)&Xs[r * 132 + li * 16 + 8 + 4 * k4] = vv;
            xb[4 * k4 + 0] = f2bs(vv.x); xb[4 * k4 + 1] = f2bs(vv.y);
            xb[4 * k4 + 2] = f2bs(vv.z); xb[4 * k4 + 3] = f2bs(vv.w);
        }
        *(v8s*)&An[r * 264 + 128 + li * 16]     = xa;
        *(v8s*)&An[r * 264 + 128 + li * 16 + 8] = xb;
    }
    __syncthreads();
    const int lane = t & 63, wv = t >> 6;
    const int m = lane & 15, quad = lane >> 4;
    const int ntb = wv * 2;
    // ---- proj MFMA ----
    {
        v4f acc[2][2];
#pragma unroll
        for (int a = 0; a < 2; ++a)
#pragma unroll
            for (int b = 0; b < 2; ++b) acc[a][b] = (v4f){0.f, 0.f, 0.f, 0.f};
#pragma unroll
        for (int ks = 0; ks < 8; ++ks) {
            v8s a0 = *(const v8s*)&An[m * 264 + ks * 32 + quad * 8];
            v8s a1 = *(const v8s*)&An[(m + 16) * 264 + ks * 32 + quad * 8];
            const v8s* bp = (const v8s*)pwf + ((size_t)ks * 8 + ntb) * 64 + lane;
#pragma unroll
            for (int nt = 0; nt < 2; ++nt) {
                v8s b = bp[nt * 64];
                acc[0][nt] = __builtin_amdgcn_mfma_f32_16x16x32_bf16(a0, b, acc[0][nt], 0, 0, 0);
                acc[1][nt] = __builtin_amdgcn_mfma_f32_16x16x32_bf16(a1, b, acc[1][nt], 0, 0, 0);
            }
        }
        // y -> Ys (LDS), residual from Xs
#pragma unroll
        for (int nt = 0; nt < 2; ++nt) {
            int n = (ntb + nt) * 16 + m;
            float bv = pb[n];
#pragma unroll
            for (int mt = 0; mt < 2; ++mt)
#pragma unroll
                for (int rg = 0; rg < 4; ++rg) {
                    int row = mt * 16 + quad * 4 + rg;
                    Ys[row * 132 + n] = Xs[row * 132 + n] + bv + acc[mt][nt][rg];
                }
        }
    }
    __syncthreads();    // An/Xs dead; Ys complete
    // ---- LN(y) -> An2 (bf16) ----
    short* An2 = RA;    // [32][136]
    {
        const int r = t >> 3, li = t & 7;
        const float* yr = &Ys[r * 132 + li * 16];
        float v[16];
        float s1 = 0.f, s2 = 0.f;
#pragma unroll
        for (int k = 0; k < 16; ++k) {
            float vv = yr[k];
            v[k] = vv; s1 += vv; s2 += vv * vv;
        }
#pragma unroll
        for (int o = 1; o < 8; o <<= 1) { s1 += __shfl_xor(s1, o); s2 += __shfl_xor(s2, o); }
        float mu = s1 * (1.f / 128.f);
        float rs = rsqrtf(s2 * (1.f / 128.f) - mu * mu + 1e-5f);
        v8s lo, hi;
#pragma unroll
        for (int k = 0; k < 8; ++k) {
            int c = li * 16 + k;
            lo[k] = f2bs((v[k] - mu) * rs * g[c] + bb[c]);
        }
#pragma unroll
        for (int k = 0; k < 8; ++k) {
            int c = li * 16 + 8 + k;
            hi[k] = f2bs((v[8 + k] - mu) * rs * g[c] + bb[c]);
        }
        *(v8s*)&An2[r * 136 + li * 16]     = lo;
        *(v8s*)&An2[r * 136 + li * 16 + 8] = hi;
    }
    __syncthreads();
    // ---- ffn stage 1 ----
    v4f acc1[2][8];
#pragma unroll
    for (int a = 0; a < 2; ++a)
#pragma unroll
        for (int b = 0; b < 8; ++b) acc1[a][b] = (v4f){0.f, 0.f, 0.f, 0.f};
    const int n0w = wv * 128;
#pragma unroll
    for (int ks = 0; ks < 4; ++ks) {
        v8s a0 = *(const v8s*)&An2[m * 136 + ks * 32 + quad * 8];
        v8s a1 = *(const v8s*)&An2[(m + 16) * 136 + ks * 32 + quad * 8];
        const v8s* bp = (const v8s*)w1f + ((size_t)ks * 32 + (n0w >> 4)) * 64 + lane;
#pragma unroll
        for (int nt = 0; nt < 8; ++nt) {
            v8s b = bp[nt * 64];
            acc1[0][nt] = __builtin_amdgcn_mfma_f32_16x16x32_bf16(a0, b, acc1[0][nt], 0, 0, 0);
            acc1[1][nt] = __builtin_amdgcn_mfma_f32_16x16x32_bf16(a1, b, acc1[1][nt], 0, 0, 0);
        }
    }
    __syncthreads();    // An2 dead
    short* Hs = RA;     // [32][520]
#pragma unroll
    for (int nt = 0; nt < 8; ++nt) {
        int n = n0w + nt * 16 + m;
        float b1v = b1[n];
#pragma unroll
        for (int mt = 0; mt < 2; ++mt)
#pragma unroll
            for (int rg = 0; rg < 4; ++rg)
                Hs[(mt * 16 + quad * 4 + rg) * 520 + n] = f2bs(gelu_fast(acc1[mt][nt][rg] + b1v));
    }
    __syncthreads();
    // ---- ffn stage 2 ----
    v4f acc2[2][2];
#pragma unroll
    for (int a = 0; a < 2; ++a)
#pragma unroll
        for (int b = 0; b < 2; ++b) acc2[a][b] = (v4f){0.f, 0.f, 0.f, 0.f};
#pragma unroll
    for (int ks = 0; ks < 16; ++ks) {
        v8s a0 = *(const v8s*)&Hs[m * 520 + ks * 32 + quad * 8];
        v8s a1 = *(const v8s*)&Hs[(m + 16) * 520 + ks * 32 + quad * 8];
        const v8s* bp = (const v8s*)w2f + ((size_t)ks * 8 + ntb) * 64 + lane;
#pragma unroll
        for (int nt = 0; nt < 2; ++nt) {
            v8s b = bp[nt * 64];
            acc2[0][nt] = __builtin_amdgcn_mfma_f32_16x16x32_bf16(a0, b, acc2[0][nt], 0, 0, 0);
            acc2[1][nt] = __builtin_amdgcn_mfma_f32_16x16x32_bf16(a1, b, acc2[1][nt], 0, 0, 0);
        }
    }
#pragma unroll
    for (int nt = 0; nt < 2; ++nt) {
        int n = (ntb + nt) * 16 + m;
        float b2v = b2[n];
#pragma unroll
        for (int mt = 0; mt < 2; ++mt)
#pragma unroll
            for (int rg = 0; rg < 4; ++rg) {
                int row = mt * 16 + quad * 4 + rg;
                size_t gi = (row0 + row) * 128 + n;
                outp[gi] = Ys[row * 132 + n] + b2v + acc2[mt][nt][rg];
            }
    }
}

extern "C" void kernel_launch(void* const* d_in, const int* in_sizes, int n_in,
                              void* d_out, int out_size, void* d_ws, size_t ws_size,
                              hipStream_t stream) {
    const float* x      = (const float*)d_in[0];
    const float* ctx    = (const float*)d_in[1];
    const float* ctxn_g = (const float*)d_in[2];
    const float* ctxn_b = (const float*)d_in[3];
    const float* ctxp_w = (const float*)d_in[4];
    const float* ctxp_b = (const float*)d_in[5];
    const float* n1_g   = (const float*)d_in[6];
    const float* n1_b   = (const float*)d_in[7];
    const float* n1v_g  = (const float*)d_in[8];
    const float* n1v_b  = (const float*)d_in[9];
    const float* q_w    = (const float*)d_in[10];
    const float* q_b    = (const float*)d_in[11];
    const float* k_w    = (const float*)d_in[12];
    const float* k_b    = (const float*)d_in[13];
    const float* v_w    = (const float*)d_in[14];
    const float* v_b    = (const float*)d_in[15];
    const float* rpb    = (const float*)d_in[16];
    const float* proj_w = (const float*)d_in[17];
    const float* proj_b = (const float*)d_in[18];
    const float* n2_g   = (const float*)d_in[19];
    const float* n2_b   = (const float*)d_in[20];
    const float* f1_w   = (const float*)d_in[21];
    const float* f1_b   = (const float*)d_in[22];
    const float* f2_w   = (const float*)d_in[23];
    const float* f2_b   = (const float*)d_in[24];
    float* out = (float*)d_out;

    char* ws = (char*)d_ws;
    _Float16*  qws  = (_Float16*)(ws + 8388608);   // 16,777,216 B  (B,8,HW,16) f16
    _Float16*  kws  = (_Float16*)(ws + 25165824);  // 16,777,216 B
    _Float16*  vws  = (_Float16*)(ws + 41943040);  // 16,777,216 B
    bf16*      ows  = (bf16*)(ws + 58720256);      // 16,777,216 B  (B,HW,128) bf16
    char* frag = ws + 75497472;
    bf16*  w1f  = (bf16*)(frag);                   // 131,072 B
    bf16*  w2f  = (bf16*)(frag + 131072);          // 131,072 B
    bf16*  qwf  = (bf16*)(frag + 262144);          //  49,152 B
    bf16*  kwf  = (bf16*)(frag + 311296);          //  49,152 B
    bf16*  vwf  = (bf16*)(frag + 360448);          //  32,768 B
    bf16*  pwf  = (bf16*)(frag + 393216);          //  65,536 B
    float* rpl2 = (float*)(frag + 458752);         //  14,112 B (8*441 fp32)
    // ctx-GEMM prep lives in the ows region: fully consumed by k_cqkv, which
    // completes (stream-ordered) before k_attn writes ows.
    bf16*  wgf  = (bf16*)(ws + 58720256);          //  32,768 B  g.W fragments (K=256,N=64)
    float* cgw  = (float*)(ws + 58720256 + 32768); //     256 B  sum_e g*W
    float* cbw  = (float*)(ws + 58720256 + 33024); //     256 B  sum_e b*W + pb

    k_prep<<<975, 256, 0, stream>>>(f1_w, f2_w, q_w, k_w, v_w, proj_w, ctxp_w,
                                    ctxn_g, ctxn_b, ctxp_b, rpb,
                                    w1f, w2f, qwf, kwf, vwf, pwf,
                                    wgf, cgw, cbw, rpl2);
    k_cqkv<<<2048, 256, 0, stream>>>(ctx, cgw, cbw, wgf, x,
                                     n1_g, n1_b, n1v_g, n1v_b,
                                     qwf, q_b, kwf, k_b, vwf, v_b,
                                     qws, kws, vws);
    k_attn<<<2048, 256, 0, stream>>>(qws, kws, vws, rpl2, ows);
    k_pf<<<2048, 256, 0, stream>>>(x, ows, pwf, proj_b, n2_g, n2_b,
                                   w1f, f1_b, w2f, f2_b, out);
}